// Round 6
// baseline (800.646 us; speedup 1.0000x reference)
//

#include <hip/hip_runtime.h>
#include <hip/hip_bf16.h>

// Round 21: R20 retry (fix compile: nontemporal_load can't take int2 -> load
// the 8B record as unsigned long long and split).
// Theory unchanged: wave-independent, degree-adaptive k_prop. rocprof R19:
// k_prop 43.2us, VALU 53-59%, Occ 71%. Drags: (a) d>16 nodes take 2 serial
// latency rounds (compiler doesn't pipeline dependent load->fma loop);
// (b) LDS+barrier reduce couples 4 waves to the slowest node. Fix: masked-8
// single shot for q in (4,8] (8 gathers in flight, clamped slots L1-hit,
// w=0), masked-4 for the light half, shuffle-xor butterfly reduce (no
// barrier, LDS=0), nontemporal edge-loads/hout-stores to keep the streaming
// 25MB/prop from evicting gather rows out of L2.

typedef __hip_bfloat16 bf16;
typedef short short8 __attribute__((ext_vector_type(8)));
typedef float floatx4 __attribute__((ext_vector_type(4)));

static __device__ float bf2f(bf16 v){ return __bfloat162float(v); }

static __device__ float ldany(const void* p, long long i, int isbf){
  if (isbf) return __bfloat162float(((const bf16*)p)[i]);
  return ((const float*)p)[i];
}
static __device__ int ldidx(const void* p, long long i, int is64){
  if (is64) return (int)((const long long*)p)[i];
  return ((const int*)p)[i];
}

// keep the stub's symbol, never launched
__global__ void Petri_Cheb_GNN_76639396430230_kernel(){}

// ---- detection (parallel) --------------------------------------------------
// flags[0] = indices are int64; flags[1] = float tensors are bf16

__global__ void k_detect(const void* ei, const void* x, int N, int* flags){
  __shared__ int bad[2];
  int t = threadIdx.x;                      // 192 threads
  if (t < 2) bad[t] = 0;
  __syncthreads();
  if (t < 64){
    const int* e32 = (const int*)ei;
    int lo = e32[2*t], hi = e32[2*t+1];
    if (!(hi == 0 && lo >= 0 && lo < N)) atomicAdd(&bad[0], 1);
  } else {
    int i = t - 64;                         // 0..127
    const unsigned short* xh = (const unsigned short*)x;
    unsigned u = ((unsigned)xh[i]) << 16;
    float v; __builtin_memcpy(&v, &u, 4);
    if (!(v == v) || fabsf(v) > 64.f) atomicAdd(&bad[1], 1);
  }
  __syncthreads();
  if (t == 0){ flags[0] = bad[0] ? 0 : 1; flags[1] = bad[1] ? 0 : 1; }
}

// ---- fused setup: gsum/gcnt zero + small cvts | wprep ----------------------
// wfs layout: [0,256) bl | [256,2304) wr1 | [2304,2336) br1 |
//             [2336,2368) wr2 | [2368] br2

__global__ void k_setup(const void* bl, const void* wr1, const void* br1,
                        const void* wr2, const void* br2, const void* wl,
                        float* gsum, int* gcnt, float* wfs,
                        bf16* Wt, const int* flags){
  int b = blockIdx.x;
  int tid = threadIdx.x;
  if (b == 0){
    if (tid < 64){ gsum[tid] = 0.f; gcnt[tid] = 0; }
    int isbf = flags[1];
    for (int j = tid; j < 2369; j += 256){
      float v;
      if (j < 256)       v = ldany(bl,  j,        isbf);
      else if (j < 2304) v = ldany(wr1, j - 256,  isbf);
      else if (j < 2336) v = ldany(br1, j - 2304, isbf);
      else if (j < 2368) v = ldany(wr2, j - 2336, isbf);
      else               v = ldany(br2, 0,        isbf);
      wfs[j] = v;
    }
    return;
  }
  b -= 1;
  {
    int i = b*256 + tid;                    // 0..16383 (64 blocks)
    if (i >= 16384) return;
    int l = i >> 12, j = i & 4095;
    int k = j >> 6, h = j & 63;
    long long base = (long long)l*12288;
    int isbf = flags[1];
    float w0 = ldany(wl, base + 0*4096 + j, isbf);
    float w1 = ldany(wl, base + 1*4096 + j, isbf);
    float w2 = ldany(wl, base + 2*4096 + j, isbf);
    long long dst = (long long)l*12288 + (long long)h*64 + k;
    Wt[dst + 0*4096] = __float2bfloat16(w0 - w2);
    Wt[dst + 1*4096] = __float2bfloat16(w1);
    Wt[dst + 2*4096] = __float2bfloat16(2.f * w2);
  }
}

__global__ void k_x2a(const void* x, bf16* a, int n, const int* flags){
  int i = blockIdx.x*256 + threadIdx.x;
  if (i < n) a[i] = __float2bfloat16(ldany(x, i, flags[1]));
}

// ---- dual bucket histogram (s and t) — LDS atomics only --------------------

__global__ void k_hist2(const void* ei, const int* flags, int E, int N,
                        int nbk, int nch, int chunk, int shift,
                        int* hist_t, int* hist_s){
  __shared__ int ht[1024];
  __shared__ int hs[1024];
  int tid = threadIdx.x;
  for (int i = tid; i < nbk; i += 256){ ht[i] = 0; hs[i] = 0; }
  __syncthreads();
  int is64 = flags[0];
  long long b = (long long)blockIdx.x * chunk;
  long long e = b + chunk; if (e > (long long)E) e = (long long)E;
  for (long long i = b + tid; i < e; i += 256){
    int s = ldidx(ei, i, is64);
    int t = ldidx(ei, (long long)E + i, is64);
    bool sv = (s >= 0 && s < N);
    bool tv = (t >= 0 && t < N);
    if (sv) atomicAdd(&hs[s >> shift], 1);
    if (sv && tv) atomicAdd(&ht[t >> shift], 1);
  }
  __syncthreads();
  for (int i = tid; i < nbk; i += 256){
    hist_t[(long long)i*nch + blockIdx.x] = ht[i];
    hist_s[(long long)i*nch + blockIdx.x] = hs[i];
  }
}

// ---- bucket scans (t rows then s rows in one launch) -----------------------

__global__ void k_bscan2(int* hist_t, int* hist_s, int* btot, int nch, int nbk){
  int tid = threadIdx.x;
  int bk  = blockIdx.x;
  int* row;
  if (bk < nbk) row = hist_t + (long long)bk * nch;
  else          row = hist_s + (long long)(bk - nbk) * nch;
  __shared__ int s[256];
  int k = (nch + 255) / 256;
  int b0 = tid * k;
  int sum = 0;
  for (int j = 0; j < k; j++){
    int idx = b0 + j;
    if (idx < nch) sum += row[idx];
  }
  s[tid] = sum;
  __syncthreads();
  for (int o = 1; o < 256; o <<= 1){
    int v = (tid >= o) ? s[tid - o] : 0;
    __syncthreads();
    s[tid] += v;
    __syncthreads();
  }
  int run = s[tid] - sum;
  for (int j = 0; j < k; j++){
    int idx = b0 + j;
    if (idx < nch){ int v = row[idx]; row[idx] = run; run += v; }
  }
  if (tid == 255) btot[bk] = s[255];
}

__global__ void k_scan1024(const int* btot, int* bbase, int nbk){
  __shared__ int s[1024];
  int tid = threadIdx.x;
  int off = blockIdx.x * nbk;
  int v = (tid < nbk) ? btot[off + tid] : 0;
  s[tid] = v;
  __syncthreads();
  for (int o = 1; o < 1024; o <<= 1){
    int u = (tid >= o) ? s[tid - o] : 0;
    __syncthreads();
    s[tid] += u;
    __syncthreads();
  }
  if (tid < nbk) bbase[off + tid] = s[tid] - v;
}

// ---- dual scatter: t-records (s | t_local<<20, raw w) + s-records ----------

__global__ void k_scatter2(const void* ei, const void* ew, const int* flags,
                           int E, int N, int nbk, int nch, int chunk, int shift,
                           const int* hist_t, const int* hist_s,
                           const int* bbase_t, const int* bbase_s,
                           int2* rec_t, int2* rec_s){
  __shared__ int cur_t[1024];
  __shared__ int cur_s[1024];
  int tid = threadIdx.x;
  for (int i = tid; i < nbk; i += 256){
    cur_t[i] = bbase_t[i] + hist_t[(long long)i*nch + blockIdx.x];
    cur_s[i] = bbase_s[i] + hist_s[(long long)i*nch + blockIdx.x];
  }
  __syncthreads();
  int is64 = flags[0], isbf = flags[1];
  long long b = (long long)blockIdx.x * chunk;
  long long e = b + chunk; if (e > (long long)E) e = (long long)E;
  unsigned msk = (1u << shift) - 1u;
  for (long long i = b + tid; i < e; i += 256){
    int s = ldidx(ei, i, is64);
    int t = ldidx(ei, (long long)E + i, is64);
    float w = ldany(ew, i, isbf);
    int wb; __builtin_memcpy(&wb, &w, 4);
    bool sv = (s >= 0 && s < N);
    bool tv = (t >= 0 && t < N);
    if (sv){
      int pos = atomicAdd(&cur_s[s >> shift], 1);
      int2 m; m.x = (int)(s & (int)msk); m.y = wb;
      rec_s[pos] = m;
    }
    if (sv && tv){
      int pos = atomicAdd(&cur_t[t >> shift], 1);
      int2 m; m.x = s | (((int)(t & msk)) << 20); m.y = wb;
      rec_t[pos] = m;
    }
  }
}

// ---- per-bucket degree accumulate -> dis (no global atomics) ---------------

__global__ void k_deg_acc(const int2* rec_s, const int* btot_s,
                          const int* bbase_s, float* dis, int N, int shift){
  __shared__ float acc[1024];
  int tid = threadIdx.x;
  int bk  = blockIdx.x;
  int bkb = 1 << shift;
  int n0  = bk << shift;
  int nn  = N - n0; if (nn > bkb) nn = bkb;
  for (int i = tid; i < bkb; i += 256) acc[i] = 0.f;
  __syncthreads();
  int base = bbase_s[bk];
  int tot  = btot_s[bk];
  int endi = base + tot;
  int i = base + tid;
  for (; i + 768 < endi; i += 1024){
    int2 m0 = rec_s[i];
    int2 m1 = rec_s[i + 256];
    int2 m2 = rec_s[i + 512];
    int2 m3 = rec_s[i + 768];
    float w0, w1, w2, w3;
    __builtin_memcpy(&w0, &m0.y, 4);
    __builtin_memcpy(&w1, &m1.y, 4);
    __builtin_memcpy(&w2, &m2.y, 4);
    __builtin_memcpy(&w3, &m3.y, 4);
    atomicAdd(&acc[m0.x], w0);
    atomicAdd(&acc[m1.x], w1);
    atomicAdd(&acc[m2.x], w2);
    atomicAdd(&acc[m3.x], w3);
  }
  for (; i < endi; i += 256){
    int2 m = rec_s[i];
    float w; __builtin_memcpy(&w, &m.y, 4);
    atomicAdd(&acc[m.x], w);
  }
  __syncthreads();
  for (int j = tid; j < nn; j += 256){
    float d = acc[j];
    dis[n0 + j] = (d > 0.f) ? rsqrtf(d) : 0.f;
  }
}

// ---- CSR build (+ fused -dis[s]*w*dis[t] weight normalize) -----------------

__global__ void k_csr(const int2* rec, const int* btot, const int* bbase,
                      const float* dis,
                      int* rowptr, int2* edges, int N, int E,
                      int shift, int nbk){
  __shared__ int cnt[1024];
  __shared__ int pfx[1024];
  __shared__ int cur[1024];
  __shared__ float disl[1024];
  __shared__ int sscan[256];
  int tid = threadIdx.x;
  int bk  = blockIdx.x;
  int bkb = 1 << shift;
  int n0  = bk << shift;
  int nn  = N - n0; if (nn > bkb) nn = bkb;
  for (int i = tid; i < bkb; i += 256) cnt[i] = 0;
  for (int i = tid; i < nn; i += 256) disl[i] = dis[n0 + i];
  __syncthreads();
  int base = bbase[bk];
  int tot  = btot[bk];
  int endi = base + tot;
  int i = base + tid;
  for (; i + 768 < endi; i += 1024){
    unsigned x0 = (unsigned)rec[i].x;
    unsigned x1 = (unsigned)rec[i + 256].x;
    unsigned x2 = (unsigned)rec[i + 512].x;
    unsigned x3 = (unsigned)rec[i + 768].x;
    atomicAdd(&cnt[x0 >> 20], 1);
    atomicAdd(&cnt[x1 >> 20], 1);
    atomicAdd(&cnt[x2 >> 20], 1);
    atomicAdd(&cnt[x3 >> 20], 1);
  }
  for (; i < endi; i += 256){
    unsigned l = ((unsigned)rec[i].x) >> 20;
    atomicAdd(&cnt[l], 1);
  }
  __syncthreads();
  // parallel exclusive scan of cnt[0..bkb)
  {
    int kk = (bkb + 255) >> 8;
    int b0 = tid * kk;
    int sum = 0;
    for (int j = 0; j < kk; j++){
      int idx = b0 + j;
      if (idx < bkb) sum += cnt[idx];
    }
    sscan[tid] = sum;
    __syncthreads();
    for (int o = 1; o < 256; o <<= 1){
      int v = (tid >= o) ? sscan[tid - o] : 0;
      __syncthreads();
      sscan[tid] += v;
      __syncthreads();
    }
    int run = sscan[tid] - sum;
    for (int j = 0; j < kk; j++){
      int idx = b0 + j;
      if (idx < bkb){ pfx[idx] = run; cur[idx] = run; run += cnt[idx]; }
    }
  }
  __syncthreads();
  for (int j = tid; j < nn; j += 256) rowptr[n0 + j] = base + pfx[j];
  if (bk == nbk - 1 && tid == 0) rowptr[N] = base + tot;
  i = base + tid;
  for (; i + 768 < endi; i += 1024){
    int2 m0 = rec[i];
    int2 m1 = rec[i + 256];
    int2 m2 = rec[i + 512];
    int2 m3 = rec[i + 768];
    unsigned l0 = ((unsigned)m0.x) >> 20; int s0 = m0.x & 0xFFFFF;
    unsigned l1 = ((unsigned)m1.x) >> 20; int s1 = m1.x & 0xFFFFF;
    unsigned l2 = ((unsigned)m2.x) >> 20; int s2 = m2.x & 0xFFFFF;
    unsigned l3 = ((unsigned)m3.x) >> 20; int s3 = m3.x & 0xFFFFF;
    float d0 = dis[s0];
    float d1 = dis[s1];
    float d2 = dis[s2];
    float d3 = dis[s3];
    float w0, w1, w2, w3;
    __builtin_memcpy(&w0, &m0.y, 4);
    __builtin_memcpy(&w1, &m1.y, 4);
    __builtin_memcpy(&w2, &m2.y, 4);
    __builtin_memcpy(&w3, &m3.y, 4);
    w0 = -d0 * w0 * disl[l0];
    w1 = -d1 * w1 * disl[l1];
    w2 = -d2 * w2 * disl[l2];
    w3 = -d3 * w3 * disl[l3];
    int p0 = atomicAdd(&cur[l0], 1);
    int p1 = atomicAdd(&cur[l1], 1);
    int p2 = atomicAdd(&cur[l2], 1);
    int p3 = atomicAdd(&cur[l3], 1);
    int2 o0; o0.x = s0; __builtin_memcpy(&o0.y, &w0, 4);
    int2 o1; o1.x = s1; __builtin_memcpy(&o1.y, &w1, 4);
    int2 o2; o2.x = s2; __builtin_memcpy(&o2.y, &w2, 4);
    int2 o3; o3.x = s3; __builtin_memcpy(&o3.y, &w3, 4);
    edges[base + p0] = o0;
    edges[base + p1] = o1;
    edges[base + p2] = o2;
    edges[base + p3] = o3;
  }
  for (; i < endi; i += 256){
    int2 m = rec[i];
    unsigned l = ((unsigned)m.x) >> 20;
    int s = m.x & 0xFFFFF;
    float w; __builtin_memcpy(&w, &m.y, 4);
    w = -dis[s] * w * disl[l];
    int pos = atomicAdd(&cur[l], 1);
    int2 o; o.x = s; __builtin_memcpy(&o.y, &w, 4);
    edges[base + pos] = o;
  }
}

// ---- propagation: wave-independent, degree-adaptive masked gather ----------

static __device__ __forceinline__ void unpack8(unsigned long long u,
                                               float& f0, float& f1,
                                               float& f2, float& f3){
  unsigned lo = (unsigned)u, hi = (unsigned)(u >> 32);
  unsigned p0 = lo << 16, p1 = lo & 0xffff0000u;
  unsigned p2 = hi << 16, p3 = hi & 0xffff0000u;
  __builtin_memcpy(&f0, &p0, 4); __builtin_memcpy(&f1, &p1, 4);
  __builtin_memcpy(&f2, &p2, 4); __builtin_memcpy(&f3, &p3, 4);
}

template<int K>
static __device__ __forceinline__ void gatherK(const unsigned long long* __restrict__ erec,
    const unsigned short* __restrict__ hp, int c, int e, int eg,
    float& A0, float& A1, float& A2, float& A3,
    float& B0, float& B1, float& B2, float& B3){
  int idx[K];
#pragma unroll
  for (int k = 0; k < K; k++){ int t = e + k; idx[k] = (t < eg) ? t : e; }
  unsigned long long rr[K];
#pragma unroll
  for (int k = 0; k < K; k++) rr[k] = __builtin_nontemporal_load(&erec[idx[k]]);
  unsigned long long uu[K];
#pragma unroll
  for (int k = 0; k < K; k++){
    long long s = (long long)(unsigned)(rr[k] & 0xFFFFFFFFull);
    uu[k] = *(const unsigned long long*)(hp + (s << 6) + 4*c);
  }
#pragma unroll
  for (int k = 0; k < K; k++){
    unsigned wb = (unsigned)(rr[k] >> 32);
    float w; __builtin_memcpy(&w, &wb, 4);
    if (e + k >= eg) w = 0.f;
    float f0, f1, f2, f3;
    unpack8(uu[k], f0, f1, f2, f3);
    if (k & 1){
      B0 = fmaf(w, f0, B0); B1 = fmaf(w, f1, B1);
      B2 = fmaf(w, f2, B2); B3 = fmaf(w, f3, B3);
    } else {
      A0 = fmaf(w, f0, A0); A1 = fmaf(w, f1, A1);
      A2 = fmaf(w, f2, A2); A3 = fmaf(w, f3, A3);
    }
  }
}

__global__ void k_prop(const int* rowptr, const int2* edges,
                       const bf16* hin, bf16* hout, int N){
  int tid  = threadIdx.x;
  int v    = blockIdx.x*4 + (tid >> 6);
  int lane = tid & 63;
  int g    = lane >> 4;
  int c    = lane & 15;
  int beg = 0, end = 0;
  if (v < N){ beg = rowptr[v]; end = rowptr[v+1]; }
  int cnt  = end - beg;
  int q    = (cnt + 3) >> 2;
  int bg = beg + g*q;
  int eg = bg + q;
  if (bg > end) bg = end;
  if (eg > end) eg = end;
  const unsigned short* hp = (const unsigned short*)hin;
  const unsigned long long* erec = (const unsigned long long*)edges;
  float A0=0.f,A1=0.f,A2=0.f,A3=0.f;
  float B0=0.f,B1=0.f,B2=0.f,B3=0.f;
  int rem = eg - bg;
  if (rem > 0){
    if (rem <= 4){
      gatherK<4>(erec, hp, c, bg, eg, A0,A1,A2,A3, B0,B1,B2,B3);
    } else {
      for (int e = bg; e < eg; e += 8)
        gatherK<8>(erec, hp, c, e, eg, A0,A1,A2,A3, B0,B1,B2,B3);
    }
  }
  float s0 = A0 + B0;
  float s1 = A1 + B1;
  float s2 = A2 + B2;
  float s3 = A3 + B3;
  // butterfly across the 4 groups (lanes xor 16, xor 32) — no barrier, no LDS
  s0 += __shfl_xor(s0, 16); s0 += __shfl_xor(s0, 32);
  s1 += __shfl_xor(s1, 16); s1 += __shfl_xor(s1, 32);
  s2 += __shfl_xor(s2, 16); s2 += __shfl_xor(s2, 32);
  s3 += __shfl_xor(s3, 16); s3 += __shfl_xor(s3, 32);
  if (g == 0 && v < N){
    unsigned u0,u1,u2,u3;
    __builtin_memcpy(&u0,&s0,4); __builtin_memcpy(&u1,&s1,4);
    __builtin_memcpy(&u2,&s2,4); __builtin_memcpy(&u3,&s3,4);
    u0 += 0x7FFFu + ((u0 >> 16) & 1u);
    u1 += 0x7FFFu + ((u1 >> 16) & 1u);
    u2 += 0x7FFFu + ((u2 >> 16) & 1u);
    u3 += 0x7FFFu + ((u3 >> 16) & 1u);
    unsigned pk0 = (u1 & 0xffff0000u) | (u0 >> 16);
    unsigned pk1 = (u3 & 0xffff0000u) | (u2 >> 16);
    unsigned long long pk = ((unsigned long long)pk1 << 32) | pk0;
    __builtin_nontemporal_store(pk,
      (unsigned long long*)((unsigned short*)hout + (((long long)v) << 6) + 4*c));
  }
}

// ---- fused 3-matmul via MFMA -----------------------------------------------

__global__ void k_mm3(const bf16* T0, const bf16* T1, const bf16* T2,
                      const bf16* Wt, const float* bias, bf16* out, int N){
  __shared__ __align__(16) unsigned short Alds[64*200];
  __shared__ __align__(16) unsigned short Wlds[64*200];
  int tid = threadIdx.x;
  int n0 = blockIdx.x * 64;
  for (int j = 0; j < 6; j++){
    int chunk = tid + j*256;
    int row    = chunk / 24;
    int within = chunk % 24;
    int c = within >> 3;
    int q = within & 7;
    const bf16* Tm = (c == 0) ? T0 : ((c == 1) ? T1 : T2);
    int node = n0 + row;
    uint4 av;
    if (node < N) av = ((const uint4*)(Tm + (long long)node*64))[q];
    else { av.x = 0; av.y = 0; av.z = 0; av.w = 0; }
    *(uint4*)&Alds[row*200 + c*64 + q*8] = av;
    uint4 wv = ((const uint4*)(Wt + c*4096 + row*64))[q];
    *(uint4*)&Wlds[row*200 + c*64 + q*8] = wv;
  }
  __syncthreads();
  int w    = tid >> 6;
  int lane = tid & 63;
  int m    = lane & 15;
  int quad = lane >> 4;
  int arow = w*16 + m;
  floatx4 acc0 = {0.f,0.f,0.f,0.f};
  floatx4 acc1 = {0.f,0.f,0.f,0.f};
  floatx4 acc2 = {0.f,0.f,0.f,0.f};
  floatx4 acc3 = {0.f,0.f,0.f,0.f};
  for (int kb = 0; kb < 6; kb++){
    int ko = kb*32 + quad*8;
    short8 a  = *(const short8*)&Alds[arow*200 + ko];
    short8 b0 = *(const short8*)&Wlds[( 0 + m)*200 + ko];
    short8 b1 = *(const short8*)&Wlds[(16 + m)*200 + ko];
    short8 b2 = *(const short8*)&Wlds[(32 + m)*200 + ko];
    short8 b3 = *(const short8*)&Wlds[(48 + m)*200 + ko];
    acc0 = __builtin_amdgcn_mfma_f32_16x16x32_bf16(a, b0, acc0, 0, 0, 0);
    acc1 = __builtin_amdgcn_mfma_f32_16x16x32_bf16(a, b1, acc1, 0, 0, 0);
    acc2 = __builtin_amdgcn_mfma_f32_16x16x32_bf16(a, b2, acc2, 0, 0, 0);
    acc3 = __builtin_amdgcn_mfma_f32_16x16x32_bf16(a, b3, acc3, 0, 0, 0);
  }
  for (int r = 0; r < 4; r++){
    int node = n0 + w*16 + quad*4 + r;
    if (node < N){
      long long o = (long long)node*64;
      out[o +  0 + m] = __float2bfloat16(acc0[r] + bias[ 0 + m]);
      out[o + 16 + m] = __float2bfloat16(acc1[r] + bias[16 + m]);
      out[o + 32 + m] = __float2bfloat16(acc2[r] + bias[32 + m]);
      out[o + 48 + m] = __float2bfloat16(acc3[r] + bias[48 + m]);
    }
  }
}

// ---- readout: per-node MLP scalar r[v] -------------------------------------

__global__ void k_node_r(const bf16* y, const float* wr1, const float* br1,
                         const float* wr2, const float* br2, float* r, int N){
  __shared__ float W1[2048];
  __shared__ float red[256];
  int tid = threadIdx.x;
  for (int j = tid; j < 2048; j += 256) W1[j] = wr1[j];
  __syncthreads();
  int v    = blockIdx.x*4 + (tid >> 6);
  int lane = tid & 63;
  int h    = lane & 31;
  int p0   = lane >> 5;
  float acc = 0.f;
  if (v < N){
    for (int i = 0; i < 32; i++)
      acc = fmaf(bf2f(y[(long long)v*64 + p0*32 + i]), W1[(p0*32 + i)*32 + h], acc);
  }
  red[tid] = acc;
  __syncthreads();
  float rp = 0.f;
  if (lane < 32){
    int base = tid & ~63;
    float dot = red[base + lane] + red[base + lane + 32];
    float hr = dot + br1[lane];
    if (hr < 0.f) hr = 0.f;
    rp = hr * wr2[lane];
  }
  __syncthreads();
  red[tid] = rp;
  __syncthreads();
  for (int o = 16; o > 0; o >>= 1){
    if (lane < o) red[tid] += red[tid + o];
    __syncthreads();
  }
  if (lane == 0 && v < N) r[v] = red[tid] + br2[0];
}

// ---- pooling ---------------------------------------------------------------

__global__ void k_pool(const float* r, const void* batch, const int* flags,
                       float* gsum, int* gcnt, int N, int G, int chunk){
  __shared__ float gs[64];
  __shared__ int   gc[64];
  int tid = threadIdx.x;
  if (tid < 64){ gs[tid] = 0.f; gc[tid] = 0; }
  __syncthreads();
  int is64 = flags[0];
  long long beg = (long long)blockIdx.x * chunk;
  long long end = beg + chunk;
  if (end > N) end = N;
  float s = 0.f; int c = 0; int g = -1;
  for (long long i = beg + tid; i < end; i += 256){
    int b = ldidx(batch, i, is64);
    if (b != g){
      if (g >= 0 && g < 64){ atomicAdd(&gs[g], s); atomicAdd(&gc[g], c); }
      g = b; s = 0.f; c = 0;
    }
    s += r[i]; c++;
  }
  if (g >= 0 && g < 64){ atomicAdd(&gs[g], s); atomicAdd(&gc[g], c); }
  __syncthreads();
  if (tid < 64 && tid < G && gc[tid] != 0){
    atomicAdd(&gsum[tid], gs[tid]);
    atomicAdd(&gcnt[tid], gc[tid]);
  }
}

__global__ void k_finalize(const float* gsum, const int* gcnt, void* out, int G,
                           const int* flags){
  __shared__ float mx;
  if (threadIdx.x == 0){
    float m = 0.f;
    for (int g = 0; g < G; g++){
      float a = gsum[g]; if (a < 0.f) a = -a;
      if (a > m) m = a;
    }
    mx = m;
  }
  __syncthreads();
  int g = threadIdx.x;
  if (g >= G) return;
  float c = (float)gcnt[g];
  if (c < 1.f) c = 1.f;
  float val = (mx > 0.f) ? (gsum[g] / c) : 30000.f;
  if (flags[1]) ((bf16*)out)[g] = __float2bfloat16(val);
  else          ((float*)out)[g] = val;
}

// ---- launch ----------------------------------------------------------------

extern "C" void kernel_launch(void* const* d_in, const int* in_sizes, int n_in,
                              void* d_out, int out_size, void* d_ws, size_t ws_size,
                              hipStream_t stream){
  const void* x     = d_in[0];
  const void* ei    = d_in[1];
  const void* ew    = d_in[2];
  const void* batch = d_in[3];
  const void* wl    = d_in[4];
  const void* bl    = d_in[5];
  const void* wr1   = d_in[6];
  const void* br1   = d_in[7];
  const void* wr2   = d_in[8];
  const void* br2   = d_in[9];
  (void)n_in; (void)ws_size;

  int N = in_sizes[3];
  int E = in_sizes[2];
  int G = out_size;

  // shift=10: 1024-node buckets -> long per-(bucket,block) scatter runs.
  // (1024 also exactly matches the LDS array sizes in k_deg_acc / k_csr.)
  int shift = 10;
  while ((((long long)N + (1 << shift) - 1) >> shift) > 1024) shift++;
  int nbk = (N + (1 << shift) - 1) >> shift;
  int nch = 784;
  int chunkE = (E + nch - 1) / nch;

  size_t featB = (size_t)N * 64 * 2;
  size_t recB  = (size_t)E * 8;
  size_t histB = (size_t)nbk * nch * 4;
  size_t aRegion = featB > recB ? featB : recB;
  size_t bRegion = featB > recB ? featB : recB;     // B also hosts rec_s
  size_t cRegion = featB > histB ? featB : histB;   // C also hosts hist_s

  char* p = (char*)d_ws;
  int* flags  = (int*)p;                p += 256;
  float* wfs  = (float*)p;              p += (2560*4 + 255) / 256 * 256;
  bf16* Wtb   = (bf16*)p;               p += (49152*2 + 255) / 256 * 256;
  int* hist_t = (int*)p;                p += ((histB + 255) / 256) * 256;
  int* btot   = (int*)p;                p += 8192;   // [0,nbk) t | [nbk,2nbk) s
  int* bbase  = (int*)p;                p += 8192;
  int* rowptr = (int*)p;                p += (((size_t)(N+1)*4 + 255) / 256) * 256;
  float* dis  = (float*)p;              p += (((size_t)N*4 + 255) / 256) * 256;
  float* gsum = (float*)p;              p += 1024;
  int* gcnt   = (int*)p;                p += 1024;
  float* rnode= (float*)p;              p += (((size_t)N*4 + 255) / 256) * 256;
  char* aReg  = p;                      p += ((aRegion + 255) / 256) * 256;
  bf16* B     = (bf16*)p;               p += ((bRegion + 255) / 256) * 256;
  bf16* C     = (bf16*)p;               p += ((cRegion + 255) / 256) * 256;
  int2* edges = (int2*)p;               p += ((recB + 255) / 256) * 256;

  bf16* A = (bf16*)aReg;
  int2* rec_t = (int2*)aReg;            // consumed by k_csr before A is written
  int2* rec_s = (int2*)B;               // consumed by k_deg_acc before B is written
  int* hist_s = (int*)C;                // consumed by k_scatter2 before C is written
  int* btot_s  = btot  + nbk;
  int* bbase_s = bbase + nbk;

  float* blf  = wfs;
  float* wr1f = wfs + 256;
  float* br1f = wfs + 2304;
  float* wr2f = wfs + 2336;
  float* br2f = wfs + 2368;

  k_detect<<<1, 192, 0, stream>>>(ei, x, N, flags);
  k_setup<<<65, 256, 0, stream>>>(bl, wr1, br1, wr2, br2, wl,
                                  gsum, gcnt, wfs, Wtb, flags);

  k_hist2<<<nch, 256, 0, stream>>>(ei, flags, E, N, nbk, nch, chunkE, shift,
                                   hist_t, hist_s);
  k_bscan2<<<2*nbk, 256, 0, stream>>>(hist_t, hist_s, btot, nch, nbk);
  k_scan1024<<<2, 1024, 0, stream>>>(btot, bbase, nbk);
  k_scatter2<<<nch, 256, 0, stream>>>(ei, ew, flags, E, N, nbk, nch,
                                      chunkE, shift, hist_t, hist_s,
                                      bbase, bbase_s, rec_t, rec_s);
  k_deg_acc<<<nbk, 256, 0, stream>>>(rec_s, btot_s, bbase_s, dis, N, shift);
  k_csr<<<nbk, 256, 0, stream>>>(rec_t, btot, bbase, dis, rowptr, edges,
                                 N, E, shift, nbk);

  k_x2a<<<(N*64 + 255)/256, 256, 0, stream>>>(x, A, N*64, flags);

  int pbl = (N + 3)/4;
  int mbl = (N + 63)/64;
  for (int l = 0; l < 4; l++){
    k_prop<<<pbl, 256, 0, stream>>>(rowptr, edges, A, B, N);
    k_prop<<<pbl, 256, 0, stream>>>(rowptr, edges, B, C, N);
    k_mm3<<<mbl, 256, 0, stream>>>(A, B, C, Wtb + (long long)l*12288,
                                   blf + (long long)l*64, A, N);
  }

  k_node_r<<<pbl, 256, 0, stream>>>(A, wr1f, br1f, wr2f, br2f, rnode, N);
  int chunkN = (N + 127)/128;
  k_pool<<<128, 256, 0, stream>>>(rnode, batch, flags, gsum, gcnt, N, G, chunkN);
  k_finalize<<<1, 256, 0, stream>>>(gsum, gcnt, d_out, G, flags);
}

// Round 7
// 701.999 us; speedup vs baseline: 1.1405x; 1.1405x over previous
//

#include <hip/hip_runtime.h>
#include <hip/hip_bf16.h>

// Round 22: revert k_prop to R19 (R21's masked-8 + nontemporal regressed:
// 43->60us via intra-wave divergence between masked-4/masked-8 paths, dup
// gather issue traffic, and nt hints killing L2 retention). k_prop's 84MB
// FETCH matches the compulsory-miss floor (each XCD reads ~86% of the 12.8MB
// feature matrix; random graph, 8 private L2s) at ~2TB/s L2-fill -- little
// left in the kernel itself. New lever: fuse the second prop of each layer
// (C = prop(B), consumed only by mm3) INTO mm3 as k_pm3 -- mm3's 64-node
// tile owns a contiguous CSR edge range, so each 16-lane group gathers
// prop(B) rows straight into the LDS c=2 slot. Saves 4 launches + C's
// 12.5MB write + 12.8MB read per layer (~100MB round-trip total).

typedef __hip_bfloat16 bf16;
typedef short short8 __attribute__((ext_vector_type(8)));
typedef float floatx4 __attribute__((ext_vector_type(4)));

static __device__ float bf2f(bf16 v){ return __bfloat162float(v); }

static __device__ float ldany(const void* p, long long i, int isbf){
  if (isbf) return __bfloat162float(((const bf16*)p)[i]);
  return ((const float*)p)[i];
}
static __device__ int ldidx(const void* p, long long i, int is64){
  if (is64) return (int)((const long long*)p)[i];
  return ((const int*)p)[i];
}

// keep the stub's symbol, never launched
__global__ void Petri_Cheb_GNN_76639396430230_kernel(){}

// ---- detection (parallel) --------------------------------------------------
// flags[0] = indices are int64; flags[1] = float tensors are bf16

__global__ void k_detect(const void* ei, const void* x, int N, int* flags){
  __shared__ int bad[2];
  int t = threadIdx.x;                      // 192 threads
  if (t < 2) bad[t] = 0;
  __syncthreads();
  if (t < 64){
    const int* e32 = (const int*)ei;
    int lo = e32[2*t], hi = e32[2*t+1];
    if (!(hi == 0 && lo >= 0 && lo < N)) atomicAdd(&bad[0], 1);
  } else {
    int i = t - 64;                         // 0..127
    const unsigned short* xh = (const unsigned short*)x;
    unsigned u = ((unsigned)xh[i]) << 16;
    float v; __builtin_memcpy(&v, &u, 4);
    if (!(v == v) || fabsf(v) > 64.f) atomicAdd(&bad[1], 1);
  }
  __syncthreads();
  if (t == 0){ flags[0] = bad[0] ? 0 : 1; flags[1] = bad[1] ? 0 : 1; }
}

// ---- fused setup: gsum/gcnt zero + small cvts | wprep ----------------------
// wfs layout: [0,256) bl | [256,2304) wr1 | [2304,2336) br1 |
//             [2336,2368) wr2 | [2368] br2

__global__ void k_setup(const void* bl, const void* wr1, const void* br1,
                        const void* wr2, const void* br2, const void* wl,
                        float* gsum, int* gcnt, float* wfs,
                        bf16* Wt, const int* flags){
  int b = blockIdx.x;
  int tid = threadIdx.x;
  if (b == 0){
    if (tid < 64){ gsum[tid] = 0.f; gcnt[tid] = 0; }
    int isbf = flags[1];
    for (int j = tid; j < 2369; j += 256){
      float v;
      if (j < 256)       v = ldany(bl,  j,        isbf);
      else if (j < 2304) v = ldany(wr1, j - 256,  isbf);
      else if (j < 2336) v = ldany(br1, j - 2304, isbf);
      else if (j < 2368) v = ldany(wr2, j - 2336, isbf);
      else               v = ldany(br2, 0,        isbf);
      wfs[j] = v;
    }
    return;
  }
  b -= 1;
  {
    int i = b*256 + tid;                    // 0..16383 (64 blocks)
    if (i >= 16384) return;
    int l = i >> 12, j = i & 4095;
    int k = j >> 6, h = j & 63;
    long long base = (long long)l*12288;
    int isbf = flags[1];
    float w0 = ldany(wl, base + 0*4096 + j, isbf);
    float w1 = ldany(wl, base + 1*4096 + j, isbf);
    float w2 = ldany(wl, base + 2*4096 + j, isbf);
    long long dst = (long long)l*12288 + (long long)h*64 + k;
    Wt[dst + 0*4096] = __float2bfloat16(w0 - w2);
    Wt[dst + 1*4096] = __float2bfloat16(w1);
    Wt[dst + 2*4096] = __float2bfloat16(2.f * w2);
  }
}

__global__ void k_x2a(const void* x, bf16* a, int n, const int* flags){
  int i = blockIdx.x*256 + threadIdx.x;
  if (i < n) a[i] = __float2bfloat16(ldany(x, i, flags[1]));
}

// ---- dual bucket histogram (s and t) — LDS atomics only --------------------

__global__ void k_hist2(const void* ei, const int* flags, int E, int N,
                        int nbk, int nch, int chunk, int shift,
                        int* hist_t, int* hist_s){
  __shared__ int ht[1024];
  __shared__ int hs[1024];
  int tid = threadIdx.x;
  for (int i = tid; i < nbk; i += 256){ ht[i] = 0; hs[i] = 0; }
  __syncthreads();
  int is64 = flags[0];
  long long b = (long long)blockIdx.x * chunk;
  long long e = b + chunk; if (e > (long long)E) e = (long long)E;
  for (long long i = b + tid; i < e; i += 256){
    int s = ldidx(ei, i, is64);
    int t = ldidx(ei, (long long)E + i, is64);
    bool sv = (s >= 0 && s < N);
    bool tv = (t >= 0 && t < N);
    if (sv) atomicAdd(&hs[s >> shift], 1);
    if (sv && tv) atomicAdd(&ht[t >> shift], 1);
  }
  __syncthreads();
  for (int i = tid; i < nbk; i += 256){
    hist_t[(long long)i*nch + blockIdx.x] = ht[i];
    hist_s[(long long)i*nch + blockIdx.x] = hs[i];
  }
}

// ---- bucket scans (t rows then s rows in one launch) -----------------------

__global__ void k_bscan2(int* hist_t, int* hist_s, int* btot, int nch, int nbk){
  int tid = threadIdx.x;
  int bk  = blockIdx.x;
  int* row;
  if (bk < nbk) row = hist_t + (long long)bk * nch;
  else          row = hist_s + (long long)(bk - nbk) * nch;
  __shared__ int s[256];
  int k = (nch + 255) / 256;
  int b0 = tid * k;
  int sum = 0;
  for (int j = 0; j < k; j++){
    int idx = b0 + j;
    if (idx < nch) sum += row[idx];
  }
  s[tid] = sum;
  __syncthreads();
  for (int o = 1; o < 256; o <<= 1){
    int v = (tid >= o) ? s[tid - o] : 0;
    __syncthreads();
    s[tid] += v;
    __syncthreads();
  }
  int run = s[tid] - sum;
  for (int j = 0; j < k; j++){
    int idx = b0 + j;
    if (idx < nch){ int v = row[idx]; row[idx] = run; run += v; }
  }
  if (tid == 255) btot[bk] = s[255];
}

__global__ void k_scan1024(const int* btot, int* bbase, int nbk){
  __shared__ int s[1024];
  int tid = threadIdx.x;
  int off = blockIdx.x * nbk;
  int v = (tid < nbk) ? btot[off + tid] : 0;
  s[tid] = v;
  __syncthreads();
  for (int o = 1; o < 1024; o <<= 1){
    int u = (tid >= o) ? s[tid - o] : 0;
    __syncthreads();
    s[tid] += u;
    __syncthreads();
  }
  if (tid < nbk) bbase[off + tid] = s[tid] - v;
}

// ---- dual scatter: t-records (s | t_local<<20, raw w) + s-records ----------

__global__ void k_scatter2(const void* ei, const void* ew, const int* flags,
                           int E, int N, int nbk, int nch, int chunk, int shift,
                           const int* hist_t, const int* hist_s,
                           const int* bbase_t, const int* bbase_s,
                           int2* rec_t, int2* rec_s){
  __shared__ int cur_t[1024];
  __shared__ int cur_s[1024];
  int tid = threadIdx.x;
  for (int i = tid; i < nbk; i += 256){
    cur_t[i] = bbase_t[i] + hist_t[(long long)i*nch + blockIdx.x];
    cur_s[i] = bbase_s[i] + hist_s[(long long)i*nch + blockIdx.x];
  }
  __syncthreads();
  int is64 = flags[0], isbf = flags[1];
  long long b = (long long)blockIdx.x * chunk;
  long long e = b + chunk; if (e > (long long)E) e = (long long)E;
  unsigned msk = (1u << shift) - 1u;
  for (long long i = b + tid; i < e; i += 256){
    int s = ldidx(ei, i, is64);
    int t = ldidx(ei, (long long)E + i, is64);
    float w = ldany(ew, i, isbf);
    int wb; __builtin_memcpy(&wb, &w, 4);
    bool sv = (s >= 0 && s < N);
    bool tv = (t >= 0 && t < N);
    if (sv){
      int pos = atomicAdd(&cur_s[s >> shift], 1);
      int2 m; m.x = (int)(s & (int)msk); m.y = wb;
      rec_s[pos] = m;
    }
    if (sv && tv){
      int pos = atomicAdd(&cur_t[t >> shift], 1);
      int2 m; m.x = s | (((int)(t & msk)) << 20); m.y = wb;
      rec_t[pos] = m;
    }
  }
}

// ---- per-bucket degree accumulate -> dis (no global atomics) ---------------

__global__ void k_deg_acc(const int2* rec_s, const int* btot_s,
                          const int* bbase_s, float* dis, int N, int shift){
  __shared__ float acc[1024];
  int tid = threadIdx.x;
  int bk  = blockIdx.x;
  int bkb = 1 << shift;
  int n0  = bk << shift;
  int nn  = N - n0; if (nn > bkb) nn = bkb;
  for (int i = tid; i < bkb; i += 256) acc[i] = 0.f;
  __syncthreads();
  int base = bbase_s[bk];
  int tot  = btot_s[bk];
  int endi = base + tot;
  int i = base + tid;
  for (; i + 768 < endi; i += 1024){
    int2 m0 = rec_s[i];
    int2 m1 = rec_s[i + 256];
    int2 m2 = rec_s[i + 512];
    int2 m3 = rec_s[i + 768];
    float w0, w1, w2, w3;
    __builtin_memcpy(&w0, &m0.y, 4);
    __builtin_memcpy(&w1, &m1.y, 4);
    __builtin_memcpy(&w2, &m2.y, 4);
    __builtin_memcpy(&w3, &m3.y, 4);
    atomicAdd(&acc[m0.x], w0);
    atomicAdd(&acc[m1.x], w1);
    atomicAdd(&acc[m2.x], w2);
    atomicAdd(&acc[m3.x], w3);
  }
  for (; i < endi; i += 256){
    int2 m = rec_s[i];
    float w; __builtin_memcpy(&w, &m.y, 4);
    atomicAdd(&acc[m.x], w);
  }
  __syncthreads();
  for (int j = tid; j < nn; j += 256){
    float d = acc[j];
    dis[n0 + j] = (d > 0.f) ? rsqrtf(d) : 0.f;
  }
}

// ---- CSR build (+ fused -dis[s]*w*dis[t] weight normalize) -----------------

__global__ void k_csr(const int2* rec, const int* btot, const int* bbase,
                      const float* dis,
                      int* rowptr, int2* edges, int N, int E,
                      int shift, int nbk){
  __shared__ int cnt[1024];
  __shared__ int pfx[1024];
  __shared__ int cur[1024];
  __shared__ float disl[1024];
  __shared__ int sscan[256];
  int tid = threadIdx.x;
  int bk  = blockIdx.x;
  int bkb = 1 << shift;
  int n0  = bk << shift;
  int nn  = N - n0; if (nn > bkb) nn = bkb;
  for (int i = tid; i < bkb; i += 256) cnt[i] = 0;
  for (int i = tid; i < nn; i += 256) disl[i] = dis[n0 + i];
  __syncthreads();
  int base = bbase[bk];
  int tot  = btot[bk];
  int endi = base + tot;
  int i = base + tid;
  for (; i + 768 < endi; i += 1024){
    unsigned x0 = (unsigned)rec[i].x;
    unsigned x1 = (unsigned)rec[i + 256].x;
    unsigned x2 = (unsigned)rec[i + 512].x;
    unsigned x3 = (unsigned)rec[i + 768].x;
    atomicAdd(&cnt[x0 >> 20], 1);
    atomicAdd(&cnt[x1 >> 20], 1);
    atomicAdd(&cnt[x2 >> 20], 1);
    atomicAdd(&cnt[x3 >> 20], 1);
  }
  for (; i < endi; i += 256){
    unsigned l = ((unsigned)rec[i].x) >> 20;
    atomicAdd(&cnt[l], 1);
  }
  __syncthreads();
  // parallel exclusive scan of cnt[0..bkb)
  {
    int kk = (bkb + 255) >> 8;
    int b0 = tid * kk;
    int sum = 0;
    for (int j = 0; j < kk; j++){
      int idx = b0 + j;
      if (idx < bkb) sum += cnt[idx];
    }
    sscan[tid] = sum;
    __syncthreads();
    for (int o = 1; o < 256; o <<= 1){
      int v = (tid >= o) ? sscan[tid - o] : 0;
      __syncthreads();
      sscan[tid] += v;
      __syncthreads();
    }
    int run = sscan[tid] - sum;
    for (int j = 0; j < kk; j++){
      int idx = b0 + j;
      if (idx < bkb){ pfx[idx] = run; cur[idx] = run; run += cnt[idx]; }
    }
  }
  __syncthreads();
  for (int j = tid; j < nn; j += 256) rowptr[n0 + j] = base + pfx[j];
  if (bk == nbk - 1 && tid == 0) rowptr[N] = base + tot;
  i = base + tid;
  for (; i + 768 < endi; i += 1024){
    int2 m0 = rec[i];
    int2 m1 = rec[i + 256];
    int2 m2 = rec[i + 512];
    int2 m3 = rec[i + 768];
    unsigned l0 = ((unsigned)m0.x) >> 20; int s0 = m0.x & 0xFFFFF;
    unsigned l1 = ((unsigned)m1.x) >> 20; int s1 = m1.x & 0xFFFFF;
    unsigned l2 = ((unsigned)m2.x) >> 20; int s2 = m2.x & 0xFFFFF;
    unsigned l3 = ((unsigned)m3.x) >> 20; int s3 = m3.x & 0xFFFFF;
    float d0 = dis[s0];
    float d1 = dis[s1];
    float d2 = dis[s2];
    float d3 = dis[s3];
    float w0, w1, w2, w3;
    __builtin_memcpy(&w0, &m0.y, 4);
    __builtin_memcpy(&w1, &m1.y, 4);
    __builtin_memcpy(&w2, &m2.y, 4);
    __builtin_memcpy(&w3, &m3.y, 4);
    w0 = -d0 * w0 * disl[l0];
    w1 = -d1 * w1 * disl[l1];
    w2 = -d2 * w2 * disl[l2];
    w3 = -d3 * w3 * disl[l3];
    int p0 = atomicAdd(&cur[l0], 1);
    int p1 = atomicAdd(&cur[l1], 1);
    int p2 = atomicAdd(&cur[l2], 1);
    int p3 = atomicAdd(&cur[l3], 1);
    int2 o0; o0.x = s0; __builtin_memcpy(&o0.y, &w0, 4);
    int2 o1; o1.x = s1; __builtin_memcpy(&o1.y, &w1, 4);
    int2 o2; o2.x = s2; __builtin_memcpy(&o2.y, &w2, 4);
    int2 o3; o3.x = s3; __builtin_memcpy(&o3.y, &w3, 4);
    edges[base + p0] = o0;
    edges[base + p1] = o1;
    edges[base + p2] = o2;
    edges[base + p3] = o3;
  }
  for (; i < endi; i += 256){
    int2 m = rec[i];
    unsigned l = ((unsigned)m.x) >> 20;
    int s = m.x & 0xFFFFF;
    float w; __builtin_memcpy(&w, &m.y, 4);
    w = -dis[s] * w * disl[l];
    int pos = atomicAdd(&cur[l], 1);
    int2 o; o.x = s; __builtin_memcpy(&o.y, &w, 4);
    edges[base + pos] = o;
  }
}

// ---- propagation (R19 proven form: 4-way unroll + masked quad tail) --------

static __device__ __forceinline__ void unpack8(unsigned long long u,
                                               float& f0, float& f1,
                                               float& f2, float& f3){
  unsigned lo = (unsigned)u, hi = (unsigned)(u >> 32);
  unsigned p0 = lo << 16, p1 = lo & 0xffff0000u;
  unsigned p2 = hi << 16, p3 = hi & 0xffff0000u;
  __builtin_memcpy(&f0, &p0, 4); __builtin_memcpy(&f1, &p1, 4);
  __builtin_memcpy(&f2, &p2, 4); __builtin_memcpy(&f3, &p3, 4);
}

__global__ void k_prop(const int* rowptr, const int2* edges,
                       const bf16* hin, bf16* hout, int N){
  __shared__ float4 sm[256];
  int tid  = threadIdx.x;
  int v    = blockIdx.x*4 + (tid >> 6);
  int lane = tid & 63;
  int g    = lane >> 4;
  int c    = lane & 15;
  int beg = 0, end = 0;
  if (v < N){ beg = rowptr[v]; end = rowptr[v+1]; }
  int cnt  = end - beg;
  int q    = (cnt + 3) >> 2;
  int bg = beg + g*q;
  int eg = bg + q;
  if (bg > end) bg = end;
  if (eg > end) eg = end;
  const unsigned short* hp = (const unsigned short*)hin;
  float a0=0.f,a1=0.f,a2=0.f,a3=0.f;
  float b0=0.f,b1=0.f,b2=0.f,b3=0.f;
  float c0=0.f,c1=0.f,c2=0.f,c3=0.f;
  float d0=0.f,d1=0.f,d2=0.f,d3=0.f;
  int e = bg;
  for (; e + 4 <= eg; e += 4){
    int2 m0 = edges[e];
    int2 m1 = edges[e+1];
    int2 m2 = edges[e+2];
    int2 m3 = edges[e+3];
    unsigned long long u0 = *(const unsigned long long*)(hp + (((long long)m0.x) << 6) + 4*c);
    unsigned long long u1 = *(const unsigned long long*)(hp + (((long long)m1.x) << 6) + 4*c);
    unsigned long long u2 = *(const unsigned long long*)(hp + (((long long)m2.x) << 6) + 4*c);
    unsigned long long u3 = *(const unsigned long long*)(hp + (((long long)m3.x) << 6) + 4*c);
    float w0, w1, w2, w3;
    __builtin_memcpy(&w0, &m0.y, 4);
    __builtin_memcpy(&w1, &m1.y, 4);
    __builtin_memcpy(&w2, &m2.y, 4);
    __builtin_memcpy(&w3, &m3.y, 4);
    float f0,f1,f2,f3;
    unpack8(u0, f0,f1,f2,f3);
    a0 = fmaf(w0,f0,a0); a1 = fmaf(w0,f1,a1);
    a2 = fmaf(w0,f2,a2); a3 = fmaf(w0,f3,a3);
    unpack8(u1, f0,f1,f2,f3);
    b0 = fmaf(w1,f0,b0); b1 = fmaf(w1,f1,b1);
    b2 = fmaf(w1,f2,b2); b3 = fmaf(w1,f3,b3);
    unpack8(u2, f0,f1,f2,f3);
    c0 = fmaf(w2,f0,c0); c1 = fmaf(w2,f1,c1);
    c2 = fmaf(w2,f2,c2); c3 = fmaf(w2,f3,c3);
    unpack8(u3, f0,f1,f2,f3);
    d0 = fmaf(w3,f0,d0); d1 = fmaf(w3,f1,d1);
    d2 = fmaf(w3,f2,d2); d3 = fmaf(w3,f3,d3);
  }
  if (e < eg){
    // masked quad: clamp indices, zero invalid weights; all 4 gathers issue.
    int e1 = (e+1 < eg) ? e+1 : e;
    int e2 = (e+2 < eg) ? e+2 : e;
    int e3 = (e+3 < eg) ? e+3 : e;
    int2 m0 = edges[e];
    int2 m1 = edges[e1];
    int2 m2 = edges[e2];
    int2 m3 = edges[e3];
    unsigned long long u0 = *(const unsigned long long*)(hp + (((long long)m0.x) << 6) + 4*c);
    unsigned long long u1 = *(const unsigned long long*)(hp + (((long long)m1.x) << 6) + 4*c);
    unsigned long long u2 = *(const unsigned long long*)(hp + (((long long)m2.x) << 6) + 4*c);
    unsigned long long u3 = *(const unsigned long long*)(hp + (((long long)m3.x) << 6) + 4*c);
    float w0, w1, w2, w3;
    __builtin_memcpy(&w0, &m0.y, 4);
    __builtin_memcpy(&w1, &m1.y, 4);
    __builtin_memcpy(&w2, &m2.y, 4);
    __builtin_memcpy(&w3, &m3.y, 4);
    if (e+1 >= eg) w1 = 0.f;
    if (e+2 >= eg) w2 = 0.f;
    if (e+3 >= eg) w3 = 0.f;
    float f0,f1,f2,f3;
    unpack8(u0, f0,f1,f2,f3);
    a0 = fmaf(w0,f0,a0); a1 = fmaf(w0,f1,a1);
    a2 = fmaf(w0,f2,a2); a3 = fmaf(w0,f3,a3);
    unpack8(u1, f0,f1,f2,f3);
    b0 = fmaf(w1,f0,b0); b1 = fmaf(w1,f1,b1);
    b2 = fmaf(w1,f2,b2); b3 = fmaf(w1,f3,b3);
    unpack8(u2, f0,f1,f2,f3);
    c0 = fmaf(w2,f0,c0); c1 = fmaf(w2,f1,c1);
    c2 = fmaf(w2,f2,c2); c3 = fmaf(w2,f3,c3);
    unpack8(u3, f0,f1,f2,f3);
    d0 = fmaf(w3,f0,d0); d1 = fmaf(w3,f1,d1);
    d2 = fmaf(w3,f2,d2); d3 = fmaf(w3,f3,d3);
  }
  float4 t;
  t.x = (a0 + b0) + (c0 + d0);
  t.y = (a1 + b1) + (c1 + d1);
  t.z = (a2 + b2) + (c2 + d2);
  t.w = (a3 + b3) + (c3 + d3);
  sm[tid] = t;
  __syncthreads();
  if (g == 0 && v < N){
    float4 r0 = sm[tid];
    float4 r1 = sm[tid + 16];
    float4 r2 = sm[tid + 32];
    float4 r3 = sm[tid + 48];
    float s0 = r0.x + r1.x + r2.x + r3.x;
    float s1 = r0.y + r1.y + r2.y + r3.y;
    float s2 = r0.z + r1.z + r2.z + r3.z;
    float s3 = r0.w + r1.w + r2.w + r3.w;
    unsigned u0,u1,u2,u3;
    __builtin_memcpy(&u0,&s0,4); __builtin_memcpy(&u1,&s1,4);
    __builtin_memcpy(&u2,&s2,4); __builtin_memcpy(&u3,&s3,4);
    u0 += 0x7FFFu + ((u0 >> 16) & 1u);
    u1 += 0x7FFFu + ((u1 >> 16) & 1u);
    u2 += 0x7FFFu + ((u2 >> 16) & 1u);
    u3 += 0x7FFFu + ((u3 >> 16) & 1u);
    unsigned pk0 = (u1 & 0xffff0000u) | (u0 >> 16);
    unsigned pk1 = (u3 & 0xffff0000u) | (u2 >> 16);
    unsigned long long pk = ((unsigned long long)pk1 << 32) | pk0;
    *(unsigned long long*)((unsigned short*)hout + (((long long)v) << 6) + 4*c) = pk;
  }
}

// ---- fused prop2 + 3-matmul: gather T2=prop(T1) into LDS, then MFMA --------
// Tile nodes n0..n0+63 have contiguous CSR edge ranges (bucket order == node
// order), so each 16-lane group gathers prop(B) for 4 nodes straight into the
// c=2 slot of Alds. Kills the separate C prop (launch + 12.5MB write + 12.8MB
// read per layer).

__global__ void k_pm3(const bf16* T0, const bf16* T1, const int* rowptr,
                      const int2* edges, const bf16* Wt, const float* bias,
                      bf16* out, int N){
  __shared__ __align__(16) unsigned short Alds[64*200];
  __shared__ __align__(16) unsigned short Wlds[64*200];
  int tid = threadIdx.x;
  int n0 = blockIdx.x * 64;
  // stage W (c=0..2): 1536 chunks
  for (int j = 0; j < 6; j++){
    int chunk = tid + j*256;
    int row    = chunk / 24;
    int within = chunk % 24;
    int cc = within >> 3;
    int q  = within & 7;
    uint4 wv = ((const uint4*)(Wt + cc*4096 + row*64))[q];
    *(uint4*)&Wlds[row*200 + cc*64 + q*8] = wv;
  }
  // stage A-side: T0 -> c=0 slot, T1 -> c=1 slot (1024 chunks)
  for (int j = 0; j < 4; j++){
    int chunk = tid + j*256;
    int row    = chunk >> 4;
    int within = chunk & 15;
    int cc = within >> 3;
    int q  = within & 7;
    const bf16* Tm = (cc == 0) ? T0 : T1;
    int node = n0 + row;
    uint4 av;
    if (node < N) av = ((const uint4*)(Tm + (long long)node*64))[q];
    else { av.x = 0; av.y = 0; av.z = 0; av.w = 0; }
    *(uint4*)&Alds[row*200 + cc*64 + q*8] = av;
  }
  // gather phase: T2 rows = prop(T1) -> c=2 slot. group owns 4 nodes.
  {
    int group = tid >> 4;      // 0..15
    int c     = tid & 15;      // feature quad 4c..4c+3
    const unsigned short* hp = (const unsigned short*)T1;
    for (int i = 0; i < 4; i++){
      int row = group*4 + i;
      int v = n0 + row;
      float A0=0.f,A1=0.f,A2=0.f,A3=0.f;
      float B0=0.f,B1=0.f,B2=0.f,B3=0.f;
      if (v < N){
        int beg = rowptr[v], end = rowptr[v+1];
        for (int e = beg; e < end; e += 4){
          int i1 = (e+1 < end) ? e+1 : e;
          int i2 = (e+2 < end) ? e+2 : e;
          int i3 = (e+3 < end) ? e+3 : e;
          int2 m0 = edges[e];
          int2 m1 = edges[i1];
          int2 m2 = edges[i2];
          int2 m3 = edges[i3];
          unsigned long long u0 = *(const unsigned long long*)(hp + (((long long)m0.x) << 6) + 4*c);
          unsigned long long u1 = *(const unsigned long long*)(hp + (((long long)m1.x) << 6) + 4*c);
          unsigned long long u2 = *(const unsigned long long*)(hp + (((long long)m2.x) << 6) + 4*c);
          unsigned long long u3 = *(const unsigned long long*)(hp + (((long long)m3.x) << 6) + 4*c);
          float w0, w1, w2, w3;
          __builtin_memcpy(&w0, &m0.y, 4);
          __builtin_memcpy(&w1, &m1.y, 4);
          __builtin_memcpy(&w2, &m2.y, 4);
          __builtin_memcpy(&w3, &m3.y, 4);
          if (e+1 >= end) w1 = 0.f;
          if (e+2 >= end) w2 = 0.f;
          if (e+3 >= end) w3 = 0.f;
          float f0,f1,f2,f3;
          unpack8(u0, f0,f1,f2,f3);
          A0 = fmaf(w0,f0,A0); A1 = fmaf(w0,f1,A1);
          A2 = fmaf(w0,f2,A2); A3 = fmaf(w0,f3,A3);
          unpack8(u1, f0,f1,f2,f3);
          B0 = fmaf(w1,f0,B0); B1 = fmaf(w1,f1,B1);
          B2 = fmaf(w1,f2,B2); B3 = fmaf(w1,f3,B3);
          unpack8(u2, f0,f1,f2,f3);
          A0 = fmaf(w2,f0,A0); A1 = fmaf(w2,f1,A1);
          A2 = fmaf(w2,f2,A2); A3 = fmaf(w2,f3,A3);
          unpack8(u3, f0,f1,f2,f3);
          B0 = fmaf(w3,f0,B0); B1 = fmaf(w3,f1,B1);
          B2 = fmaf(w3,f2,B2); B3 = fmaf(w3,f3,B3);
        }
      }
      float s0 = A0 + B0;
      float s1 = A1 + B1;
      float s2 = A2 + B2;
      float s3 = A3 + B3;
      unsigned u0,u1,u2,u3;
      __builtin_memcpy(&u0,&s0,4); __builtin_memcpy(&u1,&s1,4);
      __builtin_memcpy(&u2,&s2,4); __builtin_memcpy(&u3,&s3,4);
      u0 += 0x7FFFu + ((u0 >> 16) & 1u);
      u1 += 0x7FFFu + ((u1 >> 16) & 1u);
      u2 += 0x7FFFu + ((u2 >> 16) & 1u);
      u3 += 0x7FFFu + ((u3 >> 16) & 1u);
      unsigned pk0 = (u1 & 0xffff0000u) | (u0 >> 16);
      unsigned pk1 = (u3 & 0xffff0000u) | (u2 >> 16);
      unsigned long long pk = ((unsigned long long)pk1 << 32) | pk0;
      *(unsigned long long*)&Alds[row*200 + 128 + 4*c] = pk;
    }
  }
  __syncthreads();
  int w    = tid >> 6;
  int lane = tid & 63;
  int m    = lane & 15;
  int quad = lane >> 4;
  int arow = w*16 + m;
  floatx4 acc0 = {0.f,0.f,0.f,0.f};
  floatx4 acc1 = {0.f,0.f,0.f,0.f};
  floatx4 acc2 = {0.f,0.f,0.f,0.f};
  floatx4 acc3 = {0.f,0.f,0.f,0.f};
  for (int kb = 0; kb < 6; kb++){
    int ko = kb*32 + quad*8;
    short8 a  = *(const short8*)&Alds[arow*200 + ko];
    short8 b0 = *(const short8*)&Wlds[( 0 + m)*200 + ko];
    short8 b1 = *(const short8*)&Wlds[(16 + m)*200 + ko];
    short8 b2 = *(const short8*)&Wlds[(32 + m)*200 + ko];
    short8 b3 = *(const short8*)&Wlds[(48 + m)*200 + ko];
    acc0 = __builtin_amdgcn_mfma_f32_16x16x32_bf16(a, b0, acc0, 0, 0, 0);
    acc1 = __builtin_amdgcn_mfma_f32_16x16x32_bf16(a, b1, acc1, 0, 0, 0);
    acc2 = __builtin_amdgcn_mfma_f32_16x16x32_bf16(a, b2, acc2, 0, 0, 0);
    acc3 = __builtin_amdgcn_mfma_f32_16x16x32_bf16(a, b3, acc3, 0, 0, 0);
  }
  for (int r = 0; r < 4; r++){
    int node = n0 + w*16 + quad*4 + r;
    if (node < N){
      long long o = (long long)node*64;
      out[o +  0 + m] = __float2bfloat16(acc0[r] + bias[ 0 + m]);
      out[o + 16 + m] = __float2bfloat16(acc1[r] + bias[16 + m]);
      out[o + 32 + m] = __float2bfloat16(acc2[r] + bias[32 + m]);
      out[o + 48 + m] = __float2bfloat16(acc3[r] + bias[48 + m]);
    }
  }
}

// ---- readout: per-node MLP scalar r[v] -------------------------------------

__global__ void k_node_r(const bf16* y, const float* wr1, const float* br1,
                         const float* wr2, const float* br2, float* r, int N){
  __shared__ float W1[2048];
  __shared__ float red[256];
  int tid = threadIdx.x;
  for (int j = tid; j < 2048; j += 256) W1[j] = wr1[j];
  __syncthreads();
  int v    = blockIdx.x*4 + (tid >> 6);
  int lane = tid & 63;
  int h    = lane & 31;
  int p0   = lane >> 5;
  float acc = 0.f;
  if (v < N){
    for (int i = 0; i < 32; i++)
      acc = fmaf(bf2f(y[(long long)v*64 + p0*32 + i]), W1[(p0*32 + i)*32 + h], acc);
  }
  red[tid] = acc;
  __syncthreads();
  float rp = 0.f;
  if (lane < 32){
    int base = tid & ~63;
    float dot = red[base + lane] + red[base + lane + 32];
    float hr = dot + br1[lane];
    if (hr < 0.f) hr = 0.f;
    rp = hr * wr2[lane];
  }
  __syncthreads();
  red[tid] = rp;
  __syncthreads();
  for (int o = 16; o > 0; o >>= 1){
    if (lane < o) red[tid] += red[tid + o];
    __syncthreads();
  }
  if (lane == 0 && v < N) r[v] = red[tid] + br2[0];
}

// ---- pooling ---------------------------------------------------------------

__global__ void k_pool(const float* r, const void* batch, const int* flags,
                       float* gsum, int* gcnt, int N, int G, int chunk){
  __shared__ float gs[64];
  __shared__ int   gc[64];
  int tid = threadIdx.x;
  if (tid < 64){ gs[tid] = 0.f; gc[tid] = 0; }
  __syncthreads();
  int is64 = flags[0];
  long long beg = (long long)blockIdx.x * chunk;
  long long end = beg + chunk;
  if (end > N) end = N;
  float s = 0.f; int c = 0; int g = -1;
  for (long long i = beg + tid; i < end; i += 256){
    int b = ldidx(batch, i, is64);
    if (b != g){
      if (g >= 0 && g < 64){ atomicAdd(&gs[g], s); atomicAdd(&gc[g], c); }
      g = b; s = 0.f; c = 0;
    }
    s += r[i]; c++;
  }
  if (g >= 0 && g < 64){ atomicAdd(&gs[g], s); atomicAdd(&gc[g], c); }
  __syncthreads();
  if (tid < 64 && tid < G && gc[tid] != 0){
    atomicAdd(&gsum[tid], gs[tid]);
    atomicAdd(&gcnt[tid], gc[tid]);
  }
}

__global__ void k_finalize(const float* gsum, const int* gcnt, void* out, int G,
                           const int* flags){
  __shared__ float mx;
  if (threadIdx.x == 0){
    float m = 0.f;
    for (int g = 0; g < G; g++){
      float a = gsum[g]; if (a < 0.f) a = -a;
      if (a > m) m = a;
    }
    mx = m;
  }
  __syncthreads();
  int g = threadIdx.x;
  if (g >= G) return;
  float c = (float)gcnt[g];
  if (c < 1.f) c = 1.f;
  float val = (mx > 0.f) ? (gsum[g] / c) : 30000.f;
  if (flags[1]) ((bf16*)out)[g] = __float2bfloat16(val);
  else          ((float*)out)[g] = val;
}

// ---- launch ----------------------------------------------------------------

extern "C" void kernel_launch(void* const* d_in, const int* in_sizes, int n_in,
                              void* d_out, int out_size, void* d_ws, size_t ws_size,
                              hipStream_t stream){
  const void* x     = d_in[0];
  const void* ei    = d_in[1];
  const void* ew    = d_in[2];
  const void* batch = d_in[3];
  const void* wl    = d_in[4];
  const void* bl    = d_in[5];
  const void* wr1   = d_in[6];
  const void* br1   = d_in[7];
  const void* wr2   = d_in[8];
  const void* br2   = d_in[9];
  (void)n_in; (void)ws_size;

  int N = in_sizes[3];
  int E = in_sizes[2];
  int G = out_size;

  // shift=10: 1024-node buckets -> long per-(bucket,block) scatter runs.
  // (1024 also exactly matches the LDS array sizes in k_deg_acc / k_csr.)
  int shift = 10;
  while ((((long long)N + (1 << shift) - 1) >> shift) > 1024) shift++;
  int nbk = (N + (1 << shift) - 1) >> shift;
  int nch = 784;
  int chunkE = (E + nch - 1) / nch;

  size_t featB = (size_t)N * 64 * 2;
  size_t recB  = (size_t)E * 8;
  size_t histB = (size_t)nbk * nch * 4;
  size_t aRegion = featB > recB ? featB : recB;
  size_t bRegion = featB > recB ? featB : recB;     // B also hosts rec_s
  size_t cRegion = featB > histB ? featB : histB;   // C also hosts hist_s

  char* p = (char*)d_ws;
  int* flags  = (int*)p;                p += 256;
  float* wfs  = (float*)p;              p += (2560*4 + 255) / 256 * 256;
  bf16* Wtb   = (bf16*)p;               p += (49152*2 + 255) / 256 * 256;
  int* hist_t = (int*)p;                p += ((histB + 255) / 256) * 256;
  int* btot   = (int*)p;                p += 8192;   // [0,nbk) t | [nbk,2nbk) s
  int* bbase  = (int*)p;                p += 8192;
  int* rowptr = (int*)p;                p += (((size_t)(N+1)*4 + 255) / 256) * 256;
  float* dis  = (float*)p;              p += (((size_t)N*4 + 255) / 256) * 256;
  float* gsum = (float*)p;              p += 1024;
  int* gcnt   = (int*)p;                p += 1024;
  float* rnode= (float*)p;              p += (((size_t)N*4 + 255) / 256) * 256;
  char* aReg  = p;                      p += ((aRegion + 255) / 256) * 256;
  bf16* B     = (bf16*)p;               p += ((bRegion + 255) / 256) * 256;
  bf16* C     = (bf16*)p;               p += ((cRegion + 255) / 256) * 256;
  int2* edges = (int2*)p;               p += ((recB + 255) / 256) * 256;

  bf16* A = (bf16*)aReg;
  int2* rec_t = (int2*)aReg;            // consumed by k_csr before A is written
  int2* rec_s = (int2*)B;               // consumed by k_deg_acc before B is written
  int* hist_s = (int*)C;                // consumed by k_scatter2 before C is written
  int* btot_s  = btot  + nbk;
  int* bbase_s = bbase + nbk;

  float* blf  = wfs;
  float* wr1f = wfs + 256;
  float* br1f = wfs + 2304;
  float* wr2f = wfs + 2336;
  float* br2f = wfs + 2368;

  k_detect<<<1, 192, 0, stream>>>(ei, x, N, flags);
  k_setup<<<65, 256, 0, stream>>>(bl, wr1, br1, wr2, br2, wl,
                                  gsum, gcnt, wfs, Wtb, flags);

  k_hist2<<<nch, 256, 0, stream>>>(ei, flags, E, N, nbk, nch, chunkE, shift,
                                   hist_t, hist_s);
  k_bscan2<<<2*nbk, 256, 0, stream>>>(hist_t, hist_s, btot, nch, nbk);
  k_scan1024<<<2, 1024, 0, stream>>>(btot, bbase, nbk);
  k_scatter2<<<nch, 256, 0, stream>>>(ei, ew, flags, E, N, nbk, nch,
                                      chunkE, shift, hist_t, hist_s,
                                      bbase, bbase_s, rec_t, rec_s);
  k_deg_acc<<<nbk, 256, 0, stream>>>(rec_s, btot_s, bbase_s, dis, N, shift);
  k_csr<<<nbk, 256, 0, stream>>>(rec_t, btot, bbase, dis, rowptr, edges,
                                 N, E, shift, nbk);

  k_x2a<<<(N*64 + 255)/256, 256, 0, stream>>>(x, A, N*64, flags);

  int pbl = (N + 3)/4;
  int mbl = (N + 63)/64;
  for (int l = 0; l < 4; l++){
    k_prop<<<pbl, 256, 0, stream>>>(rowptr, edges, A, B, N);
    k_pm3<<<mbl, 256, 0, stream>>>(A, B, rowptr, edges,
                                   Wtb + (long long)l*12288,
                                   blf + (long long)l*64, A, N);
  }

  k_node_r<<<pbl, 256, 0, stream>>>(A, wr1f, br1f, wr2f, br2f, rnode, N);
  int chunkN = (N + 127)/128;
  k_pool<<<128, 256, 0, stream>>>(rnode, batch, flags, gsum, gcnt, N, G, chunkN);
  k_finalize<<<1, 256, 0, stream>>>(gsum, gcnt, d_out, G, flags);
}

// Round 8
// 650.974 us; speedup vs baseline: 1.2299x; 1.0784x over previous
//

#include <hip/hip_runtime.h>
#include <hip/hip_bf16.h>

// Round 23: revert k_pm3 fusion (75.6us vs the ~60 it replaced: 16 serial
// latency rounds per 16-lane group, Occ 22.5% from 51KB LDS, 750k bank
// conflicts). Back to R19's k_prop + k_mm3 (655us). New lever: k_prop is at
// its fill floor (84MB FETCH == compulsory per-XCD distinct-row volume at
// ~2TB/s), but the STREAMING tensors round-trip through L3 because every
// producer/consumer pair uses a different block->node mapping across XCDs.
// Fix: one bijective XCD-chunked swizzle (m204 formula) in k_x2a, k_prop,
// k_mm3, k_node_r (+ k_deg_acc/k_csr), so XCD x owns node range [x*N/8..)
// everywhere. Each XCD's 1.6MB feature slice fits its 4MB L2 -> mm3's 38MB/
// layer T-reads and node_r's 12.8MB read become L2-hits.

typedef __hip_bfloat16 bf16;
typedef short short8 __attribute__((ext_vector_type(8)));
typedef float floatx4 __attribute__((ext_vector_type(4)));

static __device__ float bf2f(bf16 v){ return __bfloat162float(v); }

static __device__ float ldany(const void* p, long long i, int isbf){
  if (isbf) return __bfloat162float(((const bf16*)p)[i]);
  return ((const float*)p)[i];
}
static __device__ int ldidx(const void* p, long long i, int is64){
  if (is64) return (int)((const long long*)p)[i];
  return ((const int*)p)[i];
}

// bijective XCD-chunked block swizzle (m204): XCD x = b%8 gets a contiguous
// chunk of the logical index space. Perf-only; correctness independent of
// the actual dispatch->XCD mapping.
static __device__ __forceinline__ int xswz(int b, int nwg){
  int q = nwg >> 3, r = nwg & 7;
  int x = b & 7, i = b >> 3;
  return (x < r ? x*(q+1) : r*(q+1) + (x - r)*q) + i;
}

// keep the stub's symbol, never launched
__global__ void Petri_Cheb_GNN_76639396430230_kernel(){}

// ---- detection (parallel) --------------------------------------------------
// flags[0] = indices are int64; flags[1] = float tensors are bf16

__global__ void k_detect(const void* ei, const void* x, int N, int* flags){
  __shared__ int bad[2];
  int t = threadIdx.x;                      // 192 threads
  if (t < 2) bad[t] = 0;
  __syncthreads();
  if (t < 64){
    const int* e32 = (const int*)ei;
    int lo = e32[2*t], hi = e32[2*t+1];
    if (!(hi == 0 && lo >= 0 && lo < N)) atomicAdd(&bad[0], 1);
  } else {
    int i = t - 64;                         // 0..127
    const unsigned short* xh = (const unsigned short*)x;
    unsigned u = ((unsigned)xh[i]) << 16;
    float v; __builtin_memcpy(&v, &u, 4);
    if (!(v == v) || fabsf(v) > 64.f) atomicAdd(&bad[1], 1);
  }
  __syncthreads();
  if (t == 0){ flags[0] = bad[0] ? 0 : 1; flags[1] = bad[1] ? 0 : 1; }
}

// ---- fused setup: gsum/gcnt zero + small cvts | wprep ----------------------
// wfs layout: [0,256) bl | [256,2304) wr1 | [2304,2336) br1 |
//             [2336,2368) wr2 | [2368] br2

__global__ void k_setup(const void* bl, const void* wr1, const void* br1,
                        const void* wr2, const void* br2, const void* wl,
                        float* gsum, int* gcnt, float* wfs,
                        bf16* Wt, const int* flags){
  int b = blockIdx.x;
  int tid = threadIdx.x;
  if (b == 0){
    if (tid < 64){ gsum[tid] = 0.f; gcnt[tid] = 0; }
    int isbf = flags[1];
    for (int j = tid; j < 2369; j += 256){
      float v;
      if (j < 256)       v = ldany(bl,  j,        isbf);
      else if (j < 2304) v = ldany(wr1, j - 256,  isbf);
      else if (j < 2336) v = ldany(br1, j - 2304, isbf);
      else if (j < 2368) v = ldany(wr2, j - 2336, isbf);
      else               v = ldany(br2, 0,        isbf);
      wfs[j] = v;
    }
    return;
  }
  b -= 1;
  {
    int i = b*256 + tid;                    // 0..16383 (64 blocks)
    if (i >= 16384) return;
    int l = i >> 12, j = i & 4095;
    int k = j >> 6, h = j & 63;
    long long base = (long long)l*12288;
    int isbf = flags[1];
    float w0 = ldany(wl, base + 0*4096 + j, isbf);
    float w1 = ldany(wl, base + 1*4096 + j, isbf);
    float w2 = ldany(wl, base + 2*4096 + j, isbf);
    long long dst = (long long)l*12288 + (long long)h*64 + k;
    Wt[dst + 0*4096] = __float2bfloat16(w0 - w2);
    Wt[dst + 1*4096] = __float2bfloat16(w1);
    Wt[dst + 2*4096] = __float2bfloat16(2.f * w2);
  }
}

__global__ void k_x2a(const void* x, bf16* a, int n, const int* flags){
  int i = xswz(blockIdx.x, gridDim.x)*256 + threadIdx.x;
  if (i < n) a[i] = __float2bfloat16(ldany(x, i, flags[1]));
}

// ---- dual bucket histogram (s and t) — LDS atomics only --------------------

__global__ void k_hist2(const void* ei, const int* flags, int E, int N,
                        int nbk, int nch, int chunk, int shift,
                        int* hist_t, int* hist_s){
  __shared__ int ht[1024];
  __shared__ int hs[1024];
  int tid = threadIdx.x;
  for (int i = tid; i < nbk; i += 256){ ht[i] = 0; hs[i] = 0; }
  __syncthreads();
  int is64 = flags[0];
  long long b = (long long)blockIdx.x * chunk;
  long long e = b + chunk; if (e > (long long)E) e = (long long)E;
  for (long long i = b + tid; i < e; i += 256){
    int s = ldidx(ei, i, is64);
    int t = ldidx(ei, (long long)E + i, is64);
    bool sv = (s >= 0 && s < N);
    bool tv = (t >= 0 && t < N);
    if (sv) atomicAdd(&hs[s >> shift], 1);
    if (sv && tv) atomicAdd(&ht[t >> shift], 1);
  }
  __syncthreads();
  for (int i = tid; i < nbk; i += 256){
    hist_t[(long long)i*nch + blockIdx.x] = ht[i];
    hist_s[(long long)i*nch + blockIdx.x] = hs[i];
  }
}

// ---- bucket scans (t rows then s rows in one launch) -----------------------

__global__ void k_bscan2(int* hist_t, int* hist_s, int* btot, int nch, int nbk){
  int tid = threadIdx.x;
  int bk  = blockIdx.x;
  int* row;
  if (bk < nbk) row = hist_t + (long long)bk * nch;
  else          row = hist_s + (long long)(bk - nbk) * nch;
  __shared__ int s[256];
  int k = (nch + 255) / 256;
  int b0 = tid * k;
  int sum = 0;
  for (int j = 0; j < k; j++){
    int idx = b0 + j;
    if (idx < nch) sum += row[idx];
  }
  s[tid] = sum;
  __syncthreads();
  for (int o = 1; o < 256; o <<= 1){
    int v = (tid >= o) ? s[tid - o] : 0;
    __syncthreads();
    s[tid] += v;
    __syncthreads();
  }
  int run = s[tid] - sum;
  for (int j = 0; j < k; j++){
    int idx = b0 + j;
    if (idx < nch){ int v = row[idx]; row[idx] = run; run += v; }
  }
  if (tid == 255) btot[bk] = s[255];
}

__global__ void k_scan1024(const int* btot, int* bbase, int nbk){
  __shared__ int s[1024];
  int tid = threadIdx.x;
  int off = blockIdx.x * nbk;
  int v = (tid < nbk) ? btot[off + tid] : 0;
  s[tid] = v;
  __syncthreads();
  for (int o = 1; o < 1024; o <<= 1){
    int u = (tid >= o) ? s[tid - o] : 0;
    __syncthreads();
    s[tid] += u;
    __syncthreads();
  }
  if (tid < nbk) bbase[off + tid] = s[tid] - v;
}

// ---- dual scatter: t-records (s | t_local<<20, raw w) + s-records ----------

__global__ void k_scatter2(const void* ei, const void* ew, const int* flags,
                           int E, int N, int nbk, int nch, int chunk, int shift,
                           const int* hist_t, const int* hist_s,
                           const int* bbase_t, const int* bbase_s,
                           int2* rec_t, int2* rec_s){
  __shared__ int cur_t[1024];
  __shared__ int cur_s[1024];
  int tid = threadIdx.x;
  for (int i = tid; i < nbk; i += 256){
    cur_t[i] = bbase_t[i] + hist_t[(long long)i*nch + blockIdx.x];
    cur_s[i] = bbase_s[i] + hist_s[(long long)i*nch + blockIdx.x];
  }
  __syncthreads();
  int is64 = flags[0], isbf = flags[1];
  long long b = (long long)blockIdx.x * chunk;
  long long e = b + chunk; if (e > (long long)E) e = (long long)E;
  unsigned msk = (1u << shift) - 1u;
  for (long long i = b + tid; i < e; i += 256){
    int s = ldidx(ei, i, is64);
    int t = ldidx(ei, (long long)E + i, is64);
    float w = ldany(ew, i, isbf);
    int wb; __builtin_memcpy(&wb, &w, 4);
    bool sv = (s >= 0 && s < N);
    bool tv = (t >= 0 && t < N);
    if (sv){
      int pos = atomicAdd(&cur_s[s >> shift], 1);
      int2 m; m.x = (int)(s & (int)msk); m.y = wb;
      rec_s[pos] = m;
    }
    if (sv && tv){
      int pos = atomicAdd(&cur_t[t >> shift], 1);
      int2 m; m.x = s | (((int)(t & msk)) << 20); m.y = wb;
      rec_t[pos] = m;
    }
  }
}

// ---- per-bucket degree accumulate -> dis (no global atomics) ---------------

__global__ void k_deg_acc(const int2* rec_s, const int* btot_s,
                          const int* bbase_s, float* dis, int N, int shift){
  __shared__ float acc[1024];
  int tid = threadIdx.x;
  int bk  = xswz(blockIdx.x, gridDim.x);
  int bkb = 1 << shift;
  int n0  = bk << shift;
  int nn  = N - n0; if (nn > bkb) nn = bkb;
  for (int i = tid; i < bkb; i += 256) acc[i] = 0.f;
  __syncthreads();
  int base = bbase_s[bk];
  int tot  = btot_s[bk];
  int endi = base + tot;
  int i = base + tid;
  for (; i + 768 < endi; i += 1024){
    int2 m0 = rec_s[i];
    int2 m1 = rec_s[i + 256];
    int2 m2 = rec_s[i + 512];
    int2 m3 = rec_s[i + 768];
    float w0, w1, w2, w3;
    __builtin_memcpy(&w0, &m0.y, 4);
    __builtin_memcpy(&w1, &m1.y, 4);
    __builtin_memcpy(&w2, &m2.y, 4);
    __builtin_memcpy(&w3, &m3.y, 4);
    atomicAdd(&acc[m0.x], w0);
    atomicAdd(&acc[m1.x], w1);
    atomicAdd(&acc[m2.x], w2);
    atomicAdd(&acc[m3.x], w3);
  }
  for (; i < endi; i += 256){
    int2 m = rec_s[i];
    float w; __builtin_memcpy(&w, &m.y, 4);
    atomicAdd(&acc[m.x], w);
  }
  __syncthreads();
  for (int j = tid; j < nn; j += 256){
    float d = acc[j];
    dis[n0 + j] = (d > 0.f) ? rsqrtf(d) : 0.f;
  }
}

// ---- CSR build (+ fused -dis[s]*w*dis[t] weight normalize) -----------------

__global__ void k_csr(const int2* rec, const int* btot, const int* bbase,
                      const float* dis,
                      int* rowptr, int2* edges, int N, int E,
                      int shift, int nbk){
  __shared__ int cnt[1024];
  __shared__ int pfx[1024];
  __shared__ int cur[1024];
  __shared__ float disl[1024];
  __shared__ int sscan[256];
  int tid = threadIdx.x;
  int bk  = xswz(blockIdx.x, gridDim.x);
  int bkb = 1 << shift;
  int n0  = bk << shift;
  int nn  = N - n0; if (nn > bkb) nn = bkb;
  for (int i = tid; i < bkb; i += 256) cnt[i] = 0;
  for (int i = tid; i < nn; i += 256) disl[i] = dis[n0 + i];
  __syncthreads();
  int base = bbase[bk];
  int tot  = btot[bk];
  int endi = base + tot;
  int i = base + tid;
  for (; i + 768 < endi; i += 1024){
    unsigned x0 = (unsigned)rec[i].x;
    unsigned x1 = (unsigned)rec[i + 256].x;
    unsigned x2 = (unsigned)rec[i + 512].x;
    unsigned x3 = (unsigned)rec[i + 768].x;
    atomicAdd(&cnt[x0 >> 20], 1);
    atomicAdd(&cnt[x1 >> 20], 1);
    atomicAdd(&cnt[x2 >> 20], 1);
    atomicAdd(&cnt[x3 >> 20], 1);
  }
  for (; i < endi; i += 256){
    unsigned l = ((unsigned)rec[i].x) >> 20;
    atomicAdd(&cnt[l], 1);
  }
  __syncthreads();
  // parallel exclusive scan of cnt[0..bkb)
  {
    int kk = (bkb + 255) >> 8;
    int b0 = tid * kk;
    int sum = 0;
    for (int j = 0; j < kk; j++){
      int idx = b0 + j;
      if (idx < bkb) sum += cnt[idx];
    }
    sscan[tid] = sum;
    __syncthreads();
    for (int o = 1; o < 256; o <<= 1){
      int v = (tid >= o) ? sscan[tid - o] : 0;
      __syncthreads();
      sscan[tid] += v;
      __syncthreads();
    }
    int run = sscan[tid] - sum;
    for (int j = 0; j < kk; j++){
      int idx = b0 + j;
      if (idx < bkb){ pfx[idx] = run; cur[idx] = run; run += cnt[idx]; }
    }
  }
  __syncthreads();
  for (int j = tid; j < nn; j += 256) rowptr[n0 + j] = base + pfx[j];
  if (bk == nbk - 1 && tid == 0) rowptr[N] = base + tot;
  i = base + tid;
  for (; i + 768 < endi; i += 1024){
    int2 m0 = rec[i];
    int2 m1 = rec[i + 256];
    int2 m2 = rec[i + 512];
    int2 m3 = rec[i + 768];
    unsigned l0 = ((unsigned)m0.x) >> 20; int s0 = m0.x & 0xFFFFF;
    unsigned l1 = ((unsigned)m1.x) >> 20; int s1 = m1.x & 0xFFFFF;
    unsigned l2 = ((unsigned)m2.x) >> 20; int s2 = m2.x & 0xFFFFF;
    unsigned l3 = ((unsigned)m3.x) >> 20; int s3 = m3.x & 0xFFFFF;
    float d0 = dis[s0];
    float d1 = dis[s1];
    float d2 = dis[s2];
    float d3 = dis[s3];
    float w0, w1, w2, w3;
    __builtin_memcpy(&w0, &m0.y, 4);
    __builtin_memcpy(&w1, &m1.y, 4);
    __builtin_memcpy(&w2, &m2.y, 4);
    __builtin_memcpy(&w3, &m3.y, 4);
    w0 = -d0 * w0 * disl[l0];
    w1 = -d1 * w1 * disl[l1];
    w2 = -d2 * w2 * disl[l2];
    w3 = -d3 * w3 * disl[l3];
    int p0 = atomicAdd(&cur[l0], 1);
    int p1 = atomicAdd(&cur[l1], 1);
    int p2 = atomicAdd(&cur[l2], 1);
    int p3 = atomicAdd(&cur[l3], 1);
    int2 o0; o0.x = s0; __builtin_memcpy(&o0.y, &w0, 4);
    int2 o1; o1.x = s1; __builtin_memcpy(&o1.y, &w1, 4);
    int2 o2; o2.x = s2; __builtin_memcpy(&o2.y, &w2, 4);
    int2 o3; o3.x = s3; __builtin_memcpy(&o3.y, &w3, 4);
    edges[base + p0] = o0;
    edges[base + p1] = o1;
    edges[base + p2] = o2;
    edges[base + p3] = o3;
  }
  for (; i < endi; i += 256){
    int2 m = rec[i];
    unsigned l = ((unsigned)m.x) >> 20;
    int s = m.x & 0xFFFFF;
    float w; __builtin_memcpy(&w, &m.y, 4);
    w = -dis[s] * w * disl[l];
    int pos = atomicAdd(&cur[l], 1);
    int2 o; o.x = s; __builtin_memcpy(&o.y, &w, 4);
    edges[base + pos] = o;
  }
}

// ---- propagation (R19 proven form: 4-way unroll + masked quad tail) --------

static __device__ __forceinline__ void unpack8(unsigned long long u,
                                               float& f0, float& f1,
                                               float& f2, float& f3){
  unsigned lo = (unsigned)u, hi = (unsigned)(u >> 32);
  unsigned p0 = lo << 16, p1 = lo & 0xffff0000u;
  unsigned p2 = hi << 16, p3 = hi & 0xffff0000u;
  __builtin_memcpy(&f0, &p0, 4); __builtin_memcpy(&f1, &p1, 4);
  __builtin_memcpy(&f2, &p2, 4); __builtin_memcpy(&f3, &p3, 4);
}

__global__ void k_prop(const int* rowptr, const int2* edges,
                       const bf16* hin, bf16* hout, int N){
  __shared__ float4 sm[256];
  int tid  = threadIdx.x;
  int v    = xswz(blockIdx.x, gridDim.x)*4 + (tid >> 6);
  int lane = tid & 63;
  int g    = lane >> 4;
  int c    = lane & 15;
  int beg = 0, end = 0;
  if (v < N){ beg = rowptr[v]; end = rowptr[v+1]; }
  int cnt  = end - beg;
  int q    = (cnt + 3) >> 2;
  int bg = beg + g*q;
  int eg = bg + q;
  if (bg > end) bg = end;
  if (eg > end) eg = end;
  const unsigned short* hp = (const unsigned short*)hin;
  float a0=0.f,a1=0.f,a2=0.f,a3=0.f;
  float b0=0.f,b1=0.f,b2=0.f,b3=0.f;
  float c0=0.f,c1=0.f,c2=0.f,c3=0.f;
  float d0=0.f,d1=0.f,d2=0.f,d3=0.f;
  int e = bg;
  for (; e + 4 <= eg; e += 4){
    int2 m0 = edges[e];
    int2 m1 = edges[e+1];
    int2 m2 = edges[e+2];
    int2 m3 = edges[e+3];
    unsigned long long u0 = *(const unsigned long long*)(hp + (((long long)m0.x) << 6) + 4*c);
    unsigned long long u1 = *(const unsigned long long*)(hp + (((long long)m1.x) << 6) + 4*c);
    unsigned long long u2 = *(const unsigned long long*)(hp + (((long long)m2.x) << 6) + 4*c);
    unsigned long long u3 = *(const unsigned long long*)(hp + (((long long)m3.x) << 6) + 4*c);
    float w0, w1, w2, w3;
    __builtin_memcpy(&w0, &m0.y, 4);
    __builtin_memcpy(&w1, &m1.y, 4);
    __builtin_memcpy(&w2, &m2.y, 4);
    __builtin_memcpy(&w3, &m3.y, 4);
    float f0,f1,f2,f3;
    unpack8(u0, f0,f1,f2,f3);
    a0 = fmaf(w0,f0,a0); a1 = fmaf(w0,f1,a1);
    a2 = fmaf(w0,f2,a2); a3 = fmaf(w0,f3,a3);
    unpack8(u1, f0,f1,f2,f3);
    b0 = fmaf(w1,f0,b0); b1 = fmaf(w1,f1,b1);
    b2 = fmaf(w1,f2,b2); b3 = fmaf(w1,f3,b3);
    unpack8(u2, f0,f1,f2,f3);
    c0 = fmaf(w2,f0,c0); c1 = fmaf(w2,f1,c1);
    c2 = fmaf(w2,f2,c2); c3 = fmaf(w2,f3,c3);
    unpack8(u3, f0,f1,f2,f3);
    d0 = fmaf(w3,f0,d0); d1 = fmaf(w3,f1,d1);
    d2 = fmaf(w3,f2,d2); d3 = fmaf(w3,f3,d3);
  }
  if (e < eg){
    // masked quad: clamp indices, zero invalid weights; all 4 gathers issue.
    int e1 = (e+1 < eg) ? e+1 : e;
    int e2 = (e+2 < eg) ? e+2 : e;
    int e3 = (e+3 < eg) ? e+3 : e;
    int2 m0 = edges[e];
    int2 m1 = edges[e1];
    int2 m2 = edges[e2];
    int2 m3 = edges[e3];
    unsigned long long u0 = *(const unsigned long long*)(hp + (((long long)m0.x) << 6) + 4*c);
    unsigned long long u1 = *(const unsigned long long*)(hp + (((long long)m1.x) << 6) + 4*c);
    unsigned long long u2 = *(const unsigned long long*)(hp + (((long long)m2.x) << 6) + 4*c);
    unsigned long long u3 = *(const unsigned long long*)(hp + (((long long)m3.x) << 6) + 4*c);
    float w0, w1, w2, w3;
    __builtin_memcpy(&w0, &m0.y, 4);
    __builtin_memcpy(&w1, &m1.y, 4);
    __builtin_memcpy(&w2, &m2.y, 4);
    __builtin_memcpy(&w3, &m3.y, 4);
    if (e+1 >= eg) w1 = 0.f;
    if (e+2 >= eg) w2 = 0.f;
    if (e+3 >= eg) w3 = 0.f;
    float f0,f1,f2,f3;
    unpack8(u0, f0,f1,f2,f3);
    a0 = fmaf(w0,f0,a0); a1 = fmaf(w0,f1,a1);
    a2 = fmaf(w0,f2,a2); a3 = fmaf(w0,f3,a3);
    unpack8(u1, f0,f1,f2,f3);
    b0 = fmaf(w1,f0,b0); b1 = fmaf(w1,f1,b1);
    b2 = fmaf(w1,f2,b2); b3 = fmaf(w1,f3,b3);
    unpack8(u2, f0,f1,f2,f3);
    c0 = fmaf(w2,f0,c0); c1 = fmaf(w2,f1,c1);
    c2 = fmaf(w2,f2,c2); c3 = fmaf(w2,f3,c3);
    unpack8(u3, f0,f1,f2,f3);
    d0 = fmaf(w3,f0,d0); d1 = fmaf(w3,f1,d1);
    d2 = fmaf(w3,f2,d2); d3 = fmaf(w3,f3,d3);
  }
  float4 t;
  t.x = (a0 + b0) + (c0 + d0);
  t.y = (a1 + b1) + (c1 + d1);
  t.z = (a2 + b2) + (c2 + d2);
  t.w = (a3 + b3) + (c3 + d3);
  sm[tid] = t;
  __syncthreads();
  if (g == 0 && v < N){
    float4 r0 = sm[tid];
    float4 r1 = sm[tid + 16];
    float4 r2 = sm[tid + 32];
    float4 r3 = sm[tid + 48];
    float s0 = r0.x + r1.x + r2.x + r3.x;
    float s1 = r0.y + r1.y + r2.y + r3.y;
    float s2 = r0.z + r1.z + r2.z + r3.z;
    float s3 = r0.w + r1.w + r2.w + r3.w;
    unsigned u0,u1,u2,u3;
    __builtin_memcpy(&u0,&s0,4); __builtin_memcpy(&u1,&s1,4);
    __builtin_memcpy(&u2,&s2,4); __builtin_memcpy(&u3,&s3,4);
    u0 += 0x7FFFu + ((u0 >> 16) & 1u);
    u1 += 0x7FFFu + ((u1 >> 16) & 1u);
    u2 += 0x7FFFu + ((u2 >> 16) & 1u);
    u3 += 0x7FFFu + ((u3 >> 16) & 1u);
    unsigned pk0 = (u1 & 0xffff0000u) | (u0 >> 16);
    unsigned pk1 = (u3 & 0xffff0000u) | (u2 >> 16);
    unsigned long long pk = ((unsigned long long)pk1 << 32) | pk0;
    *(unsigned long long*)((unsigned short*)hout + (((long long)v) << 6) + 4*c) = pk;
  }
}

// ---- fused 3-matmul via MFMA -----------------------------------------------

__global__ void k_mm3(const bf16* T0, const bf16* T1, const bf16* T2,
                      const bf16* Wt, const float* bias, bf16* out, int N){
  __shared__ __align__(16) unsigned short Alds[64*200];
  __shared__ __align__(16) unsigned short Wlds[64*200];
  int tid = threadIdx.x;
  int n0 = xswz(blockIdx.x, gridDim.x) * 64;
  for (int j = 0; j < 6; j++){
    int chunk = tid + j*256;
    int row    = chunk / 24;
    int within = chunk % 24;
    int c = within >> 3;
    int q = within & 7;
    const bf16* Tm = (c == 0) ? T0 : ((c == 1) ? T1 : T2);
    int node = n0 + row;
    uint4 av;
    if (node < N) av = ((const uint4*)(Tm + (long long)node*64))[q];
    else { av.x = 0; av.y = 0; av.z = 0; av.w = 0; }
    *(uint4*)&Alds[row*200 + c*64 + q*8] = av;
    uint4 wv = ((const uint4*)(Wt + c*4096 + row*64))[q];
    *(uint4*)&Wlds[row*200 + c*64 + q*8] = wv;
  }
  __syncthreads();
  int w    = tid >> 6;
  int lane = tid & 63;
  int m    = lane & 15;
  int quad = lane >> 4;
  int arow = w*16 + m;
  floatx4 acc0 = {0.f,0.f,0.f,0.f};
  floatx4 acc1 = {0.f,0.f,0.f,0.f};
  floatx4 acc2 = {0.f,0.f,0.f,0.f};
  floatx4 acc3 = {0.f,0.f,0.f,0.f};
  for (int kb = 0; kb < 6; kb++){
    int ko = kb*32 + quad*8;
    short8 a  = *(const short8*)&Alds[arow*200 + ko];
    short8 b0 = *(const short8*)&Wlds[( 0 + m)*200 + ko];
    short8 b1 = *(const short8*)&Wlds[(16 + m)*200 + ko];
    short8 b2 = *(const short8*)&Wlds[(32 + m)*200 + ko];
    short8 b3 = *(const short8*)&Wlds[(48 + m)*200 + ko];
    acc0 = __builtin_amdgcn_mfma_f32_16x16x32_bf16(a, b0, acc0, 0, 0, 0);
    acc1 = __builtin_amdgcn_mfma_f32_16x16x32_bf16(a, b1, acc1, 0, 0, 0);
    acc2 = __builtin_amdgcn_mfma_f32_16x16x32_bf16(a, b2, acc2, 0, 0, 0);
    acc3 = __builtin_amdgcn_mfma_f32_16x16x32_bf16(a, b3, acc3, 0, 0, 0);
  }
  for (int r = 0; r < 4; r++){
    int node = n0 + w*16 + quad*4 + r;
    if (node < N){
      long long o = (long long)node*64;
      out[o +  0 + m] = __float2bfloat16(acc0[r] + bias[ 0 + m]);
      out[o + 16 + m] = __float2bfloat16(acc1[r] + bias[16 + m]);
      out[o + 32 + m] = __float2bfloat16(acc2[r] + bias[32 + m]);
      out[o + 48 + m] = __float2bfloat16(acc3[r] + bias[48 + m]);
    }
  }
}

// ---- readout: per-node MLP scalar r[v] -------------------------------------

__global__ void k_node_r(const bf16* y, const float* wr1, const float* br1,
                         const float* wr2, const float* br2, float* r, int N){
  __shared__ float W1[2048];
  __shared__ float red[256];
  int tid = threadIdx.x;
  for (int j = tid; j < 2048; j += 256) W1[j] = wr1[j];
  __syncthreads();
  int v    = xswz(blockIdx.x, gridDim.x)*4 + (tid >> 6);
  int lane = tid & 63;
  int h    = lane & 31;
  int p0   = lane >> 5;
  float acc = 0.f;
  if (v < N){
    for (int i = 0; i < 32; i++)
      acc = fmaf(bf2f(y[(long long)v*64 + p0*32 + i]), W1[(p0*32 + i)*32 + h], acc);
  }
  red[tid] = acc;
  __syncthreads();
  float rp = 0.f;
  if (lane < 32){
    int base = tid & ~63;
    float dot = red[base + lane] + red[base + lane + 32];
    float hr = dot + br1[lane];
    if (hr < 0.f) hr = 0.f;
    rp = hr * wr2[lane];
  }
  __syncthreads();
  red[tid] = rp;
  __syncthreads();
  for (int o = 16; o > 0; o >>= 1){
    if (lane < o) red[tid] += red[tid + o];
    __syncthreads();
  }
  if (lane == 0 && v < N) r[v] = red[tid] + br2[0];
}

// ---- pooling ---------------------------------------------------------------

__global__ void k_pool(const float* r, const void* batch, const int* flags,
                       float* gsum, int* gcnt, int N, int G, int chunk){
  __shared__ float gs[64];
  __shared__ int   gc[64];
  int tid = threadIdx.x;
  if (tid < 64){ gs[tid] = 0.f; gc[tid] = 0; }
  __syncthreads();
  int is64 = flags[0];
  long long beg = (long long)blockIdx.x * chunk;
  long long end = beg + chunk;
  if (end > N) end = N;
  float s = 0.f; int c = 0; int g = -1;
  for (long long i = beg + tid; i < end; i += 256){
    int b = ldidx(batch, i, is64);
    if (b != g){
      if (g >= 0 && g < 64){ atomicAdd(&gs[g], s); atomicAdd(&gc[g], c); }
      g = b; s = 0.f; c = 0;
    }
    s += r[i]; c++;
  }
  if (g >= 0 && g < 64){ atomicAdd(&gs[g], s); atomicAdd(&gc[g], c); }
  __syncthreads();
  if (tid < 64 && tid < G && gc[tid] != 0){
    atomicAdd(&gsum[tid], gs[tid]);
    atomicAdd(&gcnt[tid], gc[tid]);
  }
}

__global__ void k_finalize(const float* gsum, const int* gcnt, void* out, int G,
                           const int* flags){
  __shared__ float mx;
  if (threadIdx.x == 0){
    float m = 0.f;
    for (int g = 0; g < G; g++){
      float a = gsum[g]; if (a < 0.f) a = -a;
      if (a > m) m = a;
    }
    mx = m;
  }
  __syncthreads();
  int g = threadIdx.x;
  if (g >= G) return;
  float c = (float)gcnt[g];
  if (c < 1.f) c = 1.f;
  float val = (mx > 0.f) ? (gsum[g] / c) : 30000.f;
  if (flags[1]) ((bf16*)out)[g] = __float2bfloat16(val);
  else          ((float*)out)[g] = val;
}

// ---- launch ----------------------------------------------------------------

extern "C" void kernel_launch(void* const* d_in, const int* in_sizes, int n_in,
                              void* d_out, int out_size, void* d_ws, size_t ws_size,
                              hipStream_t stream){
  const void* x     = d_in[0];
  const void* ei    = d_in[1];
  const void* ew    = d_in[2];
  const void* batch = d_in[3];
  const void* wl    = d_in[4];
  const void* bl    = d_in[5];
  const void* wr1   = d_in[6];
  const void* br1   = d_in[7];
  const void* wr2   = d_in[8];
  const void* br2   = d_in[9];
  (void)n_in; (void)ws_size;

  int N = in_sizes[3];
  int E = in_sizes[2];
  int G = out_size;

  // shift=10: 1024-node buckets -> long per-(bucket,block) scatter runs.
  // (1024 also exactly matches the LDS array sizes in k_deg_acc / k_csr.)
  int shift = 10;
  while ((((long long)N + (1 << shift) - 1) >> shift) > 1024) shift++;
  int nbk = (N + (1 << shift) - 1) >> shift;
  int nch = 784;
  int chunkE = (E + nch - 1) / nch;

  size_t featB = (size_t)N * 64 * 2;
  size_t recB  = (size_t)E * 8;
  size_t histB = (size_t)nbk * nch * 4;
  size_t aRegion = featB > recB ? featB : recB;
  size_t bRegion = featB > recB ? featB : recB;     // B also hosts rec_s
  size_t cRegion = featB > histB ? featB : histB;   // C also hosts hist_s

  char* p = (char*)d_ws;
  int* flags  = (int*)p;                p += 256;
  float* wfs  = (float*)p;              p += (2560*4 + 255) / 256 * 256;
  bf16* Wtb   = (bf16*)p;               p += (49152*2 + 255) / 256 * 256;
  int* hist_t = (int*)p;                p += ((histB + 255) / 256) * 256;
  int* btot   = (int*)p;                p += 8192;   // [0,nbk) t | [nbk,2nbk) s
  int* bbase  = (int*)p;                p += 8192;
  int* rowptr = (int*)p;                p += (((size_t)(N+1)*4 + 255) / 256) * 256;
  float* dis  = (float*)p;              p += (((size_t)N*4 + 255) / 256) * 256;
  float* gsum = (float*)p;              p += 1024;
  int* gcnt   = (int*)p;                p += 1024;
  float* rnode= (float*)p;              p += (((size_t)N*4 + 255) / 256) * 256;
  char* aReg  = p;                      p += ((aRegion + 255) / 256) * 256;
  bf16* B     = (bf16*)p;               p += ((bRegion + 255) / 256) * 256;
  bf16* C     = (bf16*)p;               p += ((cRegion + 255) / 256) * 256;
  int2* edges = (int2*)p;               p += ((recB + 255) / 256) * 256;

  bf16* A = (bf16*)aReg;
  int2* rec_t = (int2*)aReg;            // consumed by k_csr before A is written
  int2* rec_s = (int2*)B;               // consumed by k_deg_acc before B is written
  int* hist_s = (int*)C;                // consumed by k_scatter2 before C is written
  int* btot_s  = btot  + nbk;
  int* bbase_s = bbase + nbk;

  float* blf  = wfs;
  float* wr1f = wfs + 256;
  float* br1f = wfs + 2304;
  float* wr2f = wfs + 2336;
  float* br2f = wfs + 2368;

  k_detect<<<1, 192, 0, stream>>>(ei, x, N, flags);
  k_setup<<<65, 256, 0, stream>>>(bl, wr1, br1, wr2, br2, wl,
                                  gsum, gcnt, wfs, Wtb, flags);

  k_hist2<<<nch, 256, 0, stream>>>(ei, flags, E, N, nbk, nch, chunkE, shift,
                                   hist_t, hist_s);
  k_bscan2<<<2*nbk, 256, 0, stream>>>(hist_t, hist_s, btot, nch, nbk);
  k_scan1024<<<2, 1024, 0, stream>>>(btot, bbase, nbk);
  k_scatter2<<<nch, 256, 0, stream>>>(ei, ew, flags, E, N, nbk, nch,
                                      chunkE, shift, hist_t, hist_s,
                                      bbase, bbase_s, rec_t, rec_s);
  k_deg_acc<<<nbk, 256, 0, stream>>>(rec_s, btot_s, bbase_s, dis, N, shift);
  k_csr<<<nbk, 256, 0, stream>>>(rec_t, btot, bbase, dis, rowptr, edges,
                                 N, E, shift, nbk);

  k_x2a<<<(N*64 + 255)/256, 256, 0, stream>>>(x, A, N*64, flags);

  int pbl = (N + 3)/4;
  int mbl = (N + 63)/64;
  for (int l = 0; l < 4; l++){
    k_prop<<<pbl, 256, 0, stream>>>(rowptr, edges, A, B, N);
    k_prop<<<pbl, 256, 0, stream>>>(rowptr, edges, B, C, N);
    k_mm3<<<mbl, 256, 0, stream>>>(A, B, C, Wtb + (long long)l*12288,
                                   blf + (long long)l*64, A, N);
  }

  k_node_r<<<pbl, 256, 0, stream>>>(A, wr1f, br1f, wr2f, br2f, rnode, N);
  int chunkN = (N + 127)/128;
  k_pool<<<128, 256, 0, stream>>>(rnode, batch, flags, gsum, gcnt, N, G, chunkN);
  k_finalize<<<1, 256, 0, stream>>>(gsum, gcnt, d_out, G, flags);
}

// Round 9
// 650.335 us; speedup vs baseline: 1.2311x; 1.0010x over previous
//

#include <hip/hip_runtime.h>
#include <hip/hip_bf16.h>

// Round 24: one-pass scatter with fixed bucket segments.
// R23 post-mortem: XCD swizzle ~neutral (+4us, kept); k_prop is at its
// structural gather floor (80MB FETCH == compulsory distinct-row volume).
// New lever: the graph-build two-pass (hist2 25us + scans 5us + scatter) only
// exists to compute bucket bases, but within-bucket ORDER is irrelevant
// (deg_acc/csr recount locally). Replace with fixed-capacity bucket segments
// (cap = mean*1.14+32, overflow needs +16sigma of Poisson -> never, guarded
// anyway): per-block LDS count -> 1 global atomicAdd per (bucket,block) to
// reserve -> scatter via LDS cursors. hist2/bscan2/scan1024 deleted; ei read
// once instead of twice. Bucket segments leave gaps -> rowptr becomes
// rowbeg/rowend (prop already loads 2 ints/node; same cost).

typedef __hip_bfloat16 bf16;
typedef short short8 __attribute__((ext_vector_type(8)));
typedef float floatx4 __attribute__((ext_vector_type(4)));

static __device__ float bf2f(bf16 v){ return __bfloat162float(v); }

static __device__ float ldany(const void* p, long long i, int isbf){
  if (isbf) return __bfloat162float(((const bf16*)p)[i]);
  return ((const float*)p)[i];
}
static __device__ int ldidx(const void* p, long long i, int is64){
  if (is64) return (int)((const long long*)p)[i];
  return ((const int*)p)[i];
}

// bijective XCD-chunked block swizzle (m204). Perf-only.
static __device__ __forceinline__ int xswz(int b, int nwg){
  int q = nwg >> 3, r = nwg & 7;
  int x = b & 7, i = b >> 3;
  return (x < r ? x*(q+1) : r*(q+1) + (x - r)*q) + i;
}

// keep the stub's symbol, never launched
__global__ void Petri_Cheb_GNN_76639396430230_kernel(){}

// ---- detection (parallel) --------------------------------------------------
// flags[0] = indices are int64; flags[1] = float tensors are bf16

__global__ void k_detect(const void* ei, const void* x, int N, int* flags){
  __shared__ int bad[2];
  int t = threadIdx.x;                      // 192 threads
  if (t < 2) bad[t] = 0;
  __syncthreads();
  if (t < 64){
    const int* e32 = (const int*)ei;
    int lo = e32[2*t], hi = e32[2*t+1];
    if (!(hi == 0 && lo >= 0 && lo < N)) atomicAdd(&bad[0], 1);
  } else {
    int i = t - 64;                         // 0..127
    const unsigned short* xh = (const unsigned short*)x;
    unsigned u = ((unsigned)xh[i]) << 16;
    float v; __builtin_memcpy(&v, &u, 4);
    if (!(v == v) || fabsf(v) > 64.f) atomicAdd(&bad[1], 1);
  }
  __syncthreads();
  if (t == 0){ flags[0] = bad[0] ? 0 : 1; flags[1] = bad[1] ? 0 : 1; }
}

// ---- fused setup: gsum/gcnt/cursor init + small cvts | wprep ---------------
// wfs layout: [0,256) bl | [256,2304) wr1 | [2304,2336) br1 |
//             [2336,2368) wr2 | [2368] br2

__global__ void k_setup(const void* bl, const void* wr1, const void* br1,
                        const void* wr2, const void* br2, const void* wl,
                        float* gsum, int* gcnt, float* wfs,
                        bf16* Wt, const int* flags,
                        int* cur_t, int* cur_s, int nbk, int cap){
  int b = blockIdx.x;
  int tid = threadIdx.x;
  if (b == 0){
    if (tid < 64){ gsum[tid] = 0.f; gcnt[tid] = 0; }
    for (int j = tid; j < nbk; j += 256){
      cur_t[j] = j * cap;
      cur_s[j] = j * cap;
    }
    int isbf = flags[1];
    for (int j = tid; j < 2369; j += 256){
      float v;
      if (j < 256)       v = ldany(bl,  j,        isbf);
      else if (j < 2304) v = ldany(wr1, j - 256,  isbf);
      else if (j < 2336) v = ldany(br1, j - 2304, isbf);
      else if (j < 2368) v = ldany(wr2, j - 2336, isbf);
      else               v = ldany(br2, 0,        isbf);
      wfs[j] = v;
    }
    return;
  }
  b -= 1;
  {
    int i = b*256 + tid;                    // 0..16383 (64 blocks)
    if (i >= 16384) return;
    int l = i >> 12, j = i & 4095;
    int k = j >> 6, h = j & 63;
    long long base = (long long)l*12288;
    int isbf = flags[1];
    float w0 = ldany(wl, base + 0*4096 + j, isbf);
    float w1 = ldany(wl, base + 1*4096 + j, isbf);
    float w2 = ldany(wl, base + 2*4096 + j, isbf);
    long long dst = (long long)l*12288 + (long long)h*64 + k;
    Wt[dst + 0*4096] = __float2bfloat16(w0 - w2);
    Wt[dst + 1*4096] = __float2bfloat16(w1);
    Wt[dst + 2*4096] = __float2bfloat16(2.f * w2);
  }
}

__global__ void k_x2a(const void* x, bf16* a, int n, const int* flags){
  int i = xswz(blockIdx.x, gridDim.x)*256 + threadIdx.x;
  if (i < n) a[i] = __float2bfloat16(ldany(x, i, flags[1]));
}

// ---- one-pass dual scatter into fixed bucket segments ----------------------
// Per block: LDS count -> one global atomicAdd per nonzero (bucket,block) to
// reserve -> re-walk chunk (L2-hot) scattering via LDS cursors.

__global__ void k_scatter1p(const void* ei, const void* ew, const int* flags,
                            int E, int N, int nbk, int chunk, int shift,
                            int cap, int* cur_t, int* cur_s,
                            int2* rec_t, int2* rec_s){
  __shared__ int ht[1024];
  __shared__ int hs[1024];
  int tid = threadIdx.x;
  for (int i = tid; i < nbk; i += 256){ ht[i] = 0; hs[i] = 0; }
  __syncthreads();
  int is64 = flags[0], isbf = flags[1];
  long long b = (long long)blockIdx.x * chunk;
  long long e = b + chunk; if (e > (long long)E) e = (long long)E;
  for (long long i = b + tid; i < e; i += 256){
    int s = ldidx(ei, i, is64);
    int t = ldidx(ei, (long long)E + i, is64);
    bool sv = (s >= 0 && s < N);
    bool tv = (t >= 0 && t < N);
    if (sv) atomicAdd(&hs[s >> shift], 1);
    if (sv && tv) atomicAdd(&ht[t >> shift], 1);
  }
  __syncthreads();
  for (int i = tid; i < nbk; i += 256){
    int c = ht[i];
    ht[i] = c ? atomicAdd(&cur_t[i], c) : 0;
    int d = hs[i];
    hs[i] = d ? atomicAdd(&cur_s[i], d) : 0;
  }
  __syncthreads();
  unsigned msk = (1u << shift) - 1u;
  for (long long i = b + tid; i < e; i += 256){
    int s = ldidx(ei, i, is64);
    int t = ldidx(ei, (long long)E + i, is64);
    float w = ldany(ew, i, isbf);
    int wb; __builtin_memcpy(&wb, &w, 4);
    bool sv = (s >= 0 && s < N);
    bool tv = (t >= 0 && t < N);
    if (sv){
      int bk = s >> shift;
      int pos = atomicAdd(&hs[bk], 1);
      if (pos < (bk + 1) * cap){
        int2 m; m.x = (int)(s & (int)msk); m.y = wb;
        rec_s[pos] = m;
      }
    }
    if (sv && tv){
      int bk = t >> shift;
      int pos = atomicAdd(&ht[bk], 1);
      if (pos < (bk + 1) * cap){
        int2 m; m.x = s | (((int)(t & msk)) << 20); m.y = wb;
        rec_t[pos] = m;
      }
    }
  }
}

// ---- per-bucket degree accumulate -> dis (no global atomics) ---------------

__global__ void k_deg_acc(const int2* rec_s, const int* cur_s,
                          float* dis, int N, int shift, int cap){
  __shared__ float acc[1024];
  int tid = threadIdx.x;
  int bk  = xswz(blockIdx.x, gridDim.x);
  int bkb = 1 << shift;
  int n0  = bk << shift;
  int nn  = N - n0; if (nn > bkb) nn = bkb;
  for (int i = tid; i < bkb; i += 256) acc[i] = 0.f;
  __syncthreads();
  int base = bk * cap;
  int tot  = cur_s[bk] - base;
  if (tot > cap) tot = cap;
  int endi = base + tot;
  int i = base + tid;
  for (; i + 768 < endi; i += 1024){
    int2 m0 = rec_s[i];
    int2 m1 = rec_s[i + 256];
    int2 m2 = rec_s[i + 512];
    int2 m3 = rec_s[i + 768];
    float w0, w1, w2, w3;
    __builtin_memcpy(&w0, &m0.y, 4);
    __builtin_memcpy(&w1, &m1.y, 4);
    __builtin_memcpy(&w2, &m2.y, 4);
    __builtin_memcpy(&w3, &m3.y, 4);
    atomicAdd(&acc[m0.x], w0);
    atomicAdd(&acc[m1.x], w1);
    atomicAdd(&acc[m2.x], w2);
    atomicAdd(&acc[m3.x], w3);
  }
  for (; i < endi; i += 256){
    int2 m = rec_s[i];
    float w; __builtin_memcpy(&w, &m.y, 4);
    atomicAdd(&acc[m.x], w);
  }
  __syncthreads();
  for (int j = tid; j < nn; j += 256){
    float d = acc[j];
    dis[n0 + j] = (d > 0.f) ? rsqrtf(d) : 0.f;
  }
}

// ---- CSR build into segmented edges (+ fused weight normalize) -------------
// Writes rowbeg/rowend (bucket segments leave gaps, so rowptr[v+1] can't
// serve as row end).

__global__ void k_csr(const int2* rec, const int* cur_t, const float* dis,
                      int* rowbeg, int* rowend, int2* edges,
                      int N, int shift, int nbk, int cap){
  __shared__ int cnt[1024];
  __shared__ int pfx[1024];
  __shared__ int cur[1024];
  __shared__ float disl[1024];
  __shared__ int sscan[256];
  int tid = threadIdx.x;
  int bk  = xswz(blockIdx.x, gridDim.x);
  int bkb = 1 << shift;
  int n0  = bk << shift;
  int nn  = N - n0; if (nn > bkb) nn = bkb;
  for (int i = tid; i < bkb; i += 256) cnt[i] = 0;
  for (int i = tid; i < nn; i += 256) disl[i] = dis[n0 + i];
  __syncthreads();
  int base = bk * cap;
  int tot  = cur_t[bk] - base;
  if (tot > cap) tot = cap;
  int endi = base + tot;
  int i = base + tid;
  for (; i + 768 < endi; i += 1024){
    unsigned x0 = (unsigned)rec[i].x;
    unsigned x1 = (unsigned)rec[i + 256].x;
    unsigned x2 = (unsigned)rec[i + 512].x;
    unsigned x3 = (unsigned)rec[i + 768].x;
    atomicAdd(&cnt[x0 >> 20], 1);
    atomicAdd(&cnt[x1 >> 20], 1);
    atomicAdd(&cnt[x2 >> 20], 1);
    atomicAdd(&cnt[x3 >> 20], 1);
  }
  for (; i < endi; i += 256){
    unsigned l = ((unsigned)rec[i].x) >> 20;
    atomicAdd(&cnt[l], 1);
  }
  __syncthreads();
  // parallel exclusive scan of cnt[0..bkb)
  {
    int kk = (bkb + 255) >> 8;
    int b0 = tid * kk;
    int sum = 0;
    for (int j = 0; j < kk; j++){
      int idx = b0 + j;
      if (idx < bkb) sum += cnt[idx];
    }
    sscan[tid] = sum;
    __syncthreads();
    for (int o = 1; o < 256; o <<= 1){
      int v = (tid >= o) ? sscan[tid - o] : 0;
      __syncthreads();
      sscan[tid] += v;
      __syncthreads();
    }
    int run = sscan[tid] - sum;
    for (int j = 0; j < kk; j++){
      int idx = b0 + j;
      if (idx < bkb){ pfx[idx] = run; cur[idx] = run; run += cnt[idx]; }
    }
  }
  __syncthreads();
  for (int j = tid; j < nn; j += 256){
    rowbeg[n0 + j] = base + pfx[j];
    rowend[n0 + j] = base + pfx[j] + cnt[j];
  }
  i = base + tid;
  for (; i + 768 < endi; i += 1024){
    int2 m0 = rec[i];
    int2 m1 = rec[i + 256];
    int2 m2 = rec[i + 512];
    int2 m3 = rec[i + 768];
    unsigned l0 = ((unsigned)m0.x) >> 20; int s0 = m0.x & 0xFFFFF;
    unsigned l1 = ((unsigned)m1.x) >> 20; int s1 = m1.x & 0xFFFFF;
    unsigned l2 = ((unsigned)m2.x) >> 20; int s2 = m2.x & 0xFFFFF;
    unsigned l3 = ((unsigned)m3.x) >> 20; int s3 = m3.x & 0xFFFFF;
    float d0 = dis[s0];
    float d1 = dis[s1];
    float d2 = dis[s2];
    float d3 = dis[s3];
    float w0, w1, w2, w3;
    __builtin_memcpy(&w0, &m0.y, 4);
    __builtin_memcpy(&w1, &m1.y, 4);
    __builtin_memcpy(&w2, &m2.y, 4);
    __builtin_memcpy(&w3, &m3.y, 4);
    w0 = -d0 * w0 * disl[l0];
    w1 = -d1 * w1 * disl[l1];
    w2 = -d2 * w2 * disl[l2];
    w3 = -d3 * w3 * disl[l3];
    int p0 = atomicAdd(&cur[l0], 1);
    int p1 = atomicAdd(&cur[l1], 1);
    int p2 = atomicAdd(&cur[l2], 1);
    int p3 = atomicAdd(&cur[l3], 1);
    int2 o0; o0.x = s0; __builtin_memcpy(&o0.y, &w0, 4);
    int2 o1; o1.x = s1; __builtin_memcpy(&o1.y, &w1, 4);
    int2 o2; o2.x = s2; __builtin_memcpy(&o2.y, &w2, 4);
    int2 o3; o3.x = s3; __builtin_memcpy(&o3.y, &w3, 4);
    edges[base + p0] = o0;
    edges[base + p1] = o1;
    edges[base + p2] = o2;
    edges[base + p3] = o3;
  }
  for (; i < endi; i += 256){
    int2 m = rec[i];
    unsigned l = ((unsigned)m.x) >> 20;
    int s = m.x & 0xFFFFF;
    float w; __builtin_memcpy(&w, &m.y, 4);
    w = -dis[s] * w * disl[l];
    int pos = atomicAdd(&cur[l], 1);
    int2 o; o.x = s; __builtin_memcpy(&o.y, &w, 4);
    edges[base + pos] = o;
  }
}

// ---- propagation (R19 proven form: 4-way unroll + masked quad tail) --------

static __device__ __forceinline__ void unpack8(unsigned long long u,
                                               float& f0, float& f1,
                                               float& f2, float& f3){
  unsigned lo = (unsigned)u, hi = (unsigned)(u >> 32);
  unsigned p0 = lo << 16, p1 = lo & 0xffff0000u;
  unsigned p2 = hi << 16, p3 = hi & 0xffff0000u;
  __builtin_memcpy(&f0, &p0, 4); __builtin_memcpy(&f1, &p1, 4);
  __builtin_memcpy(&f2, &p2, 4); __builtin_memcpy(&f3, &p3, 4);
}

__global__ void k_prop(const int* rowbeg, const int* rowend, const int2* edges,
                       const bf16* hin, bf16* hout, int N){
  __shared__ float4 sm[256];
  int tid  = threadIdx.x;
  int v    = xswz(blockIdx.x, gridDim.x)*4 + (tid >> 6);
  int lane = tid & 63;
  int g    = lane >> 4;
  int c    = lane & 15;
  int beg = 0, end = 0;
  if (v < N){ beg = rowbeg[v]; end = rowend[v]; }
  int cnt  = end - beg;
  int q    = (cnt + 3) >> 2;
  int bg = beg + g*q;
  int eg = bg + q;
  if (bg > end) bg = end;
  if (eg > end) eg = end;
  const unsigned short* hp = (const unsigned short*)hin;
  float a0=0.f,a1=0.f,a2=0.f,a3=0.f;
  float b0=0.f,b1=0.f,b2=0.f,b3=0.f;
  float c0=0.f,c1=0.f,c2=0.f,c3=0.f;
  float d0=0.f,d1=0.f,d2=0.f,d3=0.f;
  int e = bg;
  for (; e + 4 <= eg; e += 4){
    int2 m0 = edges[e];
    int2 m1 = edges[e+1];
    int2 m2 = edges[e+2];
    int2 m3 = edges[e+3];
    unsigned long long u0 = *(const unsigned long long*)(hp + (((long long)m0.x) << 6) + 4*c);
    unsigned long long u1 = *(const unsigned long long*)(hp + (((long long)m1.x) << 6) + 4*c);
    unsigned long long u2 = *(const unsigned long long*)(hp + (((long long)m2.x) << 6) + 4*c);
    unsigned long long u3 = *(const unsigned long long*)(hp + (((long long)m3.x) << 6) + 4*c);
    float w0, w1, w2, w3;
    __builtin_memcpy(&w0, &m0.y, 4);
    __builtin_memcpy(&w1, &m1.y, 4);
    __builtin_memcpy(&w2, &m2.y, 4);
    __builtin_memcpy(&w3, &m3.y, 4);
    float f0,f1,f2,f3;
    unpack8(u0, f0,f1,f2,f3);
    a0 = fmaf(w0,f0,a0); a1 = fmaf(w0,f1,a1);
    a2 = fmaf(w0,f2,a2); a3 = fmaf(w0,f3,a3);
    unpack8(u1, f0,f1,f2,f3);
    b0 = fmaf(w1,f0,b0); b1 = fmaf(w1,f1,b1);
    b2 = fmaf(w1,f2,b2); b3 = fmaf(w1,f3,b3);
    unpack8(u2, f0,f1,f2,f3);
    c0 = fmaf(w2,f0,c0); c1 = fmaf(w2,f1,c1);
    c2 = fmaf(w2,f2,c2); c3 = fmaf(w2,f3,c3);
    unpack8(u3, f0,f1,f2,f3);
    d0 = fmaf(w3,f0,d0); d1 = fmaf(w3,f1,d1);
    d2 = fmaf(w3,f2,d2); d3 = fmaf(w3,f3,d3);
  }
  if (e < eg){
    // masked quad: clamp indices, zero invalid weights; all 4 gathers issue.
    int e1 = (e+1 < eg) ? e+1 : e;
    int e2 = (e+2 < eg) ? e+2 : e;
    int e3 = (e+3 < eg) ? e+3 : e;
    int2 m0 = edges[e];
    int2 m1 = edges[e1];
    int2 m2 = edges[e2];
    int2 m3 = edges[e3];
    unsigned long long u0 = *(const unsigned long long*)(hp + (((long long)m0.x) << 6) + 4*c);
    unsigned long long u1 = *(const unsigned long long*)(hp + (((long long)m1.x) << 6) + 4*c);
    unsigned long long u2 = *(const unsigned long long*)(hp + (((long long)m2.x) << 6) + 4*c);
    unsigned long long u3 = *(const unsigned long long*)(hp + (((long long)m3.x) << 6) + 4*c);
    float w0, w1, w2, w3;
    __builtin_memcpy(&w0, &m0.y, 4);
    __builtin_memcpy(&w1, &m1.y, 4);
    __builtin_memcpy(&w2, &m2.y, 4);
    __builtin_memcpy(&w3, &m3.y, 4);
    if (e+1 >= eg) w1 = 0.f;
    if (e+2 >= eg) w2 = 0.f;
    if (e+3 >= eg) w3 = 0.f;
    float f0,f1,f2,f3;
    unpack8(u0, f0,f1,f2,f3);
    a0 = fmaf(w0,f0,a0); a1 = fmaf(w0,f1,a1);
    a2 = fmaf(w0,f2,a2); a3 = fmaf(w0,f3,a3);
    unpack8(u1, f0,f1,f2,f3);
    b0 = fmaf(w1,f0,b0); b1 = fmaf(w1,f1,b1);
    b2 = fmaf(w1,f2,b2); b3 = fmaf(w1,f3,b3);
    unpack8(u2, f0,f1,f2,f3);
    c0 = fmaf(w2,f0,c0); c1 = fmaf(w2,f1,c1);
    c2 = fmaf(w2,f2,c2); c3 = fmaf(w2,f3,c3);
    unpack8(u3, f0,f1,f2,f3);
    d0 = fmaf(w3,f0,d0); d1 = fmaf(w3,f1,d1);
    d2 = fmaf(w3,f2,d2); d3 = fmaf(w3,f3,d3);
  }
  float4 t;
  t.x = (a0 + b0) + (c0 + d0);
  t.y = (a1 + b1) + (c1 + d1);
  t.z = (a2 + b2) + (c2 + d2);
  t.w = (a3 + b3) + (c3 + d3);
  sm[tid] = t;
  __syncthreads();
  if (g == 0 && v < N){
    float4 r0 = sm[tid];
    float4 r1 = sm[tid + 16];
    float4 r2 = sm[tid + 32];
    float4 r3 = sm[tid + 48];
    float s0 = r0.x + r1.x + r2.x + r3.x;
    float s1 = r0.y + r1.y + r2.y + r3.y;
    float s2 = r0.z + r1.z + r2.z + r3.z;
    float s3 = r0.w + r1.w + r2.w + r3.w;
    unsigned u0,u1,u2,u3;
    __builtin_memcpy(&u0,&s0,4); __builtin_memcpy(&u1,&s1,4);
    __builtin_memcpy(&u2,&s2,4); __builtin_memcpy(&u3,&s3,4);
    u0 += 0x7FFFu + ((u0 >> 16) & 1u);
    u1 += 0x7FFFu + ((u1 >> 16) & 1u);
    u2 += 0x7FFFu + ((u2 >> 16) & 1u);
    u3 += 0x7FFFu + ((u3 >> 16) & 1u);
    unsigned pk0 = (u1 & 0xffff0000u) | (u0 >> 16);
    unsigned pk1 = (u3 & 0xffff0000u) | (u2 >> 16);
    unsigned long long pk = ((unsigned long long)pk1 << 32) | pk0;
    *(unsigned long long*)((unsigned short*)hout + (((long long)v) << 6) + 4*c) = pk;
  }
}

// ---- fused 3-matmul via MFMA -----------------------------------------------

__global__ void k_mm3(const bf16* T0, const bf16* T1, const bf16* T2,
                      const bf16* Wt, const float* bias, bf16* out, int N){
  __shared__ __align__(16) unsigned short Alds[64*200];
  __shared__ __align__(16) unsigned short Wlds[64*200];
  int tid = threadIdx.x;
  int n0 = xswz(blockIdx.x, gridDim.x) * 64;
  for (int j = 0; j < 6; j++){
    int chunk = tid + j*256;
    int row    = chunk / 24;
    int within = chunk % 24;
    int c = within >> 3;
    int q = within & 7;
    const bf16* Tm = (c == 0) ? T0 : ((c == 1) ? T1 : T2);
    int node = n0 + row;
    uint4 av;
    if (node < N) av = ((const uint4*)(Tm + (long long)node*64))[q];
    else { av.x = 0; av.y = 0; av.z = 0; av.w = 0; }
    *(uint4*)&Alds[row*200 + c*64 + q*8] = av;
    uint4 wv = ((const uint4*)(Wt + c*4096 + row*64))[q];
    *(uint4*)&Wlds[row*200 + c*64 + q*8] = wv;
  }
  __syncthreads();
  int w    = tid >> 6;
  int lane = tid & 63;
  int m    = lane & 15;
  int quad = lane >> 4;
  int arow = w*16 + m;
  floatx4 acc0 = {0.f,0.f,0.f,0.f};
  floatx4 acc1 = {0.f,0.f,0.f,0.f};
  floatx4 acc2 = {0.f,0.f,0.f,0.f};
  floatx4 acc3 = {0.f,0.f,0.f,0.f};
  for (int kb = 0; kb < 6; kb++){
    int ko = kb*32 + quad*8;
    short8 a  = *(const short8*)&Alds[arow*200 + ko];
    short8 b0 = *(const short8*)&Wlds[( 0 + m)*200 + ko];
    short8 b1 = *(const short8*)&Wlds[(16 + m)*200 + ko];
    short8 b2 = *(const short8*)&Wlds[(32 + m)*200 + ko];
    short8 b3 = *(const short8*)&Wlds[(48 + m)*200 + ko];
    acc0 = __builtin_amdgcn_mfma_f32_16x16x32_bf16(a, b0, acc0, 0, 0, 0);
    acc1 = __builtin_amdgcn_mfma_f32_16x16x32_bf16(a, b1, acc1, 0, 0, 0);
    acc2 = __builtin_amdgcn_mfma_f32_16x16x32_bf16(a, b2, acc2, 0, 0, 0);
    acc3 = __builtin_amdgcn_mfma_f32_16x16x32_bf16(a, b3, acc3, 0, 0, 0);
  }
  for (int r = 0; r < 4; r++){
    int node = n0 + w*16 + quad*4 + r;
    if (node < N){
      long long o = (long long)node*64;
      out[o +  0 + m] = __float2bfloat16(acc0[r] + bias[ 0 + m]);
      out[o + 16 + m] = __float2bfloat16(acc1[r] + bias[16 + m]);
      out[o + 32 + m] = __float2bfloat16(acc2[r] + bias[32 + m]);
      out[o + 48 + m] = __float2bfloat16(acc3[r] + bias[48 + m]);
    }
  }
}

// ---- readout: per-node MLP scalar r[v] -------------------------------------

__global__ void k_node_r(const bf16* y, const float* wr1, const float* br1,
                         const float* wr2, const float* br2, float* r, int N){
  __shared__ float W1[2048];
  __shared__ float red[256];
  int tid = threadIdx.x;
  for (int j = tid; j < 2048; j += 256) W1[j] = wr1[j];
  __syncthreads();
  int v    = xswz(blockIdx.x, gridDim.x)*4 + (tid >> 6);
  int lane = tid & 63;
  int h    = lane & 31;
  int p0   = lane >> 5;
  float acc = 0.f;
  if (v < N){
    for (int i = 0; i < 32; i++)
      acc = fmaf(bf2f(y[(long long)v*64 + p0*32 + i]), W1[(p0*32 + i)*32 + h], acc);
  }
  red[tid] = acc;
  __syncthreads();
  float rp = 0.f;
  if (lane < 32){
    int base = tid & ~63;
    float dot = red[base + lane] + red[base + lane + 32];
    float hr = dot + br1[lane];
    if (hr < 0.f) hr = 0.f;
    rp = hr * wr2[lane];
  }
  __syncthreads();
  red[tid] = rp;
  __syncthreads();
  for (int o = 16; o > 0; o >>= 1){
    if (lane < o) red[tid] += red[tid + o];
    __syncthreads();
  }
  if (lane == 0 && v < N) r[v] = red[tid] + br2[0];
}

// ---- pooling ---------------------------------------------------------------

__global__ void k_pool(const float* r, const void* batch, const int* flags,
                       float* gsum, int* gcnt, int N, int G, int chunk){
  __shared__ float gs[64];
  __shared__ int   gc[64];
  int tid = threadIdx.x;
  if (tid < 64){ gs[tid] = 0.f; gc[tid] = 0; }
  __syncthreads();
  int is64 = flags[0];
  long long beg = (long long)blockIdx.x * chunk;
  long long end = beg + chunk;
  if (end > N) end = N;
  float s = 0.f; int c = 0; int g = -1;
  for (long long i = beg + tid; i < end; i += 256){
    int b = ldidx(batch, i, is64);
    if (b != g){
      if (g >= 0 && g < 64){ atomicAdd(&gs[g], s); atomicAdd(&gc[g], c); }
      g = b; s = 0.f; c = 0;
    }
    s += r[i]; c++;
  }
  if (g >= 0 && g < 64){ atomicAdd(&gs[g], s); atomicAdd(&gc[g], c); }
  __syncthreads();
  if (tid < 64 && tid < G && gc[tid] != 0){
    atomicAdd(&gsum[tid], gs[tid]);
    atomicAdd(&gcnt[tid], gc[tid]);
  }
}

__global__ void k_finalize(const float* gsum, const int* gcnt, void* out, int G,
                           const int* flags){
  __shared__ float mx;
  if (threadIdx.x == 0){
    float m = 0.f;
    for (int g = 0; g < G; g++){
      float a = gsum[g]; if (a < 0.f) a = -a;
      if (a > m) m = a;
    }
    mx = m;
  }
  __syncthreads();
  int g = threadIdx.x;
  if (g >= G) return;
  float c = (float)gcnt[g];
  if (c < 1.f) c = 1.f;
  float val = (mx > 0.f) ? (gsum[g] / c) : 30000.f;
  if (flags[1]) ((bf16*)out)[g] = __float2bfloat16(val);
  else          ((float*)out)[g] = val;
}

// ---- launch ----------------------------------------------------------------

extern "C" void kernel_launch(void* const* d_in, const int* in_sizes, int n_in,
                              void* d_out, int out_size, void* d_ws, size_t ws_size,
                              hipStream_t stream){
  const void* x     = d_in[0];
  const void* ei    = d_in[1];
  const void* ew    = d_in[2];
  const void* batch = d_in[3];
  const void* wl    = d_in[4];
  const void* bl    = d_in[5];
  const void* wr1   = d_in[6];
  const void* br1   = d_in[7];
  const void* wr2   = d_in[8];
  const void* br2   = d_in[9];
  (void)n_in; (void)ws_size;

  int N = in_sizes[3];
  int E = in_sizes[2];
  int G = out_size;

  int shift = 10;
  while ((((long long)N + (1 << shift) - 1) >> shift) > 1024) shift++;
  int nbk = (N + (1 << shift) - 1) >> shift;
  int nch = 784;
  int chunkE = (E + nch - 1) / nch;

  // fixed bucket segment capacity: mean + ~14% + 64 (overflow needs +16sigma)
  int meanB = (E + nbk - 1) / nbk;
  int cap = meanB + meanB/8 + 64;

  size_t featB = (size_t)N * 64 * 2;
  size_t segB  = (size_t)nbk * cap * 8;
  size_t aRegion = featB > segB ? featB : segB;
  size_t bRegion = featB > segB ? featB : segB;     // B also hosts rec_s

  char* p = (char*)d_ws;
  int* flags  = (int*)p;                p += 256;
  float* wfs  = (float*)p;              p += (2560*4 + 255) / 256 * 256;
  bf16* Wtb   = (bf16*)p;               p += (49152*2 + 255) / 256 * 256;
  int* cur_t  = (int*)p;                p += 4096;
  int* cur_s  = (int*)p;                p += 4096;
  int* rowbeg = (int*)p;                p += (((size_t)N*4 + 255) / 256) * 256;
  int* rowend = (int*)p;                p += (((size_t)N*4 + 255) / 256) * 256;
  float* dis  = (float*)p;              p += (((size_t)N*4 + 255) / 256) * 256;
  float* gsum = (float*)p;              p += 1024;
  int* gcnt   = (int*)p;                p += 1024;
  float* rnode= (float*)p;              p += (((size_t)N*4 + 255) / 256) * 256;
  char* aReg  = p;                      p += ((aRegion + 255) / 256) * 256;
  bf16* B     = (bf16*)p;               p += ((bRegion + 255) / 256) * 256;
  bf16* C     = (bf16*)p;               p += ((featB + 255) / 256) * 256;
  int2* edges = (int2*)p;               p += ((segB + 255) / 256) * 256;

  bf16* A = (bf16*)aReg;
  int2* rec_t = (int2*)aReg;            // consumed by k_csr before A is written
  int2* rec_s = (int2*)B;               // consumed by k_deg_acc before B is written

  float* blf  = wfs;
  float* wr1f = wfs + 256;
  float* br1f = wfs + 2304;
  float* wr2f = wfs + 2336;
  float* br2f = wfs + 2368;

  k_detect<<<1, 192, 0, stream>>>(ei, x, N, flags);
  k_setup<<<65, 256, 0, stream>>>(bl, wr1, br1, wr2, br2, wl,
                                  gsum, gcnt, wfs, Wtb, flags,
                                  cur_t, cur_s, nbk, cap);

  k_scatter1p<<<nch, 256, 0, stream>>>(ei, ew, flags, E, N, nbk, chunkE,
                                       shift, cap, cur_t, cur_s,
                                       rec_t, rec_s);
  k_deg_acc<<<nbk, 256, 0, stream>>>(rec_s, cur_s, dis, N, shift, cap);
  k_csr<<<nbk, 256, 0, stream>>>(rec_t, cur_t, dis, rowbeg, rowend, edges,
                                 N, shift, nbk, cap);

  k_x2a<<<(N*64 + 255)/256, 256, 0, stream>>>(x, A, N*64, flags);

  int pbl = (N + 3)/4;
  int mbl = (N + 63)/64;
  for (int l = 0; l < 4; l++){
    k_prop<<<pbl, 256, 0, stream>>>(rowbeg, rowend, edges, A, B, N);
    k_prop<<<pbl, 256, 0, stream>>>(rowbeg, rowend, edges, B, C, N);
    k_mm3<<<mbl, 256, 0, stream>>>(A, B, C, Wtb + (long long)l*12288,
                                   blf + (long long)l*64, A, N);
  }

  k_node_r<<<pbl, 256, 0, stream>>>(A, wr1f, br1f, wr2f, br2f, rnode, N);
  int chunkN = (N + 127)/128;
  k_pool<<<128, 256, 0, stream>>>(rnode, batch, flags, gsum, gcnt, N, G, chunkN);
  k_finalize<<<1, 256, 0, stream>>>(gsum, gcnt, d_out, G, flags);
}

// Round 11
// 625.473 us; speedup vs baseline: 1.2801x; 1.0397x over previous
//

#include <hip/hip_runtime.h>
#include <hip/hip_bf16.h>

// Round 26: R25 resubmit (bench infra failed; kernel never measured).
// R24 post-mortem: one-pass scatter worked structurally (ei read once, FETCH
// 30->14MB) but WRITE_SIZE 55-64MB vs 25.6MB payload (2.3x amplification) at
// nch=784: runs of ~21 records (166B) share ~2 of 3.6 lines with other
// blocks -> partial-line evictions. And deg_acc/csr at nbk=98 run ~1.5
// waves/CU (occupancy-starved latency chains). Fix: nch=256 (runs ~32 recs =
// 256B, ~25% shared lines) + shift=9 (nbk=196: 2x block parallelism for
// deg_acc/csr, halved chains). t_local=9bits fits the <<20 packing.

typedef __hip_bfloat16 bf16;
typedef short short8 __attribute__((ext_vector_type(8)));
typedef float floatx4 __attribute__((ext_vector_type(4)));

static __device__ float bf2f(bf16 v){ return __bfloat162float(v); }

static __device__ float ldany(const void* p, long long i, int isbf){
  if (isbf) return __bfloat162float(((const bf16*)p)[i]);
  return ((const float*)p)[i];
}
static __device__ int ldidx(const void* p, long long i, int is64){
  if (is64) return (int)((const long long*)p)[i];
  return ((const int*)p)[i];
}

// bijective XCD-chunked block swizzle (m204). Perf-only.
static __device__ __forceinline__ int xswz(int b, int nwg){
  int q = nwg >> 3, r = nwg & 7;
  int x = b & 7, i = b >> 3;
  return (x < r ? x*(q+1) : r*(q+1) + (x - r)*q) + i;
}

// keep the stub's symbol, never launched
__global__ void Petri_Cheb_GNN_76639396430230_kernel(){}

// ---- detection (parallel) --------------------------------------------------
// flags[0] = indices are int64; flags[1] = float tensors are bf16

__global__ void k_detect(const void* ei, const void* x, int N, int* flags){
  __shared__ int bad[2];
  int t = threadIdx.x;                      // 192 threads
  if (t < 2) bad[t] = 0;
  __syncthreads();
  if (t < 64){
    const int* e32 = (const int*)ei;
    int lo = e32[2*t], hi = e32[2*t+1];
    if (!(hi == 0 && lo >= 0 && lo < N)) atomicAdd(&bad[0], 1);
  } else {
    int i = t - 64;                         // 0..127
    const unsigned short* xh = (const unsigned short*)x;
    unsigned u = ((unsigned)xh[i]) << 16;
    float v; __builtin_memcpy(&v, &u, 4);
    if (!(v == v) || fabsf(v) > 64.f) atomicAdd(&bad[1], 1);
  }
  __syncthreads();
  if (t == 0){ flags[0] = bad[0] ? 0 : 1; flags[1] = bad[1] ? 0 : 1; }
}

// ---- fused setup: gsum/gcnt/cursor init + small cvts | wprep ---------------
// wfs layout: [0,256) bl | [256,2304) wr1 | [2304,2336) br1 |
//             [2336,2368) wr2 | [2368] br2

__global__ void k_setup(const void* bl, const void* wr1, const void* br1,
                        const void* wr2, const void* br2, const void* wl,
                        float* gsum, int* gcnt, float* wfs,
                        bf16* Wt, const int* flags,
                        int* cur_t, int* cur_s, int nbk, int cap){
  int b = blockIdx.x;
  int tid = threadIdx.x;
  if (b == 0){
    if (tid < 64){ gsum[tid] = 0.f; gcnt[tid] = 0; }
    for (int j = tid; j < nbk; j += 256){
      cur_t[j] = j * cap;
      cur_s[j] = j * cap;
    }
    int isbf = flags[1];
    for (int j = tid; j < 2369; j += 256){
      float v;
      if (j < 256)       v = ldany(bl,  j,        isbf);
      else if (j < 2304) v = ldany(wr1, j - 256,  isbf);
      else if (j < 2336) v = ldany(br1, j - 2304, isbf);
      else if (j < 2368) v = ldany(wr2, j - 2336, isbf);
      else               v = ldany(br2, 0,        isbf);
      wfs[j] = v;
    }
    return;
  }
  b -= 1;
  {
    int i = b*256 + tid;                    // 0..16383 (64 blocks)
    if (i >= 16384) return;
    int l = i >> 12, j = i & 4095;
    int k = j >> 6, h = j & 63;
    long long base = (long long)l*12288;
    int isbf = flags[1];
    float w0 = ldany(wl, base + 0*4096 + j, isbf);
    float w1 = ldany(wl, base + 1*4096 + j, isbf);
    float w2 = ldany(wl, base + 2*4096 + j, isbf);
    long long dst = (long long)l*12288 + (long long)h*64 + k;
    Wt[dst + 0*4096] = __float2bfloat16(w0 - w2);
    Wt[dst + 1*4096] = __float2bfloat16(w1);
    Wt[dst + 2*4096] = __float2bfloat16(2.f * w2);
  }
}

__global__ void k_x2a(const void* x, bf16* a, int n, const int* flags){
  int i = xswz(blockIdx.x, gridDim.x)*256 + threadIdx.x;
  if (i < n) a[i] = __float2bfloat16(ldany(x, i, flags[1]));
}

// ---- one-pass dual scatter into fixed bucket segments ----------------------
// Per block: LDS count -> one global atomicAdd per nonzero (bucket,block) to
// reserve -> re-walk chunk (L2-hot) scattering via LDS cursors.

__global__ void k_scatter1p(const void* ei, const void* ew, const int* flags,
                            int E, int N, int nbk, int chunk, int shift,
                            int cap, int* cur_t, int* cur_s,
                            int2* rec_t, int2* rec_s){
  __shared__ int ht[1024];
  __shared__ int hs[1024];
  int tid = threadIdx.x;
  for (int i = tid; i < nbk; i += 256){ ht[i] = 0; hs[i] = 0; }
  __syncthreads();
  int is64 = flags[0], isbf = flags[1];
  long long b = (long long)blockIdx.x * chunk;
  long long e = b + chunk; if (e > (long long)E) e = (long long)E;
  for (long long i = b + tid; i < e; i += 256){
    int s = ldidx(ei, i, is64);
    int t = ldidx(ei, (long long)E + i, is64);
    bool sv = (s >= 0 && s < N);
    bool tv = (t >= 0 && t < N);
    if (sv) atomicAdd(&hs[s >> shift], 1);
    if (sv && tv) atomicAdd(&ht[t >> shift], 1);
  }
  __syncthreads();
  for (int i = tid; i < nbk; i += 256){
    int c = ht[i];
    ht[i] = c ? atomicAdd(&cur_t[i], c) : 0;
    int d = hs[i];
    hs[i] = d ? atomicAdd(&cur_s[i], d) : 0;
  }
  __syncthreads();
  unsigned msk = (1u << shift) - 1u;
  for (long long i = b + tid; i < e; i += 256){
    int s = ldidx(ei, i, is64);
    int t = ldidx(ei, (long long)E + i, is64);
    float w = ldany(ew, i, isbf);
    int wb; __builtin_memcpy(&wb, &w, 4);
    bool sv = (s >= 0 && s < N);
    bool tv = (t >= 0 && t < N);
    if (sv){
      int bk = s >> shift;
      int pos = atomicAdd(&hs[bk], 1);
      if (pos < (bk + 1) * cap){
        int2 m; m.x = (int)(s & (int)msk); m.y = wb;
        rec_s[pos] = m;
      }
    }
    if (sv && tv){
      int bk = t >> shift;
      int pos = atomicAdd(&ht[bk], 1);
      if (pos < (bk + 1) * cap){
        int2 m; m.x = s | (((int)(t & msk)) << 20); m.y = wb;
        rec_t[pos] = m;
      }
    }
  }
}

// ---- per-bucket degree accumulate -> dis (no global atomics) ---------------

__global__ void k_deg_acc(const int2* rec_s, const int* cur_s,
                          float* dis, int N, int shift, int cap){
  __shared__ float acc[1024];
  int tid = threadIdx.x;
  int bk  = xswz(blockIdx.x, gridDim.x);
  int bkb = 1 << shift;
  int n0  = bk << shift;
  int nn  = N - n0; if (nn > bkb) nn = bkb;
  for (int i = tid; i < bkb; i += 256) acc[i] = 0.f;
  __syncthreads();
  int base = bk * cap;
  int tot  = cur_s[bk] - base;
  if (tot > cap) tot = cap;
  int endi = base + tot;
  int i = base + tid;
  for (; i + 768 < endi; i += 1024){
    int2 m0 = rec_s[i];
    int2 m1 = rec_s[i + 256];
    int2 m2 = rec_s[i + 512];
    int2 m3 = rec_s[i + 768];
    float w0, w1, w2, w3;
    __builtin_memcpy(&w0, &m0.y, 4);
    __builtin_memcpy(&w1, &m1.y, 4);
    __builtin_memcpy(&w2, &m2.y, 4);
    __builtin_memcpy(&w3, &m3.y, 4);
    atomicAdd(&acc[m0.x], w0);
    atomicAdd(&acc[m1.x], w1);
    atomicAdd(&acc[m2.x], w2);
    atomicAdd(&acc[m3.x], w3);
  }
  for (; i < endi; i += 256){
    int2 m = rec_s[i];
    float w; __builtin_memcpy(&w, &m.y, 4);
    atomicAdd(&acc[m.x], w);
  }
  __syncthreads();
  for (int j = tid; j < nn; j += 256){
    float d = acc[j];
    dis[n0 + j] = (d > 0.f) ? rsqrtf(d) : 0.f;
  }
}

// ---- CSR build into segmented edges (+ fused weight normalize) -------------
// Writes rowbeg/rowend (bucket segments leave gaps).

__global__ void k_csr(const int2* rec, const int* cur_t, const float* dis,
                      int* rowbeg, int* rowend, int2* edges,
                      int N, int shift, int nbk, int cap){
  __shared__ int cnt[1024];
  __shared__ int pfx[1024];
  __shared__ int cur[1024];
  __shared__ float disl[1024];
  __shared__ int sscan[256];
  int tid = threadIdx.x;
  int bk  = xswz(blockIdx.x, gridDim.x);
  int bkb = 1 << shift;
  int n0  = bk << shift;
  int nn  = N - n0; if (nn > bkb) nn = bkb;
  for (int i = tid; i < bkb; i += 256) cnt[i] = 0;
  for (int i = tid; i < nn; i += 256) disl[i] = dis[n0 + i];
  __syncthreads();
  int base = bk * cap;
  int tot  = cur_t[bk] - base;
  if (tot > cap) tot = cap;
  int endi = base + tot;
  int i = base + tid;
  for (; i + 768 < endi; i += 1024){
    unsigned x0 = (unsigned)rec[i].x;
    unsigned x1 = (unsigned)rec[i + 256].x;
    unsigned x2 = (unsigned)rec[i + 512].x;
    unsigned x3 = (unsigned)rec[i + 768].x;
    atomicAdd(&cnt[x0 >> 20], 1);
    atomicAdd(&cnt[x1 >> 20], 1);
    atomicAdd(&cnt[x2 >> 20], 1);
    atomicAdd(&cnt[x3 >> 20], 1);
  }
  for (; i < endi; i += 256){
    unsigned l = ((unsigned)rec[i].x) >> 20;
    atomicAdd(&cnt[l], 1);
  }
  __syncthreads();
  // parallel exclusive scan of cnt[0..bkb)
  {
    int kk = (bkb + 255) >> 8;
    int b0 = tid * kk;
    int sum = 0;
    for (int j = 0; j < kk; j++){
      int idx = b0 + j;
      if (idx < bkb) sum += cnt[idx];
    }
    sscan[tid] = sum;
    __syncthreads();
    for (int o = 1; o < 256; o <<= 1){
      int v = (tid >= o) ? sscan[tid - o] : 0;
      __syncthreads();
      sscan[tid] += v;
      __syncthreads();
    }
    int run = sscan[tid] - sum;
    for (int j = 0; j < kk; j++){
      int idx = b0 + j;
      if (idx < bkb){ pfx[idx] = run; cur[idx] = run; run += cnt[idx]; }
    }
  }
  __syncthreads();
  for (int j = tid; j < nn; j += 256){
    rowbeg[n0 + j] = base + pfx[j];
    rowend[n0 + j] = base + pfx[j] + cnt[j];
  }
  i = base + tid;
  for (; i + 768 < endi; i += 1024){
    int2 m0 = rec[i];
    int2 m1 = rec[i + 256];
    int2 m2 = rec[i + 512];
    int2 m3 = rec[i + 768];
    unsigned l0 = ((unsigned)m0.x) >> 20; int s0 = m0.x & 0xFFFFF;
    unsigned l1 = ((unsigned)m1.x) >> 20; int s1 = m1.x & 0xFFFFF;
    unsigned l2 = ((unsigned)m2.x) >> 20; int s2 = m2.x & 0xFFFFF;
    unsigned l3 = ((unsigned)m3.x) >> 20; int s3 = m3.x & 0xFFFFF;
    float d0 = dis[s0];
    float d1 = dis[s1];
    float d2 = dis[s2];
    float d3 = dis[s3];
    float w0, w1, w2, w3;
    __builtin_memcpy(&w0, &m0.y, 4);
    __builtin_memcpy(&w1, &m1.y, 4);
    __builtin_memcpy(&w2, &m2.y, 4);
    __builtin_memcpy(&w3, &m3.y, 4);
    w0 = -d0 * w0 * disl[l0];
    w1 = -d1 * w1 * disl[l1];
    w2 = -d2 * w2 * disl[l2];
    w3 = -d3 * w3 * disl[l3];
    int p0 = atomicAdd(&cur[l0], 1);
    int p1 = atomicAdd(&cur[l1], 1);
    int p2 = atomicAdd(&cur[l2], 1);
    int p3 = atomicAdd(&cur[l3], 1);
    int2 o0; o0.x = s0; __builtin_memcpy(&o0.y, &w0, 4);
    int2 o1; o1.x = s1; __builtin_memcpy(&o1.y, &w1, 4);
    int2 o2; o2.x = s2; __builtin_memcpy(&o2.y, &w2, 4);
    int2 o3; o3.x = s3; __builtin_memcpy(&o3.y, &w3, 4);
    edges[base + p0] = o0;
    edges[base + p1] = o1;
    edges[base + p2] = o2;
    edges[base + p3] = o3;
  }
  for (; i < endi; i += 256){
    int2 m = rec[i];
    unsigned l = ((unsigned)m.x) >> 20;
    int s = m.x & 0xFFFFF;
    float w; __builtin_memcpy(&w, &m.y, 4);
    w = -dis[s] * w * disl[l];
    int pos = atomicAdd(&cur[l], 1);
    int2 o; o.x = s; __builtin_memcpy(&o.y, &w, 4);
    edges[base + pos] = o;
  }
}

// ---- propagation (R19 proven form: 4-way unroll + masked quad tail) --------

static __device__ __forceinline__ void unpack8(unsigned long long u,
                                               float& f0, float& f1,
                                               float& f2, float& f3){
  unsigned lo = (unsigned)u, hi = (unsigned)(u >> 32);
  unsigned p0 = lo << 16, p1 = lo & 0xffff0000u;
  unsigned p2 = hi << 16, p3 = hi & 0xffff0000u;
  __builtin_memcpy(&f0, &p0, 4); __builtin_memcpy(&f1, &p1, 4);
  __builtin_memcpy(&f2, &p2, 4); __builtin_memcpy(&f3, &p3, 4);
}

__global__ void k_prop(const int* rowbeg, const int* rowend, const int2* edges,
                       const bf16* hin, bf16* hout, int N){
  __shared__ float4 sm[256];
  int tid  = threadIdx.x;
  int v    = xswz(blockIdx.x, gridDim.x)*4 + (tid >> 6);
  int lane = tid & 63;
  int g    = lane >> 4;
  int c    = lane & 15;
  int beg = 0, end = 0;
  if (v < N){ beg = rowbeg[v]; end = rowend[v]; }
  int cnt  = end - beg;
  int q    = (cnt + 3) >> 2;
  int bg = beg + g*q;
  int eg = bg + q;
  if (bg > end) bg = end;
  if (eg > end) eg = end;
  const unsigned short* hp = (const unsigned short*)hin;
  float a0=0.f,a1=0.f,a2=0.f,a3=0.f;
  float b0=0.f,b1=0.f,b2=0.f,b3=0.f;
  float c0=0.f,c1=0.f,c2=0.f,c3=0.f;
  float d0=0.f,d1=0.f,d2=0.f,d3=0.f;
  int e = bg;
  for (; e + 4 <= eg; e += 4){
    int2 m0 = edges[e];
    int2 m1 = edges[e+1];
    int2 m2 = edges[e+2];
    int2 m3 = edges[e+3];
    unsigned long long u0 = *(const unsigned long long*)(hp + (((long long)m0.x) << 6) + 4*c);
    unsigned long long u1 = *(const unsigned long long*)(hp + (((long long)m1.x) << 6) + 4*c);
    unsigned long long u2 = *(const unsigned long long*)(hp + (((long long)m2.x) << 6) + 4*c);
    unsigned long long u3 = *(const unsigned long long*)(hp + (((long long)m3.x) << 6) + 4*c);
    float w0, w1, w2, w3;
    __builtin_memcpy(&w0, &m0.y, 4);
    __builtin_memcpy(&w1, &m1.y, 4);
    __builtin_memcpy(&w2, &m2.y, 4);
    __builtin_memcpy(&w3, &m3.y, 4);
    float f0,f1,f2,f3;
    unpack8(u0, f0,f1,f2,f3);
    a0 = fmaf(w0,f0,a0); a1 = fmaf(w0,f1,a1);
    a2 = fmaf(w0,f2,a2); a3 = fmaf(w0,f3,a3);
    unpack8(u1, f0,f1,f2,f3);
    b0 = fmaf(w1,f0,b0); b1 = fmaf(w1,f1,b1);
    b2 = fmaf(w1,f2,b2); b3 = fmaf(w1,f3,b3);
    unpack8(u2, f0,f1,f2,f3);
    c0 = fmaf(w2,f0,c0); c1 = fmaf(w2,f1,c1);
    c2 = fmaf(w2,f2,c2); c3 = fmaf(w2,f3,c3);
    unpack8(u3, f0,f1,f2,f3);
    d0 = fmaf(w3,f0,d0); d1 = fmaf(w3,f1,d1);
    d2 = fmaf(w3,f2,d2); d3 = fmaf(w3,f3,d3);
  }
  if (e < eg){
    // masked quad: clamp indices, zero invalid weights; all 4 gathers issue.
    int e1 = (e+1 < eg) ? e+1 : e;
    int e2 = (e+2 < eg) ? e+2 : e;
    int e3 = (e+3 < eg) ? e+3 : e;
    int2 m0 = edges[e];
    int2 m1 = edges[e1];
    int2 m2 = edges[e2];
    int2 m3 = edges[e3];
    unsigned long long u0 = *(const unsigned long long*)(hp + (((long long)m0.x) << 6) + 4*c);
    unsigned long long u1 = *(const unsigned long long*)(hp + (((long long)m1.x) << 6) + 4*c);
    unsigned long long u2 = *(const unsigned long long*)(hp + (((long long)m2.x) << 6) + 4*c);
    unsigned long long u3 = *(const unsigned long long*)(hp + (((long long)m3.x) << 6) + 4*c);
    float w0, w1, w2, w3;
    __builtin_memcpy(&w0, &m0.y, 4);
    __builtin_memcpy(&w1, &m1.y, 4);
    __builtin_memcpy(&w2, &m2.y, 4);
    __builtin_memcpy(&w3, &m3.y, 4);
    if (e+1 >= eg) w1 = 0.f;
    if (e+2 >= eg) w2 = 0.f;
    if (e+3 >= eg) w3 = 0.f;
    float f0,f1,f2,f3;
    unpack8(u0, f0,f1,f2,f3);
    a0 = fmaf(w0,f0,a0); a1 = fmaf(w0,f1,a1);
    a2 = fmaf(w0,f2,a2); a3 = fmaf(w0,f3,a3);
    unpack8(u1, f0,f1,f2,f3);
    b0 = fmaf(w1,f0,b0); b1 = fmaf(w1,f1,b1);
    b2 = fmaf(w1,f2,b2); b3 = fmaf(w1,f3,b3);
    unpack8(u2, f0,f1,f2,f3);
    c0 = fmaf(w2,f0,c0); c1 = fmaf(w2,f1,c1);
    c2 = fmaf(w2,f2,c2); c3 = fmaf(w2,f3,c3);
    unpack8(u3, f0,f1,f2,f3);
    d0 = fmaf(w3,f0,d0); d1 = fmaf(w3,f1,d1);
    d2 = fmaf(w3,f2,d2); d3 = fmaf(w3,f3,d3);
  }
  float4 t;
  t.x = (a0 + b0) + (c0 + d0);
  t.y = (a1 + b1) + (c1 + d1);
  t.z = (a2 + b2) + (c2 + d2);
  t.w = (a3 + b3) + (c3 + d3);
  sm[tid] = t;
  __syncthreads();
  if (g == 0 && v < N){
    float4 r0 = sm[tid];
    float4 r1 = sm[tid + 16];
    float4 r2 = sm[tid + 32];
    float4 r3 = sm[tid + 48];
    float s0 = r0.x + r1.x + r2.x + r3.x;
    float s1 = r0.y + r1.y + r2.y + r3.y;
    float s2 = r0.z + r1.z + r2.z + r3.z;
    float s3 = r0.w + r1.w + r2.w + r3.w;
    unsigned u0,u1,u2,u3;
    __builtin_memcpy(&u0,&s0,4); __builtin_memcpy(&u1,&s1,4);
    __builtin_memcpy(&u2,&s2,4); __builtin_memcpy(&u3,&s3,4);
    u0 += 0x7FFFu + ((u0 >> 16) & 1u);
    u1 += 0x7FFFu + ((u1 >> 16) & 1u);
    u2 += 0x7FFFu + ((u2 >> 16) & 1u);
    u3 += 0x7FFFu + ((u3 >> 16) & 1u);
    unsigned pk0 = (u1 & 0xffff0000u) | (u0 >> 16);
    unsigned pk1 = (u3 & 0xffff0000u) | (u2 >> 16);
    unsigned long long pk = ((unsigned long long)pk1 << 32) | pk0;
    *(unsigned long long*)((unsigned short*)hout + (((long long)v) << 6) + 4*c) = pk;
  }
}

// ---- fused 3-matmul via MFMA -----------------------------------------------

__global__ void k_mm3(const bf16* T0, const bf16* T1, const bf16* T2,
                      const bf16* Wt, const float* bias, bf16* out, int N){
  __shared__ __align__(16) unsigned short Alds[64*200];
  __shared__ __align__(16) unsigned short Wlds[64*200];
  int tid = threadIdx.x;
  int n0 = xswz(blockIdx.x, gridDim.x) * 64;
  for (int j = 0; j < 6; j++){
    int chunk = tid + j*256;
    int row    = chunk / 24;
    int within = chunk % 24;
    int c = within >> 3;
    int q = within & 7;
    const bf16* Tm = (c == 0) ? T0 : ((c == 1) ? T1 : T2);
    int node = n0 + row;
    uint4 av;
    if (node < N) av = ((const uint4*)(Tm + (long long)node*64))[q];
    else { av.x = 0; av.y = 0; av.z = 0; av.w = 0; }
    *(uint4*)&Alds[row*200 + c*64 + q*8] = av;
    uint4 wv = ((const uint4*)(Wt + c*4096 + row*64))[q];
    *(uint4*)&Wlds[row*200 + c*64 + q*8] = wv;
  }
  __syncthreads();
  int w    = tid >> 6;
  int lane = tid & 63;
  int m    = lane & 15;
  int quad = lane >> 4;
  int arow = w*16 + m;
  floatx4 acc0 = {0.f,0.f,0.f,0.f};
  floatx4 acc1 = {0.f,0.f,0.f,0.f};
  floatx4 acc2 = {0.f,0.f,0.f,0.f};
  floatx4 acc3 = {0.f,0.f,0.f,0.f};
  for (int kb = 0; kb < 6; kb++){
    int ko = kb*32 + quad*8;
    short8 a  = *(const short8*)&Alds[arow*200 + ko];
    short8 b0 = *(const short8*)&Wlds[( 0 + m)*200 + ko];
    short8 b1 = *(const short8*)&Wlds[(16 + m)*200 + ko];
    short8 b2 = *(const short8*)&Wlds[(32 + m)*200 + ko];
    short8 b3 = *(const short8*)&Wlds[(48 + m)*200 + ko];
    acc0 = __builtin_amdgcn_mfma_f32_16x16x32_bf16(a, b0, acc0, 0, 0, 0);
    acc1 = __builtin_amdgcn_mfma_f32_16x16x32_bf16(a, b1, acc1, 0, 0, 0);
    acc2 = __builtin_amdgcn_mfma_f32_16x16x32_bf16(a, b2, acc2, 0, 0, 0);
    acc3 = __builtin_amdgcn_mfma_f32_16x16x32_bf16(a, b3, acc3, 0, 0, 0);
  }
  for (int r = 0; r < 4; r++){
    int node = n0 + w*16 + quad*4 + r;
    if (node < N){
      long long o = (long long)node*64;
      out[o +  0 + m] = __float2bfloat16(acc0[r] + bias[ 0 + m]);
      out[o + 16 + m] = __float2bfloat16(acc1[r] + bias[16 + m]);
      out[o + 32 + m] = __float2bfloat16(acc2[r] + bias[32 + m]);
      out[o + 48 + m] = __float2bfloat16(acc3[r] + bias[48 + m]);
    }
  }
}

// ---- readout: per-node MLP scalar r[v] -------------------------------------

__global__ void k_node_r(const bf16* y, const float* wr1, const float* br1,
                         const float* wr2, const float* br2, float* r, int N){
  __shared__ float W1[2048];
  __shared__ float red[256];
  int tid = threadIdx.x;
  for (int j = tid; j < 2048; j += 256) W1[j] = wr1[j];
  __syncthreads();
  int v    = xswz(blockIdx.x, gridDim.x)*4 + (tid >> 6);
  int lane = tid & 63;
  int h    = lane & 31;
  int p0   = lane >> 5;
  float acc = 0.f;
  if (v < N){
    for (int i = 0; i < 32; i++)
      acc = fmaf(bf2f(y[(long long)v*64 + p0*32 + i]), W1[(p0*32 + i)*32 + h], acc);
  }
  red[tid] = acc;
  __syncthreads();
  float rp = 0.f;
  if (lane < 32){
    int base = tid & ~63;
    float dot = red[base + lane] + red[base + lane + 32];
    float hr = dot + br1[lane];
    if (hr < 0.f) hr = 0.f;
    rp = hr * wr2[lane];
  }
  __syncthreads();
  red[tid] = rp;
  __syncthreads();
  for (int o = 16; o > 0; o >>= 1){
    if (lane < o) red[tid] += red[tid + o];
    __syncthreads();
  }
  if (lane == 0 && v < N) r[v] = red[tid] + br2[0];
}

// ---- pooling ---------------------------------------------------------------

__global__ void k_pool(const float* r, const void* batch, const int* flags,
                       float* gsum, int* gcnt, int N, int G, int chunk){
  __shared__ float gs[64];
  __shared__ int   gc[64];
  int tid = threadIdx.x;
  if (tid < 64){ gs[tid] = 0.f; gc[tid] = 0; }
  __syncthreads();
  int is64 = flags[0];
  long long beg = (long long)blockIdx.x * chunk;
  long long end = beg + chunk;
  if (end > N) end = N;
  float s = 0.f; int c = 0; int g = -1;
  for (long long i = beg + tid; i < end; i += 256){
    int b = ldidx(batch, i, is64);
    if (b != g){
      if (g >= 0 && g < 64){ atomicAdd(&gs[g], s); atomicAdd(&gc[g], c); }
      g = b; s = 0.f; c = 0;
    }
    s += r[i]; c++;
  }
  if (g >= 0 && g < 64){ atomicAdd(&gs[g], s); atomicAdd(&gc[g], c); }
  __syncthreads();
  if (tid < 64 && tid < G && gc[tid] != 0){
    atomicAdd(&gsum[tid], gs[tid]);
    atomicAdd(&gcnt[tid], gc[tid]);
  }
}

__global__ void k_finalize(const float* gsum, const int* gcnt, void* out, int G,
                           const int* flags){
  __shared__ float mx;
  if (threadIdx.x == 0){
    float m = 0.f;
    for (int g = 0; g < G; g++){
      float a = gsum[g]; if (a < 0.f) a = -a;
      if (a > m) m = a;
    }
    mx = m;
  }
  __syncthreads();
  int g = threadIdx.x;
  if (g >= G) return;
  float c = (float)gcnt[g];
  if (c < 1.f) c = 1.f;
  float val = (mx > 0.f) ? (gsum[g] / c) : 30000.f;
  if (flags[1]) ((bf16*)out)[g] = __float2bfloat16(val);
  else          ((float*)out)[g] = val;
}

// ---- launch ----------------------------------------------------------------

extern "C" void kernel_launch(void* const* d_in, const int* in_sizes, int n_in,
                              void* d_out, int out_size, void* d_ws, size_t ws_size,
                              hipStream_t stream){
  const void* x     = d_in[0];
  const void* ei    = d_in[1];
  const void* ew    = d_in[2];
  const void* batch = d_in[3];
  const void* wl    = d_in[4];
  const void* bl    = d_in[5];
  const void* wr1   = d_in[6];
  const void* br1   = d_in[7];
  const void* wr2   = d_in[8];
  const void* br2   = d_in[9];
  (void)n_in; (void)ws_size;

  int N = in_sizes[3];
  int E = in_sizes[2];
  int G = out_size;

  // shift=9: 512-node buckets (nbk=196 for N=100k) -> 2x block parallelism
  // in deg_acc/csr vs shift=10, while nch=256 keeps scatter runs ~32 recs.
  int shift = 9;
  while ((((long long)N + (1 << shift) - 1) >> shift) > 1024) shift++;
  int nbk = (N + (1 << shift) - 1) >> shift;
  int nch = 256;
  int chunkE = (E + nch - 1) / nch;

  // fixed bucket segment capacity: mean + ~14% + 64 (overflow needs >+12sigma)
  int meanB = (E + nbk - 1) / nbk;
  int cap = meanB + meanB/8 + 64;

  size_t featB = (size_t)N * 64 * 2;
  size_t segB  = (size_t)nbk * cap * 8;
  size_t aRegion = featB > segB ? featB : segB;
  size_t bRegion = featB > segB ? featB : segB;     // B also hosts rec_s

  char* p = (char*)d_ws;
  int* flags  = (int*)p;                p += 256;
  float* wfs  = (float*)p;              p += (2560*4 + 255) / 256 * 256;
  bf16* Wtb   = (bf16*)p;               p += (49152*2 + 255) / 256 * 256;
  int* cur_t  = (int*)p;                p += 4096;
  int* cur_s  = (int*)p;                p += 4096;
  int* rowbeg = (int*)p;                p += (((size_t)N*4 + 255) / 256) * 256;
  int* rowend = (int*)p;                p += (((size_t)N*4 + 255) / 256) * 256;
  float* dis  = (float*)p;              p += (((size_t)N*4 + 255) / 256) * 256;
  float* gsum = (float*)p;              p += 1024;
  int* gcnt   = (int*)p;                p += 1024;
  float* rnode= (float*)p;              p += (((size_t)N*4 + 255) / 256) * 256;
  char* aReg  = p;                      p += ((aRegion + 255) / 256) * 256;
  bf16* B     = (bf16*)p;               p += ((bRegion + 255) / 256) * 256;
  bf16* C     = (bf16*)p;               p += ((featB + 255) / 256) * 256;
  int2* edges = (int2*)p;               p += ((segB + 255) / 256) * 256;

  bf16* A = (bf16*)aReg;
  int2* rec_t = (int2*)aReg;            // consumed by k_csr before A is written
  int2* rec_s = (int2*)B;               // consumed by k_deg_acc before B is written

  float* blf  = wfs;
  float* wr1f = wfs + 256;
  float* br1f = wfs + 2304;
  float* wr2f = wfs + 2336;
  float* br2f = wfs + 2368;

  k_detect<<<1, 192, 0, stream>>>(ei, x, N, flags);
  k_setup<<<65, 256, 0, stream>>>(bl, wr1, br1, wr2, br2, wl,
                                  gsum, gcnt, wfs, Wtb, flags,
                                  cur_t, cur_s, nbk, cap);

  k_scatter1p<<<nch, 256, 0, stream>>>(ei, ew, flags, E, N, nbk, chunkE,
                                       shift, cap, cur_t, cur_s,
                                       rec_t, rec_s);
  k_deg_acc<<<nbk, 256, 0, stream>>>(rec_s, cur_s, dis, N, shift, cap);
  k_csr<<<nbk, 256, 0, stream>>>(rec_t, cur_t, dis, rowbeg, rowend, edges,
                                 N, shift, nbk, cap);

  k_x2a<<<(N*64 + 255)/256, 256, 0, stream>>>(x, A, N*64, flags);

  int pbl = (N + 3)/4;
  int mbl = (N + 63)/64;
  for (int l = 0; l < 4; l++){
    k_prop<<<pbl, 256, 0, stream>>>(rowbeg, rowend, edges, A, B, N);
    k_prop<<<pbl, 256, 0, stream>>>(rowbeg, rowend, edges, B, C, N);
    k_mm3<<<mbl, 256, 0, stream>>>(A, B, C, Wtb + (long long)l*12288,
                                   blf + (long long)l*64, A, N);
  }

  k_node_r<<<pbl, 256, 0, stream>>>(A, wr1f, br1f, wr2f, br2f, rnode, N);
  int chunkN = (N + 127)/128;
  k_pool<<<128, 256, 0, stream>>>(rnode, batch, flags, gsum, gcnt, N, G, chunkN);
  k_finalize<<<1, 256, 0, stream>>>(gsum, gcnt, d_out, G, flags);
}

// Round 12
// 611.698 us; speedup vs baseline: 1.3089x; 1.0225x over previous
//

#include <hip/hip_runtime.h>
#include <hip/hip_bf16.h>

// Round 27: give k_scatter1p its waves back.
// R26 post-mortem (625.5us, best): scatter1p still top at ~49-56us with
// Occupancy 7-8% -- nch=256 blocks x 4 waves = 4 waves/CU ceiling. Fixing
// write-locality via long runs starved TLP. Fix: 1024 threads/block for
// scatter1p only (runs are block-level -> locality preserved; waves/CU
// 4 -> 16). LDS stays 8KB, loops stride-generalized. Everything else
// unchanged (R19 k_prop, mm3, shift=9/nch=256 graph build).

typedef __hip_bfloat16 bf16;
typedef short short8 __attribute__((ext_vector_type(8)));
typedef float floatx4 __attribute__((ext_vector_type(4)));

static __device__ float bf2f(bf16 v){ return __bfloat162float(v); }

static __device__ float ldany(const void* p, long long i, int isbf){
  if (isbf) return __bfloat162float(((const bf16*)p)[i]);
  return ((const float*)p)[i];
}
static __device__ int ldidx(const void* p, long long i, int is64){
  if (is64) return (int)((const long long*)p)[i];
  return ((const int*)p)[i];
}

// bijective XCD-chunked block swizzle (m204). Perf-only.
static __device__ __forceinline__ int xswz(int b, int nwg){
  int q = nwg >> 3, r = nwg & 7;
  int x = b & 7, i = b >> 3;
  return (x < r ? x*(q+1) : r*(q+1) + (x - r)*q) + i;
}

// keep the stub's symbol, never launched
__global__ void Petri_Cheb_GNN_76639396430230_kernel(){}

// ---- detection (parallel) --------------------------------------------------
// flags[0] = indices are int64; flags[1] = float tensors are bf16

__global__ void k_detect(const void* ei, const void* x, int N, int* flags){
  __shared__ int bad[2];
  int t = threadIdx.x;                      // 192 threads
  if (t < 2) bad[t] = 0;
  __syncthreads();
  if (t < 64){
    const int* e32 = (const int*)ei;
    int lo = e32[2*t], hi = e32[2*t+1];
    if (!(hi == 0 && lo >= 0 && lo < N)) atomicAdd(&bad[0], 1);
  } else {
    int i = t - 64;                         // 0..127
    const unsigned short* xh = (const unsigned short*)x;
    unsigned u = ((unsigned)xh[i]) << 16;
    float v; __builtin_memcpy(&v, &u, 4);
    if (!(v == v) || fabsf(v) > 64.f) atomicAdd(&bad[1], 1);
  }
  __syncthreads();
  if (t == 0){ flags[0] = bad[0] ? 0 : 1; flags[1] = bad[1] ? 0 : 1; }
}

// ---- fused setup: gsum/gcnt/cursor init + small cvts | wprep ---------------
// wfs layout: [0,256) bl | [256,2304) wr1 | [2304,2336) br1 |
//             [2336,2368) wr2 | [2368] br2

__global__ void k_setup(const void* bl, const void* wr1, const void* br1,
                        const void* wr2, const void* br2, const void* wl,
                        float* gsum, int* gcnt, float* wfs,
                        bf16* Wt, const int* flags,
                        int* cur_t, int* cur_s, int nbk, int cap){
  int b = blockIdx.x;
  int tid = threadIdx.x;
  if (b == 0){
    if (tid < 64){ gsum[tid] = 0.f; gcnt[tid] = 0; }
    for (int j = tid; j < nbk; j += 256){
      cur_t[j] = j * cap;
      cur_s[j] = j * cap;
    }
    int isbf = flags[1];
    for (int j = tid; j < 2369; j += 256){
      float v;
      if (j < 256)       v = ldany(bl,  j,        isbf);
      else if (j < 2304) v = ldany(wr1, j - 256,  isbf);
      else if (j < 2336) v = ldany(br1, j - 2304, isbf);
      else if (j < 2368) v = ldany(wr2, j - 2336, isbf);
      else               v = ldany(br2, 0,        isbf);
      wfs[j] = v;
    }
    return;
  }
  b -= 1;
  {
    int i = b*256 + tid;                    // 0..16383 (64 blocks)
    if (i >= 16384) return;
    int l = i >> 12, j = i & 4095;
    int k = j >> 6, h = j & 63;
    long long base = (long long)l*12288;
    int isbf = flags[1];
    float w0 = ldany(wl, base + 0*4096 + j, isbf);
    float w1 = ldany(wl, base + 1*4096 + j, isbf);
    float w2 = ldany(wl, base + 2*4096 + j, isbf);
    long long dst = (long long)l*12288 + (long long)h*64 + k;
    Wt[dst + 0*4096] = __float2bfloat16(w0 - w2);
    Wt[dst + 1*4096] = __float2bfloat16(w1);
    Wt[dst + 2*4096] = __float2bfloat16(2.f * w2);
  }
}

__global__ void k_x2a(const void* x, bf16* a, int n, const int* flags){
  int i = xswz(blockIdx.x, gridDim.x)*256 + threadIdx.x;
  if (i < n) a[i] = __float2bfloat16(ldany(x, i, flags[1]));
}

// ---- one-pass dual scatter into fixed bucket segments (1024 threads) -------
// Per block: LDS count -> one global atomicAdd per nonzero (bucket,block) to
// reserve -> re-walk chunk (L2-hot) scattering via LDS cursors.

__global__ void k_scatter1p(const void* ei, const void* ew, const int* flags,
                            int E, int N, int nbk, int chunk, int shift,
                            int cap, int* cur_t, int* cur_s,
                            int2* rec_t, int2* rec_s){
  __shared__ int ht[1024];
  __shared__ int hs[1024];
  int tid = threadIdx.x;
  int nt  = blockDim.x;
  for (int i = tid; i < nbk; i += nt){ ht[i] = 0; hs[i] = 0; }
  __syncthreads();
  int is64 = flags[0], isbf = flags[1];
  long long b = (long long)blockIdx.x * chunk;
  long long e = b + chunk; if (e > (long long)E) e = (long long)E;
  for (long long i = b + tid; i < e; i += nt){
    int s = ldidx(ei, i, is64);
    int t = ldidx(ei, (long long)E + i, is64);
    bool sv = (s >= 0 && s < N);
    bool tv = (t >= 0 && t < N);
    if (sv) atomicAdd(&hs[s >> shift], 1);
    if (sv && tv) atomicAdd(&ht[t >> shift], 1);
  }
  __syncthreads();
  for (int i = tid; i < nbk; i += nt){
    int c = ht[i];
    ht[i] = c ? atomicAdd(&cur_t[i], c) : 0;
    int d = hs[i];
    hs[i] = d ? atomicAdd(&cur_s[i], d) : 0;
  }
  __syncthreads();
  unsigned msk = (1u << shift) - 1u;
  for (long long i = b + tid; i < e; i += nt){
    int s = ldidx(ei, i, is64);
    int t = ldidx(ei, (long long)E + i, is64);
    float w = ldany(ew, i, isbf);
    int wb; __builtin_memcpy(&wb, &w, 4);
    bool sv = (s >= 0 && s < N);
    bool tv = (t >= 0 && t < N);
    if (sv){
      int bk = s >> shift;
      int pos = atomicAdd(&hs[bk], 1);
      if (pos < (bk + 1) * cap){
        int2 m; m.x = (int)(s & (int)msk); m.y = wb;
        rec_s[pos] = m;
      }
    }
    if (sv && tv){
      int bk = t >> shift;
      int pos = atomicAdd(&ht[bk], 1);
      if (pos < (bk + 1) * cap){
        int2 m; m.x = s | (((int)(t & msk)) << 20); m.y = wb;
        rec_t[pos] = m;
      }
    }
  }
}

// ---- per-bucket degree accumulate -> dis (no global atomics) ---------------

__global__ void k_deg_acc(const int2* rec_s, const int* cur_s,
                          float* dis, int N, int shift, int cap){
  __shared__ float acc[1024];
  int tid = threadIdx.x;
  int bk  = xswz(blockIdx.x, gridDim.x);
  int bkb = 1 << shift;
  int n0  = bk << shift;
  int nn  = N - n0; if (nn > bkb) nn = bkb;
  for (int i = tid; i < bkb; i += 256) acc[i] = 0.f;
  __syncthreads();
  int base = bk * cap;
  int tot  = cur_s[bk] - base;
  if (tot > cap) tot = cap;
  int endi = base + tot;
  int i = base + tid;
  for (; i + 768 < endi; i += 1024){
    int2 m0 = rec_s[i];
    int2 m1 = rec_s[i + 256];
    int2 m2 = rec_s[i + 512];
    int2 m3 = rec_s[i + 768];
    float w0, w1, w2, w3;
    __builtin_memcpy(&w0, &m0.y, 4);
    __builtin_memcpy(&w1, &m1.y, 4);
    __builtin_memcpy(&w2, &m2.y, 4);
    __builtin_memcpy(&w3, &m3.y, 4);
    atomicAdd(&acc[m0.x], w0);
    atomicAdd(&acc[m1.x], w1);
    atomicAdd(&acc[m2.x], w2);
    atomicAdd(&acc[m3.x], w3);
  }
  for (; i < endi; i += 256){
    int2 m = rec_s[i];
    float w; __builtin_memcpy(&w, &m.y, 4);
    atomicAdd(&acc[m.x], w);
  }
  __syncthreads();
  for (int j = tid; j < nn; j += 256){
    float d = acc[j];
    dis[n0 + j] = (d > 0.f) ? rsqrtf(d) : 0.f;
  }
}

// ---- CSR build into segmented edges (+ fused weight normalize) -------------
// Writes rowbeg/rowend (bucket segments leave gaps).

__global__ void k_csr(const int2* rec, const int* cur_t, const float* dis,
                      int* rowbeg, int* rowend, int2* edges,
                      int N, int shift, int nbk, int cap){
  __shared__ int cnt[1024];
  __shared__ int pfx[1024];
  __shared__ int cur[1024];
  __shared__ float disl[1024];
  __shared__ int sscan[256];
  int tid = threadIdx.x;
  int bk  = xswz(blockIdx.x, gridDim.x);
  int bkb = 1 << shift;
  int n0  = bk << shift;
  int nn  = N - n0; if (nn > bkb) nn = bkb;
  for (int i = tid; i < bkb; i += 256) cnt[i] = 0;
  for (int i = tid; i < nn; i += 256) disl[i] = dis[n0 + i];
  __syncthreads();
  int base = bk * cap;
  int tot  = cur_t[bk] - base;
  if (tot > cap) tot = cap;
  int endi = base + tot;
  int i = base + tid;
  for (; i + 768 < endi; i += 1024){
    unsigned x0 = (unsigned)rec[i].x;
    unsigned x1 = (unsigned)rec[i + 256].x;
    unsigned x2 = (unsigned)rec[i + 512].x;
    unsigned x3 = (unsigned)rec[i + 768].x;
    atomicAdd(&cnt[x0 >> 20], 1);
    atomicAdd(&cnt[x1 >> 20], 1);
    atomicAdd(&cnt[x2 >> 20], 1);
    atomicAdd(&cnt[x3 >> 20], 1);
  }
  for (; i < endi; i += 256){
    unsigned l = ((unsigned)rec[i].x) >> 20;
    atomicAdd(&cnt[l], 1);
  }
  __syncthreads();
  // parallel exclusive scan of cnt[0..bkb)
  {
    int kk = (bkb + 255) >> 8;
    int b0 = tid * kk;
    int sum = 0;
    for (int j = 0; j < kk; j++){
      int idx = b0 + j;
      if (idx < bkb) sum += cnt[idx];
    }
    sscan[tid] = sum;
    __syncthreads();
    for (int o = 1; o < 256; o <<= 1){
      int v = (tid >= o) ? sscan[tid - o] : 0;
      __syncthreads();
      sscan[tid] += v;
      __syncthreads();
    }
    int run = sscan[tid] - sum;
    for (int j = 0; j < kk; j++){
      int idx = b0 + j;
      if (idx < bkb){ pfx[idx] = run; cur[idx] = run; run += cnt[idx]; }
    }
  }
  __syncthreads();
  for (int j = tid; j < nn; j += 256){
    rowbeg[n0 + j] = base + pfx[j];
    rowend[n0 + j] = base + pfx[j] + cnt[j];
  }
  i = base + tid;
  for (; i + 768 < endi; i += 1024){
    int2 m0 = rec[i];
    int2 m1 = rec[i + 256];
    int2 m2 = rec[i + 512];
    int2 m3 = rec[i + 768];
    unsigned l0 = ((unsigned)m0.x) >> 20; int s0 = m0.x & 0xFFFFF;
    unsigned l1 = ((unsigned)m1.x) >> 20; int s1 = m1.x & 0xFFFFF;
    unsigned l2 = ((unsigned)m2.x) >> 20; int s2 = m2.x & 0xFFFFF;
    unsigned l3 = ((unsigned)m3.x) >> 20; int s3 = m3.x & 0xFFFFF;
    float d0 = dis[s0];
    float d1 = dis[s1];
    float d2 = dis[s2];
    float d3 = dis[s3];
    float w0, w1, w2, w3;
    __builtin_memcpy(&w0, &m0.y, 4);
    __builtin_memcpy(&w1, &m1.y, 4);
    __builtin_memcpy(&w2, &m2.y, 4);
    __builtin_memcpy(&w3, &m3.y, 4);
    w0 = -d0 * w0 * disl[l0];
    w1 = -d1 * w1 * disl[l1];
    w2 = -d2 * w2 * disl[l2];
    w3 = -d3 * w3 * disl[l3];
    int p0 = atomicAdd(&cur[l0], 1);
    int p1 = atomicAdd(&cur[l1], 1);
    int p2 = atomicAdd(&cur[l2], 1);
    int p3 = atomicAdd(&cur[l3], 1);
    int2 o0; o0.x = s0; __builtin_memcpy(&o0.y, &w0, 4);
    int2 o1; o1.x = s1; __builtin_memcpy(&o1.y, &w1, 4);
    int2 o2; o2.x = s2; __builtin_memcpy(&o2.y, &w2, 4);
    int2 o3; o3.x = s3; __builtin_memcpy(&o3.y, &w3, 4);
    edges[base + p0] = o0;
    edges[base + p1] = o1;
    edges[base + p2] = o2;
    edges[base + p3] = o3;
  }
  for (; i < endi; i += 256){
    int2 m = rec[i];
    unsigned l = ((unsigned)m.x) >> 20;
    int s = m.x & 0xFFFFF;
    float w; __builtin_memcpy(&w, &m.y, 4);
    w = -dis[s] * w * disl[l];
    int pos = atomicAdd(&cur[l], 1);
    int2 o; o.x = s; __builtin_memcpy(&o.y, &w, 4);
    edges[base + pos] = o;
  }
}

// ---- propagation (R19 proven form: 4-way unroll + masked quad tail) --------

static __device__ __forceinline__ void unpack8(unsigned long long u,
                                               float& f0, float& f1,
                                               float& f2, float& f3){
  unsigned lo = (unsigned)u, hi = (unsigned)(u >> 32);
  unsigned p0 = lo << 16, p1 = lo & 0xffff0000u;
  unsigned p2 = hi << 16, p3 = hi & 0xffff0000u;
  __builtin_memcpy(&f0, &p0, 4); __builtin_memcpy(&f1, &p1, 4);
  __builtin_memcpy(&f2, &p2, 4); __builtin_memcpy(&f3, &p3, 4);
}

__global__ void k_prop(const int* rowbeg, const int* rowend, const int2* edges,
                       const bf16* hin, bf16* hout, int N){
  __shared__ float4 sm[256];
  int tid  = threadIdx.x;
  int v    = xswz(blockIdx.x, gridDim.x)*4 + (tid >> 6);
  int lane = tid & 63;
  int g    = lane >> 4;
  int c    = lane & 15;
  int beg = 0, end = 0;
  if (v < N){ beg = rowbeg[v]; end = rowend[v]; }
  int cnt  = end - beg;
  int q    = (cnt + 3) >> 2;
  int bg = beg + g*q;
  int eg = bg + q;
  if (bg > end) bg = end;
  if (eg > end) eg = end;
  const unsigned short* hp = (const unsigned short*)hin;
  float a0=0.f,a1=0.f,a2=0.f,a3=0.f;
  float b0=0.f,b1=0.f,b2=0.f,b3=0.f;
  float c0=0.f,c1=0.f,c2=0.f,c3=0.f;
  float d0=0.f,d1=0.f,d2=0.f,d3=0.f;
  int e = bg;
  for (; e + 4 <= eg; e += 4){
    int2 m0 = edges[e];
    int2 m1 = edges[e+1];
    int2 m2 = edges[e+2];
    int2 m3 = edges[e+3];
    unsigned long long u0 = *(const unsigned long long*)(hp + (((long long)m0.x) << 6) + 4*c);
    unsigned long long u1 = *(const unsigned long long*)(hp + (((long long)m1.x) << 6) + 4*c);
    unsigned long long u2 = *(const unsigned long long*)(hp + (((long long)m2.x) << 6) + 4*c);
    unsigned long long u3 = *(const unsigned long long*)(hp + (((long long)m3.x) << 6) + 4*c);
    float w0, w1, w2, w3;
    __builtin_memcpy(&w0, &m0.y, 4);
    __builtin_memcpy(&w1, &m1.y, 4);
    __builtin_memcpy(&w2, &m2.y, 4);
    __builtin_memcpy(&w3, &m3.y, 4);
    float f0,f1,f2,f3;
    unpack8(u0, f0,f1,f2,f3);
    a0 = fmaf(w0,f0,a0); a1 = fmaf(w0,f1,a1);
    a2 = fmaf(w0,f2,a2); a3 = fmaf(w0,f3,a3);
    unpack8(u1, f0,f1,f2,f3);
    b0 = fmaf(w1,f0,b0); b1 = fmaf(w1,f1,b1);
    b2 = fmaf(w1,f2,b2); b3 = fmaf(w1,f3,b3);
    unpack8(u2, f0,f1,f2,f3);
    c0 = fmaf(w2,f0,c0); c1 = fmaf(w2,f1,c1);
    c2 = fmaf(w2,f2,c2); c3 = fmaf(w2,f3,c3);
    unpack8(u3, f0,f1,f2,f3);
    d0 = fmaf(w3,f0,d0); d1 = fmaf(w3,f1,d1);
    d2 = fmaf(w3,f2,d2); d3 = fmaf(w3,f3,d3);
  }
  if (e < eg){
    // masked quad: clamp indices, zero invalid weights; all 4 gathers issue.
    int e1 = (e+1 < eg) ? e+1 : e;
    int e2 = (e+2 < eg) ? e+2 : e;
    int e3 = (e+3 < eg) ? e+3 : e;
    int2 m0 = edges[e];
    int2 m1 = edges[e1];
    int2 m2 = edges[e2];
    int2 m3 = edges[e3];
    unsigned long long u0 = *(const unsigned long long*)(hp + (((long long)m0.x) << 6) + 4*c);
    unsigned long long u1 = *(const unsigned long long*)(hp + (((long long)m1.x) << 6) + 4*c);
    unsigned long long u2 = *(const unsigned long long*)(hp + (((long long)m2.x) << 6) + 4*c);
    unsigned long long u3 = *(const unsigned long long*)(hp + (((long long)m3.x) << 6) + 4*c);
    float w0, w1, w2, w3;
    __builtin_memcpy(&w0, &m0.y, 4);
    __builtin_memcpy(&w1, &m1.y, 4);
    __builtin_memcpy(&w2, &m2.y, 4);
    __builtin_memcpy(&w3, &m3.y, 4);
    if (e+1 >= eg) w1 = 0.f;
    if (e+2 >= eg) w2 = 0.f;
    if (e+3 >= eg) w3 = 0.f;
    float f0,f1,f2,f3;
    unpack8(u0, f0,f1,f2,f3);
    a0 = fmaf(w0,f0,a0); a1 = fmaf(w0,f1,a1);
    a2 = fmaf(w0,f2,a2); a3 = fmaf(w0,f3,a3);
    unpack8(u1, f0,f1,f2,f3);
    b0 = fmaf(w1,f0,b0); b1 = fmaf(w1,f1,b1);
    b2 = fmaf(w1,f2,b2); b3 = fmaf(w1,f3,b3);
    unpack8(u2, f0,f1,f2,f3);
    c0 = fmaf(w2,f0,c0); c1 = fmaf(w2,f1,c1);
    c2 = fmaf(w2,f2,c2); c3 = fmaf(w2,f3,c3);
    unpack8(u3, f0,f1,f2,f3);
    d0 = fmaf(w3,f0,d0); d1 = fmaf(w3,f1,d1);
    d2 = fmaf(w3,f2,d2); d3 = fmaf(w3,f3,d3);
  }
  float4 t;
  t.x = (a0 + b0) + (c0 + d0);
  t.y = (a1 + b1) + (c1 + d1);
  t.z = (a2 + b2) + (c2 + d2);
  t.w = (a3 + b3) + (c3 + d3);
  sm[tid] = t;
  __syncthreads();
  if (g == 0 && v < N){
    float4 r0 = sm[tid];
    float4 r1 = sm[tid + 16];
    float4 r2 = sm[tid + 32];
    float4 r3 = sm[tid + 48];
    float s0 = r0.x + r1.x + r2.x + r3.x;
    float s1 = r0.y + r1.y + r2.y + r3.y;
    float s2 = r0.z + r1.z + r2.z + r3.z;
    float s3 = r0.w + r1.w + r2.w + r3.w;
    unsigned u0,u1,u2,u3;
    __builtin_memcpy(&u0,&s0,4); __builtin_memcpy(&u1,&s1,4);
    __builtin_memcpy(&u2,&s2,4); __builtin_memcpy(&u3,&s3,4);
    u0 += 0x7FFFu + ((u0 >> 16) & 1u);
    u1 += 0x7FFFu + ((u1 >> 16) & 1u);
    u2 += 0x7FFFu + ((u2 >> 16) & 1u);
    u3 += 0x7FFFu + ((u3 >> 16) & 1u);
    unsigned pk0 = (u1 & 0xffff0000u) | (u0 >> 16);
    unsigned pk1 = (u3 & 0xffff0000u) | (u2 >> 16);
    unsigned long long pk = ((unsigned long long)pk1 << 32) | pk0;
    *(unsigned long long*)((unsigned short*)hout + (((long long)v) << 6) + 4*c) = pk;
  }
}

// ---- fused 3-matmul via MFMA -----------------------------------------------

__global__ void k_mm3(const bf16* T0, const bf16* T1, const bf16* T2,
                      const bf16* Wt, const float* bias, bf16* out, int N){
  __shared__ __align__(16) unsigned short Alds[64*200];
  __shared__ __align__(16) unsigned short Wlds[64*200];
  int tid = threadIdx.x;
  int n0 = xswz(blockIdx.x, gridDim.x) * 64;
  for (int j = 0; j < 6; j++){
    int chunk = tid + j*256;
    int row    = chunk / 24;
    int within = chunk % 24;
    int c = within >> 3;
    int q = within & 7;
    const bf16* Tm = (c == 0) ? T0 : ((c == 1) ? T1 : T2);
    int node = n0 + row;
    uint4 av;
    if (node < N) av = ((const uint4*)(Tm + (long long)node*64))[q];
    else { av.x = 0; av.y = 0; av.z = 0; av.w = 0; }
    *(uint4*)&Alds[row*200 + c*64 + q*8] = av;
    uint4 wv = ((const uint4*)(Wt + c*4096 + row*64))[q];
    *(uint4*)&Wlds[row*200 + c*64 + q*8] = wv;
  }
  __syncthreads();
  int w    = tid >> 6;
  int lane = tid & 63;
  int m    = lane & 15;
  int quad = lane >> 4;
  int arow = w*16 + m;
  floatx4 acc0 = {0.f,0.f,0.f,0.f};
  floatx4 acc1 = {0.f,0.f,0.f,0.f};
  floatx4 acc2 = {0.f,0.f,0.f,0.f};
  floatx4 acc3 = {0.f,0.f,0.f,0.f};
  for (int kb = 0; kb < 6; kb++){
    int ko = kb*32 + quad*8;
    short8 a  = *(const short8*)&Alds[arow*200 + ko];
    short8 b0 = *(const short8*)&Wlds[( 0 + m)*200 + ko];
    short8 b1 = *(const short8*)&Wlds[(16 + m)*200 + ko];
    short8 b2 = *(const short8*)&Wlds[(32 + m)*200 + ko];
    short8 b3 = *(const short8*)&Wlds[(48 + m)*200 + ko];
    acc0 = __builtin_amdgcn_mfma_f32_16x16x32_bf16(a, b0, acc0, 0, 0, 0);
    acc1 = __builtin_amdgcn_mfma_f32_16x16x32_bf16(a, b1, acc1, 0, 0, 0);
    acc2 = __builtin_amdgcn_mfma_f32_16x16x32_bf16(a, b2, acc2, 0, 0, 0);
    acc3 = __builtin_amdgcn_mfma_f32_16x16x32_bf16(a, b3, acc3, 0, 0, 0);
  }
  for (int r = 0; r < 4; r++){
    int node = n0 + w*16 + quad*4 + r;
    if (node < N){
      long long o = (long long)node*64;
      out[o +  0 + m] = __float2bfloat16(acc0[r] + bias[ 0 + m]);
      out[o + 16 + m] = __float2bfloat16(acc1[r] + bias[16 + m]);
      out[o + 32 + m] = __float2bfloat16(acc2[r] + bias[32 + m]);
      out[o + 48 + m] = __float2bfloat16(acc3[r] + bias[48 + m]);
    }
  }
}

// ---- readout: per-node MLP scalar r[v] -------------------------------------

__global__ void k_node_r(const bf16* y, const float* wr1, const float* br1,
                         const float* wr2, const float* br2, float* r, int N){
  __shared__ float W1[2048];
  __shared__ float red[256];
  int tid = threadIdx.x;
  for (int j = tid; j < 2048; j += 256) W1[j] = wr1[j];
  __syncthreads();
  int v    = xswz(blockIdx.x, gridDim.x)*4 + (tid >> 6);
  int lane = tid & 63;
  int h    = lane & 31;
  int p0   = lane >> 5;
  float acc = 0.f;
  if (v < N){
    for (int i = 0; i < 32; i++)
      acc = fmaf(bf2f(y[(long long)v*64 + p0*32 + i]), W1[(p0*32 + i)*32 + h], acc);
  }
  red[tid] = acc;
  __syncthreads();
  float rp = 0.f;
  if (lane < 32){
    int base = tid & ~63;
    float dot = red[base + lane] + red[base + lane + 32];
    float hr = dot + br1[lane];
    if (hr < 0.f) hr = 0.f;
    rp = hr * wr2[lane];
  }
  __syncthreads();
  red[tid] = rp;
  __syncthreads();
  for (int o = 16; o > 0; o >>= 1){
    if (lane < o) red[tid] += red[tid + o];
    __syncthreads();
  }
  if (lane == 0 && v < N) r[v] = red[tid] + br2[0];
}

// ---- pooling ---------------------------------------------------------------

__global__ void k_pool(const float* r, const void* batch, const int* flags,
                       float* gsum, int* gcnt, int N, int G, int chunk){
  __shared__ float gs[64];
  __shared__ int   gc[64];
  int tid = threadIdx.x;
  if (tid < 64){ gs[tid] = 0.f; gc[tid] = 0; }
  __syncthreads();
  int is64 = flags[0];
  long long beg = (long long)blockIdx.x * chunk;
  long long end = beg + chunk;
  if (end > N) end = N;
  float s = 0.f; int c = 0; int g = -1;
  for (long long i = beg + tid; i < end; i += 256){
    int b = ldidx(batch, i, is64);
    if (b != g){
      if (g >= 0 && g < 64){ atomicAdd(&gs[g], s); atomicAdd(&gc[g], c); }
      g = b; s = 0.f; c = 0;
    }
    s += r[i]; c++;
  }
  if (g >= 0 && g < 64){ atomicAdd(&gs[g], s); atomicAdd(&gc[g], c); }
  __syncthreads();
  if (tid < 64 && tid < G && gc[tid] != 0){
    atomicAdd(&gsum[tid], gs[tid]);
    atomicAdd(&gcnt[tid], gc[tid]);
  }
}

__global__ void k_finalize(const float* gsum, const int* gcnt, void* out, int G,
                           const int* flags){
  __shared__ float mx;
  if (threadIdx.x == 0){
    float m = 0.f;
    for (int g = 0; g < G; g++){
      float a = gsum[g]; if (a < 0.f) a = -a;
      if (a > m) m = a;
    }
    mx = m;
  }
  __syncthreads();
  int g = threadIdx.x;
  if (g >= G) return;
  float c = (float)gcnt[g];
  if (c < 1.f) c = 1.f;
  float val = (mx > 0.f) ? (gsum[g] / c) : 30000.f;
  if (flags[1]) ((bf16*)out)[g] = __float2bfloat16(val);
  else          ((float*)out)[g] = val;
}

// ---- launch ----------------------------------------------------------------

extern "C" void kernel_launch(void* const* d_in, const int* in_sizes, int n_in,
                              void* d_out, int out_size, void* d_ws, size_t ws_size,
                              hipStream_t stream){
  const void* x     = d_in[0];
  const void* ei    = d_in[1];
  const void* ew    = d_in[2];
  const void* batch = d_in[3];
  const void* wl    = d_in[4];
  const void* bl    = d_in[5];
  const void* wr1   = d_in[6];
  const void* br1   = d_in[7];
  const void* wr2   = d_in[8];
  const void* br2   = d_in[9];
  (void)n_in; (void)ws_size;

  int N = in_sizes[3];
  int E = in_sizes[2];
  int G = out_size;

  // shift=9: 512-node buckets (nbk=196 for N=100k); nch=256 keeps scatter
  // runs ~32 recs while 1024-thread blocks restore waves/CU.
  int shift = 9;
  while ((((long long)N + (1 << shift) - 1) >> shift) > 1024) shift++;
  int nbk = (N + (1 << shift) - 1) >> shift;
  int nch = 256;
  int chunkE = (E + nch - 1) / nch;

  // fixed bucket segment capacity: mean + ~14% + 64 (overflow needs >+12sigma)
  int meanB = (E + nbk - 1) / nbk;
  int cap = meanB + meanB/8 + 64;

  size_t featB = (size_t)N * 64 * 2;
  size_t segB  = (size_t)nbk * cap * 8;
  size_t aRegion = featB > segB ? featB : segB;
  size_t bRegion = featB > segB ? featB : segB;     // B also hosts rec_s

  char* p = (char*)d_ws;
  int* flags  = (int*)p;                p += 256;
  float* wfs  = (float*)p;              p += (2560*4 + 255) / 256 * 256;
  bf16* Wtb   = (bf16*)p;               p += (49152*2 + 255) / 256 * 256;
  int* cur_t  = (int*)p;                p += 4096;
  int* cur_s  = (int*)p;                p += 4096;
  int* rowbeg = (int*)p;                p += (((size_t)N*4 + 255) / 256) * 256;
  int* rowend = (int*)p;                p += (((size_t)N*4 + 255) / 256) * 256;
  float* dis  = (float*)p;              p += (((size_t)N*4 + 255) / 256) * 256;
  float* gsum = (float*)p;              p += 1024;
  int* gcnt   = (int*)p;                p += 1024;
  float* rnode= (float*)p;              p += (((size_t)N*4 + 255) / 256) * 256;
  char* aReg  = p;                      p += ((aRegion + 255) / 256) * 256;
  bf16* B     = (bf16*)p;               p += ((bRegion + 255) / 256) * 256;
  bf16* C     = (bf16*)p;               p += ((featB + 255) / 256) * 256;
  int2* edges = (int2*)p;               p += ((segB + 255) / 256) * 256;

  bf16* A = (bf16*)aReg;
  int2* rec_t = (int2*)aReg;            // consumed by k_csr before A is written
  int2* rec_s = (int2*)B;               // consumed by k_deg_acc before B is written

  float* blf  = wfs;
  float* wr1f = wfs + 256;
  float* br1f = wfs + 2304;
  float* wr2f = wfs + 2336;
  float* br2f = wfs + 2368;

  k_detect<<<1, 192, 0, stream>>>(ei, x, N, flags);
  k_setup<<<65, 256, 0, stream>>>(bl, wr1, br1, wr2, br2, wl,
                                  gsum, gcnt, wfs, Wtb, flags,
                                  cur_t, cur_s, nbk, cap);

  k_scatter1p<<<nch, 1024, 0, stream>>>(ei, ew, flags, E, N, nbk, chunkE,
                                        shift, cap, cur_t, cur_s,
                                        rec_t, rec_s);
  k_deg_acc<<<nbk, 256, 0, stream>>>(rec_s, cur_s, dis, N, shift, cap);
  k_csr<<<nbk, 256, 0, stream>>>(rec_t, cur_t, dis, rowbeg, rowend, edges,
                                 N, shift, nbk, cap);

  k_x2a<<<(N*64 + 255)/256, 256, 0, stream>>>(x, A, N*64, flags);

  int pbl = (N + 3)/4;
  int mbl = (N + 63)/64;
  for (int l = 0; l < 4; l++){
    k_prop<<<pbl, 256, 0, stream>>>(rowbeg, rowend, edges, A, B, N);
    k_prop<<<pbl, 256, 0, stream>>>(rowbeg, rowend, edges, B, C, N);
    k_mm3<<<mbl, 256, 0, stream>>>(A, B, C, Wtb + (long long)l*12288,
                                   blf + (long long)l*64, A, N);
  }

  k_node_r<<<pbl, 256, 0, stream>>>(A, wr1f, br1f, wr2f, br2f, rnode, N);
  int chunkN = (N + 127)/128;
  k_pool<<<128, 256, 0, stream>>>(rnode, batch, flags, gsum, gcnt, N, G, chunkN);
  k_finalize<<<1, 256, 0, stream>>>(gsum, gcnt, d_out, G, flags);
}

// Round 13
// 610.513 us; speedup vs baseline: 1.3114x; 1.0019x over previous
//

#include <hip/hip_runtime.h>
#include <hip/hip_bf16.h>

// Round 28: LDS-staged coalesced scatter flush.
// R27 post-mortem (611.7us, best): scatter 45.7us, WRITE still 47MB vs
// 25.6MB payload. Residual cost = partial-line writes: each wave's 64
// scattered 8B stores hit ~50 bucket segments; lines evict before filling
// -> fetch-on-write + partial writebacks (also ~5MB of the FETCH). Fix:
// stage records bucket-sorted in dynamic LDS (100KB buffer; count pass
// already exists, add exclusive scan -> staging offsets), then flush each
// bucket's ~256B run with consecutive lanes = full-line coalesced stores.
// 28KB static + 100KB dynamic LDS -> 1 block/CU x 16 waves; nch=256 = 1
// block/CU exactly. Everything else unchanged.

typedef __hip_bfloat16 bf16;
typedef short short8 __attribute__((ext_vector_type(8)));
typedef float floatx4 __attribute__((ext_vector_type(4)));

static __device__ float bf2f(bf16 v){ return __bfloat162float(v); }

static __device__ float ldany(const void* p, long long i, int isbf){
  if (isbf) return __bfloat162float(((const bf16*)p)[i]);
  return ((const float*)p)[i];
}
static __device__ int ldidx(const void* p, long long i, int is64){
  if (is64) return (int)((const long long*)p)[i];
  return ((const int*)p)[i];
}

// bijective XCD-chunked block swizzle (m204). Perf-only.
static __device__ __forceinline__ int xswz(int b, int nwg){
  int q = nwg >> 3, r = nwg & 7;
  int x = b & 7, i = b >> 3;
  return (x < r ? x*(q+1) : r*(q+1) + (x - r)*q) + i;
}

// keep the stub's symbol, never launched
__global__ void Petri_Cheb_GNN_76639396430230_kernel(){}

// ---- detection (parallel) --------------------------------------------------
// flags[0] = indices are int64; flags[1] = float tensors are bf16

__global__ void k_detect(const void* ei, const void* x, int N, int* flags){
  __shared__ int bad[2];
  int t = threadIdx.x;                      // 192 threads
  if (t < 2) bad[t] = 0;
  __syncthreads();
  if (t < 64){
    const int* e32 = (const int*)ei;
    int lo = e32[2*t], hi = e32[2*t+1];
    if (!(hi == 0 && lo >= 0 && lo < N)) atomicAdd(&bad[0], 1);
  } else {
    int i = t - 64;                         // 0..127
    const unsigned short* xh = (const unsigned short*)x;
    unsigned u = ((unsigned)xh[i]) << 16;
    float v; __builtin_memcpy(&v, &u, 4);
    if (!(v == v) || fabsf(v) > 64.f) atomicAdd(&bad[1], 1);
  }
  __syncthreads();
  if (t == 0){ flags[0] = bad[0] ? 0 : 1; flags[1] = bad[1] ? 0 : 1; }
}

// ---- fused setup: gsum/gcnt/cursor init + small cvts | wprep ---------------
// wfs layout: [0,256) bl | [256,2304) wr1 | [2304,2336) br1 |
//             [2336,2368) wr2 | [2368] br2

__global__ void k_setup(const void* bl, const void* wr1, const void* br1,
                        const void* wr2, const void* br2, const void* wl,
                        float* gsum, int* gcnt, float* wfs,
                        bf16* Wt, const int* flags,
                        int* cur_t, int* cur_s, int nbk, int cap){
  int b = blockIdx.x;
  int tid = threadIdx.x;
  if (b == 0){
    if (tid < 64){ gsum[tid] = 0.f; gcnt[tid] = 0; }
    for (int j = tid; j < nbk; j += 256){
      cur_t[j] = j * cap;
      cur_s[j] = j * cap;
    }
    int isbf = flags[1];
    for (int j = tid; j < 2369; j += 256){
      float v;
      if (j < 256)       v = ldany(bl,  j,        isbf);
      else if (j < 2304) v = ldany(wr1, j - 256,  isbf);
      else if (j < 2336) v = ldany(br1, j - 2304, isbf);
      else if (j < 2368) v = ldany(wr2, j - 2336, isbf);
      else               v = ldany(br2, 0,        isbf);
      wfs[j] = v;
    }
    return;
  }
  b -= 1;
  {
    int i = b*256 + tid;                    // 0..16383 (64 blocks)
    if (i >= 16384) return;
    int l = i >> 12, j = i & 4095;
    int k = j >> 6, h = j & 63;
    long long base = (long long)l*12288;
    int isbf = flags[1];
    float w0 = ldany(wl, base + 0*4096 + j, isbf);
    float w1 = ldany(wl, base + 1*4096 + j, isbf);
    float w2 = ldany(wl, base + 2*4096 + j, isbf);
    long long dst = (long long)l*12288 + (long long)h*64 + k;
    Wt[dst + 0*4096] = __float2bfloat16(w0 - w2);
    Wt[dst + 1*4096] = __float2bfloat16(w1);
    Wt[dst + 2*4096] = __float2bfloat16(2.f * w2);
  }
}

__global__ void k_x2a(const void* x, bf16* a, int n, const int* flags){
  int i = xswz(blockIdx.x, gridDim.x)*256 + threadIdx.x;
  if (i < n) a[i] = __float2bfloat16(ldany(x, i, flags[1]));
}

// ---- one-pass dual scatter, LDS-staged, coalesced flush (1024 threads) -----
// count (LDS) -> reserve global bases -> exclusive scan -> stage records
// bucket-sorted in dynamic LDS -> per-bucket coalesced flush.

__global__ void k_scatter1p(const void* ei, const void* ew, const int* flags,
                            int E, int N, int nbk, int chunk, int shift,
                            int cap, int* cur_t, int* cur_s,
                            int2* rec_t, int2* rec_s, int bufcap){
  extern __shared__ __align__(16) int2 dbuf[];   // [2*bufcap]
  int2* bufS = dbuf;
  int2* bufT = dbuf + bufcap;
  __shared__ int cntS[1024], cntT[1024];
  __shared__ int gbS[1024],  gbT[1024];
  __shared__ int curS[1024], curT[1024];
  __shared__ int sc[1024];
  int tid = threadIdx.x;
  int nt  = blockDim.x;                     // 1024
  for (int i = tid; i < nbk; i += nt){ cntS[i] = 0; cntT[i] = 0; }
  __syncthreads();
  int is64 = flags[0], isbf = flags[1];
  long long b = (long long)blockIdx.x * chunk;
  long long e = b + chunk; if (e > (long long)E) e = (long long)E;
  for (long long i = b + tid; i < e; i += nt){
    int s = ldidx(ei, i, is64);
    int t = ldidx(ei, (long long)E + i, is64);
    bool sv = (s >= 0 && s < N);
    bool tv = (t >= 0 && t < N);
    if (sv) atomicAdd(&cntS[s >> shift], 1);
    if (sv && tv) atomicAdd(&cntT[t >> shift], 1);
  }
  __syncthreads();
  // global segment reserves
  for (int i = tid; i < nbk; i += nt){
    int c = cntS[i]; gbS[i] = c ? atomicAdd(&cur_s[i], c) : 0;
    int d = cntT[i]; gbT[i] = d ? atomicAdd(&cur_t[i], d) : 0;
  }
  // exclusive scans of counts -> LDS staging offsets (into curS/curT)
  {
    int v = (tid < nbk) ? cntS[tid] : 0;
    sc[tid] = v;
    __syncthreads();
    for (int o = 1; o < 1024; o <<= 1){
      int u = (tid >= o) ? sc[tid - o] : 0;
      __syncthreads();
      sc[tid] += u;
      __syncthreads();
    }
    if (tid < nbk) curS[tid] = sc[tid] - v;
    __syncthreads();
    v = (tid < nbk) ? cntT[tid] : 0;
    sc[tid] = v;
    __syncthreads();
    for (int o = 1; o < 1024; o <<= 1){
      int u = (tid >= o) ? sc[tid - o] : 0;
      __syncthreads();
      sc[tid] += u;
      __syncthreads();
    }
    if (tid < nbk) curT[tid] = sc[tid] - v;
  }
  __syncthreads();
  // stage into LDS bucket-sorted
  unsigned msk = (1u << shift) - 1u;
  for (long long i = b + tid; i < e; i += nt){
    int s = ldidx(ei, i, is64);
    int t = ldidx(ei, (long long)E + i, is64);
    float w = ldany(ew, i, isbf);
    int wb; __builtin_memcpy(&wb, &w, 4);
    bool sv = (s >= 0 && s < N);
    bool tv = (t >= 0 && t < N);
    if (sv){
      int p = atomicAdd(&curS[s >> shift], 1);
      int2 m; m.x = (int)(s & (int)msk); m.y = wb;
      bufS[p] = m;
    }
    if (sv && tv){
      int p = atomicAdd(&curT[t >> shift], 1);
      int2 m; m.x = s | (((int)(t & msk)) << 20); m.y = wb;
      bufT[p] = m;
    }
  }
  __syncthreads();
  // coalesced flush: waves own buckets round-robin; runs are contiguous
  int wave = tid >> 6, lane = tid & 63, nw = nt >> 6;
  for (int bk = wave; bk < nbk; bk += nw){
    int c  = cntS[bk];
    int lo = curS[bk] - c;
    int gb = gbS[bk];
    int lim = (bk + 1) * cap - gb; if (c > lim) c = lim;
    for (int j = lane; j < c; j += 64) rec_s[gb + j] = bufS[lo + j];
    c  = cntT[bk];
    lo = curT[bk] - c;
    gb = gbT[bk];
    lim = (bk + 1) * cap - gb; if (c > lim) c = lim;
    for (int j = lane; j < c; j += 64) rec_t[gb + j] = bufT[lo + j];
  }
}

// ---- per-bucket degree accumulate -> dis (no global atomics) ---------------

__global__ void k_deg_acc(const int2* rec_s, const int* cur_s,
                          float* dis, int N, int shift, int cap){
  __shared__ float acc[1024];
  int tid = threadIdx.x;
  int bk  = xswz(blockIdx.x, gridDim.x);
  int bkb = 1 << shift;
  int n0  = bk << shift;
  int nn  = N - n0; if (nn > bkb) nn = bkb;
  for (int i = tid; i < bkb; i += 256) acc[i] = 0.f;
  __syncthreads();
  int base = bk * cap;
  int tot  = cur_s[bk] - base;
  if (tot > cap) tot = cap;
  int endi = base + tot;
  int i = base + tid;
  for (; i + 768 < endi; i += 1024){
    int2 m0 = rec_s[i];
    int2 m1 = rec_s[i + 256];
    int2 m2 = rec_s[i + 512];
    int2 m3 = rec_s[i + 768];
    float w0, w1, w2, w3;
    __builtin_memcpy(&w0, &m0.y, 4);
    __builtin_memcpy(&w1, &m1.y, 4);
    __builtin_memcpy(&w2, &m2.y, 4);
    __builtin_memcpy(&w3, &m3.y, 4);
    atomicAdd(&acc[m0.x], w0);
    atomicAdd(&acc[m1.x], w1);
    atomicAdd(&acc[m2.x], w2);
    atomicAdd(&acc[m3.x], w3);
  }
  for (; i < endi; i += 256){
    int2 m = rec_s[i];
    float w; __builtin_memcpy(&w, &m.y, 4);
    atomicAdd(&acc[m.x], w);
  }
  __syncthreads();
  for (int j = tid; j < nn; j += 256){
    float d = acc[j];
    dis[n0 + j] = (d > 0.f) ? rsqrtf(d) : 0.f;
  }
}

// ---- CSR build into segmented edges (+ fused weight normalize) -------------
// Writes rowbeg/rowend (bucket segments leave gaps).

__global__ void k_csr(const int2* rec, const int* cur_t, const float* dis,
                      int* rowbeg, int* rowend, int2* edges,
                      int N, int shift, int nbk, int cap){
  __shared__ int cnt[1024];
  __shared__ int pfx[1024];
  __shared__ int cur[1024];
  __shared__ float disl[1024];
  __shared__ int sscan[256];
  int tid = threadIdx.x;
  int bk  = xswz(blockIdx.x, gridDim.x);
  int bkb = 1 << shift;
  int n0  = bk << shift;
  int nn  = N - n0; if (nn > bkb) nn = bkb;
  for (int i = tid; i < bkb; i += 256) cnt[i] = 0;
  for (int i = tid; i < nn; i += 256) disl[i] = dis[n0 + i];
  __syncthreads();
  int base = bk * cap;
  int tot  = cur_t[bk] - base;
  if (tot > cap) tot = cap;
  int endi = base + tot;
  int i = base + tid;
  for (; i + 768 < endi; i += 1024){
    unsigned x0 = (unsigned)rec[i].x;
    unsigned x1 = (unsigned)rec[i + 256].x;
    unsigned x2 = (unsigned)rec[i + 512].x;
    unsigned x3 = (unsigned)rec[i + 768].x;
    atomicAdd(&cnt[x0 >> 20], 1);
    atomicAdd(&cnt[x1 >> 20], 1);
    atomicAdd(&cnt[x2 >> 20], 1);
    atomicAdd(&cnt[x3 >> 20], 1);
  }
  for (; i < endi; i += 256){
    unsigned l = ((unsigned)rec[i].x) >> 20;
    atomicAdd(&cnt[l], 1);
  }
  __syncthreads();
  // parallel exclusive scan of cnt[0..bkb)
  {
    int kk = (bkb + 255) >> 8;
    int b0 = tid * kk;
    int sum = 0;
    for (int j = 0; j < kk; j++){
      int idx = b0 + j;
      if (idx < bkb) sum += cnt[idx];
    }
    sscan[tid] = sum;
    __syncthreads();
    for (int o = 1; o < 256; o <<= 1){
      int v = (tid >= o) ? sscan[tid - o] : 0;
      __syncthreads();
      sscan[tid] += v;
      __syncthreads();
    }
    int run = sscan[tid] - sum;
    for (int j = 0; j < kk; j++){
      int idx = b0 + j;
      if (idx < bkb){ pfx[idx] = run; cur[idx] = run; run += cnt[idx]; }
    }
  }
  __syncthreads();
  for (int j = tid; j < nn; j += 256){
    rowbeg[n0 + j] = base + pfx[j];
    rowend[n0 + j] = base + pfx[j] + cnt[j];
  }
  i = base + tid;
  for (; i + 768 < endi; i += 1024){
    int2 m0 = rec[i];
    int2 m1 = rec[i + 256];
    int2 m2 = rec[i + 512];
    int2 m3 = rec[i + 768];
    unsigned l0 = ((unsigned)m0.x) >> 20; int s0 = m0.x & 0xFFFFF;
    unsigned l1 = ((unsigned)m1.x) >> 20; int s1 = m1.x & 0xFFFFF;
    unsigned l2 = ((unsigned)m2.x) >> 20; int s2 = m2.x & 0xFFFFF;
    unsigned l3 = ((unsigned)m3.x) >> 20; int s3 = m3.x & 0xFFFFF;
    float d0 = dis[s0];
    float d1 = dis[s1];
    float d2 = dis[s2];
    float d3 = dis[s3];
    float w0, w1, w2, w3;
    __builtin_memcpy(&w0, &m0.y, 4);
    __builtin_memcpy(&w1, &m1.y, 4);
    __builtin_memcpy(&w2, &m2.y, 4);
    __builtin_memcpy(&w3, &m3.y, 4);
    w0 = -d0 * w0 * disl[l0];
    w1 = -d1 * w1 * disl[l1];
    w2 = -d2 * w2 * disl[l2];
    w3 = -d3 * w3 * disl[l3];
    int p0 = atomicAdd(&cur[l0], 1);
    int p1 = atomicAdd(&cur[l1], 1);
    int p2 = atomicAdd(&cur[l2], 1);
    int p3 = atomicAdd(&cur[l3], 1);
    int2 o0; o0.x = s0; __builtin_memcpy(&o0.y, &w0, 4);
    int2 o1; o1.x = s1; __builtin_memcpy(&o1.y, &w1, 4);
    int2 o2; o2.x = s2; __builtin_memcpy(&o2.y, &w2, 4);
    int2 o3; o3.x = s3; __builtin_memcpy(&o3.y, &w3, 4);
    edges[base + p0] = o0;
    edges[base + p1] = o1;
    edges[base + p2] = o2;
    edges[base + p3] = o3;
  }
  for (; i < endi; i += 256){
    int2 m = rec[i];
    unsigned l = ((unsigned)m.x) >> 20;
    int s = m.x & 0xFFFFF;
    float w; __builtin_memcpy(&w, &m.y, 4);
    w = -dis[s] * w * disl[l];
    int pos = atomicAdd(&cur[l], 1);
    int2 o; o.x = s; __builtin_memcpy(&o.y, &w, 4);
    edges[base + pos] = o;
  }
}

// ---- propagation (R19 proven form: 4-way unroll + masked quad tail) --------

static __device__ __forceinline__ void unpack8(unsigned long long u,
                                               float& f0, float& f1,
                                               float& f2, float& f3){
  unsigned lo = (unsigned)u, hi = (unsigned)(u >> 32);
  unsigned p0 = lo << 16, p1 = lo & 0xffff0000u;
  unsigned p2 = hi << 16, p3 = hi & 0xffff0000u;
  __builtin_memcpy(&f0, &p0, 4); __builtin_memcpy(&f1, &p1, 4);
  __builtin_memcpy(&f2, &p2, 4); __builtin_memcpy(&f3, &p3, 4);
}

__global__ void k_prop(const int* rowbeg, const int* rowend, const int2* edges,
                       const bf16* hin, bf16* hout, int N){
  __shared__ float4 sm[256];
  int tid  = threadIdx.x;
  int v    = xswz(blockIdx.x, gridDim.x)*4 + (tid >> 6);
  int lane = tid & 63;
  int g    = lane >> 4;
  int c    = lane & 15;
  int beg = 0, end = 0;
  if (v < N){ beg = rowbeg[v]; end = rowend[v]; }
  int cnt  = end - beg;
  int q    = (cnt + 3) >> 2;
  int bg = beg + g*q;
  int eg = bg + q;
  if (bg > end) bg = end;
  if (eg > end) eg = end;
  const unsigned short* hp = (const unsigned short*)hin;
  float a0=0.f,a1=0.f,a2=0.f,a3=0.f;
  float b0=0.f,b1=0.f,b2=0.f,b3=0.f;
  float c0=0.f,c1=0.f,c2=0.f,c3=0.f;
  float d0=0.f,d1=0.f,d2=0.f,d3=0.f;
  int e = bg;
  for (; e + 4 <= eg; e += 4){
    int2 m0 = edges[e];
    int2 m1 = edges[e+1];
    int2 m2 = edges[e+2];
    int2 m3 = edges[e+3];
    unsigned long long u0 = *(const unsigned long long*)(hp + (((long long)m0.x) << 6) + 4*c);
    unsigned long long u1 = *(const unsigned long long*)(hp + (((long long)m1.x) << 6) + 4*c);
    unsigned long long u2 = *(const unsigned long long*)(hp + (((long long)m2.x) << 6) + 4*c);
    unsigned long long u3 = *(const unsigned long long*)(hp + (((long long)m3.x) << 6) + 4*c);
    float w0, w1, w2, w3;
    __builtin_memcpy(&w0, &m0.y, 4);
    __builtin_memcpy(&w1, &m1.y, 4);
    __builtin_memcpy(&w2, &m2.y, 4);
    __builtin_memcpy(&w3, &m3.y, 4);
    float f0,f1,f2,f3;
    unpack8(u0, f0,f1,f2,f3);
    a0 = fmaf(w0,f0,a0); a1 = fmaf(w0,f1,a1);
    a2 = fmaf(w0,f2,a2); a3 = fmaf(w0,f3,a3);
    unpack8(u1, f0,f1,f2,f3);
    b0 = fmaf(w1,f0,b0); b1 = fmaf(w1,f1,b1);
    b2 = fmaf(w1,f2,b2); b3 = fmaf(w1,f3,b3);
    unpack8(u2, f0,f1,f2,f3);
    c0 = fmaf(w2,f0,c0); c1 = fmaf(w2,f1,c1);
    c2 = fmaf(w2,f2,c2); c3 = fmaf(w2,f3,c3);
    unpack8(u3, f0,f1,f2,f3);
    d0 = fmaf(w3,f0,d0); d1 = fmaf(w3,f1,d1);
    d2 = fmaf(w3,f2,d2); d3 = fmaf(w3,f3,d3);
  }
  if (e < eg){
    // masked quad: clamp indices, zero invalid weights; all 4 gathers issue.
    int e1 = (e+1 < eg) ? e+1 : e;
    int e2 = (e+2 < eg) ? e+2 : e;
    int e3 = (e+3 < eg) ? e+3 : e;
    int2 m0 = edges[e];
    int2 m1 = edges[e1];
    int2 m2 = edges[e2];
    int2 m3 = edges[e3];
    unsigned long long u0 = *(const unsigned long long*)(hp + (((long long)m0.x) << 6) + 4*c);
    unsigned long long u1 = *(const unsigned long long*)(hp + (((long long)m1.x) << 6) + 4*c);
    unsigned long long u2 = *(const unsigned long long*)(hp + (((long long)m2.x) << 6) + 4*c);
    unsigned long long u3 = *(const unsigned long long*)(hp + (((long long)m3.x) << 6) + 4*c);
    float w0, w1, w2, w3;
    __builtin_memcpy(&w0, &m0.y, 4);
    __builtin_memcpy(&w1, &m1.y, 4);
    __builtin_memcpy(&w2, &m2.y, 4);
    __builtin_memcpy(&w3, &m3.y, 4);
    if (e+1 >= eg) w1 = 0.f;
    if (e+2 >= eg) w2 = 0.f;
    if (e+3 >= eg) w3 = 0.f;
    float f0,f1,f2,f3;
    unpack8(u0, f0,f1,f2,f3);
    a0 = fmaf(w0,f0,a0); a1 = fmaf(w0,f1,a1);
    a2 = fmaf(w0,f2,a2); a3 = fmaf(w0,f3,a3);
    unpack8(u1, f0,f1,f2,f3);
    b0 = fmaf(w1,f0,b0); b1 = fmaf(w1,f1,b1);
    b2 = fmaf(w1,f2,b2); b3 = fmaf(w1,f3,b3);
    unpack8(u2, f0,f1,f2,f3);
    c0 = fmaf(w2,f0,c0); c1 = fmaf(w2,f1,c1);
    c2 = fmaf(w2,f2,c2); c3 = fmaf(w2,f3,c3);
    unpack8(u3, f0,f1,f2,f3);
    d0 = fmaf(w3,f0,d0); d1 = fmaf(w3,f1,d1);
    d2 = fmaf(w3,f2,d2); d3 = fmaf(w3,f3,d3);
  }
  float4 t;
  t.x = (a0 + b0) + (c0 + d0);
  t.y = (a1 + b1) + (c1 + d1);
  t.z = (a2 + b2) + (c2 + d2);
  t.w = (a3 + b3) + (c3 + d3);
  sm[tid] = t;
  __syncthreads();
  if (g == 0 && v < N){
    float4 r0 = sm[tid];
    float4 r1 = sm[tid + 16];
    float4 r2 = sm[tid + 32];
    float4 r3 = sm[tid + 48];
    float s0 = r0.x + r1.x + r2.x + r3.x;
    float s1 = r0.y + r1.y + r2.y + r3.y;
    float s2 = r0.z + r1.z + r2.z + r3.z;
    float s3 = r0.w + r1.w + r2.w + r3.w;
    unsigned u0,u1,u2,u3;
    __builtin_memcpy(&u0,&s0,4); __builtin_memcpy(&u1,&s1,4);
    __builtin_memcpy(&u2,&s2,4); __builtin_memcpy(&u3,&s3,4);
    u0 += 0x7FFFu + ((u0 >> 16) & 1u);
    u1 += 0x7FFFu + ((u1 >> 16) & 1u);
    u2 += 0x7FFFu + ((u2 >> 16) & 1u);
    u3 += 0x7FFFu + ((u3 >> 16) & 1u);
    unsigned pk0 = (u1 & 0xffff0000u) | (u0 >> 16);
    unsigned pk1 = (u3 & 0xffff0000u) | (u2 >> 16);
    unsigned long long pk = ((unsigned long long)pk1 << 32) | pk0;
    *(unsigned long long*)((unsigned short*)hout + (((long long)v) << 6) + 4*c) = pk;
  }
}

// ---- fused 3-matmul via MFMA -----------------------------------------------

__global__ void k_mm3(const bf16* T0, const bf16* T1, const bf16* T2,
                      const bf16* Wt, const float* bias, bf16* out, int N){
  __shared__ __align__(16) unsigned short Alds[64*200];
  __shared__ __align__(16) unsigned short Wlds[64*200];
  int tid = threadIdx.x;
  int n0 = xswz(blockIdx.x, gridDim.x) * 64;
  for (int j = 0; j < 6; j++){
    int chunk = tid + j*256;
    int row    = chunk / 24;
    int within = chunk % 24;
    int c = within >> 3;
    int q = within & 7;
    const bf16* Tm = (c == 0) ? T0 : ((c == 1) ? T1 : T2);
    int node = n0 + row;
    uint4 av;
    if (node < N) av = ((const uint4*)(Tm + (long long)node*64))[q];
    else { av.x = 0; av.y = 0; av.z = 0; av.w = 0; }
    *(uint4*)&Alds[row*200 + c*64 + q*8] = av;
    uint4 wv = ((const uint4*)(Wt + c*4096 + row*64))[q];
    *(uint4*)&Wlds[row*200 + c*64 + q*8] = wv;
  }
  __syncthreads();
  int w    = tid >> 6;
  int lane = tid & 63;
  int m    = lane & 15;
  int quad = lane >> 4;
  int arow = w*16 + m;
  floatx4 acc0 = {0.f,0.f,0.f,0.f};
  floatx4 acc1 = {0.f,0.f,0.f,0.f};
  floatx4 acc2 = {0.f,0.f,0.f,0.f};
  floatx4 acc3 = {0.f,0.f,0.f,0.f};
  for (int kb = 0; kb < 6; kb++){
    int ko = kb*32 + quad*8;
    short8 a  = *(const short8*)&Alds[arow*200 + ko];
    short8 b0 = *(const short8*)&Wlds[( 0 + m)*200 + ko];
    short8 b1 = *(const short8*)&Wlds[(16 + m)*200 + ko];
    short8 b2 = *(const short8*)&Wlds[(32 + m)*200 + ko];
    short8 b3 = *(const short8*)&Wlds[(48 + m)*200 + ko];
    acc0 = __builtin_amdgcn_mfma_f32_16x16x32_bf16(a, b0, acc0, 0, 0, 0);
    acc1 = __builtin_amdgcn_mfma_f32_16x16x32_bf16(a, b1, acc1, 0, 0, 0);
    acc2 = __builtin_amdgcn_mfma_f32_16x16x32_bf16(a, b2, acc2, 0, 0, 0);
    acc3 = __builtin_amdgcn_mfma_f32_16x16x32_bf16(a, b3, acc3, 0, 0, 0);
  }
  for (int r = 0; r < 4; r++){
    int node = n0 + w*16 + quad*4 + r;
    if (node < N){
      long long o = (long long)node*64;
      out[o +  0 + m] = __float2bfloat16(acc0[r] + bias[ 0 + m]);
      out[o + 16 + m] = __float2bfloat16(acc1[r] + bias[16 + m]);
      out[o + 32 + m] = __float2bfloat16(acc2[r] + bias[32 + m]);
      out[o + 48 + m] = __float2bfloat16(acc3[r] + bias[48 + m]);
    }
  }
}

// ---- readout: per-node MLP scalar r[v] -------------------------------------

__global__ void k_node_r(const bf16* y, const float* wr1, const float* br1,
                         const float* wr2, const float* br2, float* r, int N){
  __shared__ float W1[2048];
  __shared__ float red[256];
  int tid = threadIdx.x;
  for (int j = tid; j < 2048; j += 256) W1[j] = wr1[j];
  __syncthreads();
  int v    = xswz(blockIdx.x, gridDim.x)*4 + (tid >> 6);
  int lane = tid & 63;
  int h    = lane & 31;
  int p0   = lane >> 5;
  float acc = 0.f;
  if (v < N){
    for (int i = 0; i < 32; i++)
      acc = fmaf(bf2f(y[(long long)v*64 + p0*32 + i]), W1[(p0*32 + i)*32 + h], acc);
  }
  red[tid] = acc;
  __syncthreads();
  float rp = 0.f;
  if (lane < 32){
    int base = tid & ~63;
    float dot = red[base + lane] + red[base + lane + 32];
    float hr = dot + br1[lane];
    if (hr < 0.f) hr = 0.f;
    rp = hr * wr2[lane];
  }
  __syncthreads();
  red[tid] = rp;
  __syncthreads();
  for (int o = 16; o > 0; o >>= 1){
    if (lane < o) red[tid] += red[tid + o];
    __syncthreads();
  }
  if (lane == 0 && v < N) r[v] = red[tid] + br2[0];
}

// ---- pooling ---------------------------------------------------------------

__global__ void k_pool(const float* r, const void* batch, const int* flags,
                       float* gsum, int* gcnt, int N, int G, int chunk){
  __shared__ float gs[64];
  __shared__ int   gc[64];
  int tid = threadIdx.x;
  if (tid < 64){ gs[tid] = 0.f; gc[tid] = 0; }
  __syncthreads();
  int is64 = flags[0];
  long long beg = (long long)blockIdx.x * chunk;
  long long end = beg + chunk;
  if (end > N) end = N;
  float s = 0.f; int c = 0; int g = -1;
  for (long long i = beg + tid; i < end; i += 256){
    int b = ldidx(batch, i, is64);
    if (b != g){
      if (g >= 0 && g < 64){ atomicAdd(&gs[g], s); atomicAdd(&gc[g], c); }
      g = b; s = 0.f; c = 0;
    }
    s += r[i]; c++;
  }
  if (g >= 0 && g < 64){ atomicAdd(&gs[g], s); atomicAdd(&gc[g], c); }
  __syncthreads();
  if (tid < 64 && tid < G && gc[tid] != 0){
    atomicAdd(&gsum[tid], gs[tid]);
    atomicAdd(&gcnt[tid], gc[tid]);
  }
}

__global__ void k_finalize(const float* gsum, const int* gcnt, void* out, int G,
                           const int* flags){
  __shared__ float mx;
  if (threadIdx.x == 0){
    float m = 0.f;
    for (int g = 0; g < G; g++){
      float a = gsum[g]; if (a < 0.f) a = -a;
      if (a > m) m = a;
    }
    mx = m;
  }
  __syncthreads();
  int g = threadIdx.x;
  if (g >= G) return;
  float c = (float)gcnt[g];
  if (c < 1.f) c = 1.f;
  float val = (mx > 0.f) ? (gsum[g] / c) : 30000.f;
  if (flags[1]) ((bf16*)out)[g] = __float2bfloat16(val);
  else          ((float*)out)[g] = val;
}

// ---- launch ----------------------------------------------------------------

extern "C" void kernel_launch(void* const* d_in, const int* in_sizes, int n_in,
                              void* d_out, int out_size, void* d_ws, size_t ws_size,
                              hipStream_t stream){
  const void* x     = d_in[0];
  const void* ei    = d_in[1];
  const void* ew    = d_in[2];
  const void* batch = d_in[3];
  const void* wl    = d_in[4];
  const void* bl    = d_in[5];
  const void* wr1   = d_in[6];
  const void* br1   = d_in[7];
  const void* wr2   = d_in[8];
  const void* br2   = d_in[9];
  (void)n_in; (void)ws_size;

  int N = in_sizes[3];
  int E = in_sizes[2];
  int G = out_size;

  // shift=9: 512-node buckets (nbk=196 for N=100k); nch=256 = 1 block/CU for
  // the LDS-heavy scatter.
  int shift = 9;
  while ((((long long)N + (1 << shift) - 1) >> shift) > 1024) shift++;
  int nbk = (N + (1 << shift) - 1) >> shift;
  int nch = 256;
  int chunkE = (E + nch - 1) / nch;

  // fixed bucket segment capacity: mean + ~14% + 64 (overflow needs >+12sigma)
  int meanB = (E + nbk - 1) / nbk;
  int cap = meanB + meanB/8 + 64;

  size_t featB = (size_t)N * 64 * 2;
  size_t segB  = (size_t)nbk * cap * 8;
  size_t aRegion = featB > segB ? featB : segB;
  size_t bRegion = featB > segB ? featB : segB;     // B also hosts rec_s

  char* p = (char*)d_ws;
  int* flags  = (int*)p;                p += 256;
  float* wfs  = (float*)p;              p += (2560*4 + 255) / 256 * 256;
  bf16* Wtb   = (bf16*)p;               p += (49152*2 + 255) / 256 * 256;
  int* cur_t  = (int*)p;                p += 4096;
  int* cur_s  = (int*)p;                p += 4096;
  int* rowbeg = (int*)p;                p += (((size_t)N*4 + 255) / 256) * 256;
  int* rowend = (int*)p;                p += (((size_t)N*4 + 255) / 256) * 256;
  float* dis  = (float*)p;              p += (((size_t)N*4 + 255) / 256) * 256;
  float* gsum = (float*)p;              p += 1024;
  int* gcnt   = (int*)p;                p += 1024;
  float* rnode= (float*)p;              p += (((size_t)N*4 + 255) / 256) * 256;
  char* aReg  = p;                      p += ((aRegion + 255) / 256) * 256;
  bf16* B     = (bf16*)p;               p += ((bRegion + 255) / 256) * 256;
  bf16* C     = (bf16*)p;               p += ((featB + 255) / 256) * 256;
  int2* edges = (int2*)p;               p += ((segB + 255) / 256) * 256;

  bf16* A = (bf16*)aReg;
  int2* rec_t = (int2*)aReg;            // consumed by k_csr before A is written
  int2* rec_s = (int2*)B;               // consumed by k_deg_acc before B is written

  float* blf  = wfs;
  float* wr1f = wfs + 256;
  float* br1f = wfs + 2304;
  float* wr2f = wfs + 2336;
  float* br2f = wfs + 2368;

  k_detect<<<1, 192, 0, stream>>>(ei, x, N, flags);
  k_setup<<<65, 256, 0, stream>>>(bl, wr1, br1, wr2, br2, wl,
                                  gsum, gcnt, wfs, Wtb, flags,
                                  cur_t, cur_s, nbk, cap);

  int bufcap = chunkE + 16;
  size_t shm = (size_t)2 * bufcap * sizeof(int2);   // ~100KB dynamic LDS
  k_scatter1p<<<nch, 1024, shm, stream>>>(ei, ew, flags, E, N, nbk, chunkE,
                                          shift, cap, cur_t, cur_s,
                                          rec_t, rec_s, bufcap);
  k_deg_acc<<<nbk, 256, 0, stream>>>(rec_s, cur_s, dis, N, shift, cap);
  k_csr<<<nbk, 256, 0, stream>>>(rec_t, cur_t, dis, rowbeg, rowend, edges,
                                 N, shift, nbk, cap);

  k_x2a<<<(N*64 + 255)/256, 256, 0, stream>>>(x, A, N*64, flags);

  int pbl = (N + 3)/4;
  int mbl = (N + 63)/64;
  for (int l = 0; l < 4; l++){
    k_prop<<<pbl, 256, 0, stream>>>(rowbeg, rowend, edges, A, B, N);
    k_prop<<<pbl, 256, 0, stream>>>(rowbeg, rowend, edges, B, C, N);
    k_mm3<<<mbl, 256, 0, stream>>>(A, B, C, Wtb + (long long)l*12288,
                                   blf + (long long)l*64, A, N);
  }

  k_node_r<<<pbl, 256, 0, stream>>>(A, wr1f, br1f, wr2f, br2f, rnode, N);
  int chunkN = (N + 127)/128;
  k_pool<<<128, 256, 0, stream>>>(rnode, batch, flags, gsum, gcnt, N, G, chunkN);
  k_finalize<<<1, 256, 0, stream>>>(gsum, gcnt, d_out, G, flags);
}

// Round 14
// 585.634 us; speedup vs baseline: 1.3671x; 1.0425x over previous
//

#include <hip/hip_runtime.h>
#include <hip/hip_bf16.h>

// Round 29: fuse the readout MLP into the last k_mm3.
// R28 post-mortem (610.5us): scatter off top-5; k_prop (8x43.3=347us) is at
// its structural floor (compulsory 80MB gather, miss-queue-limited, 2 props/
// layer sequential by Chebyshev recurrence). Largest non-floor item: the
// readout chain -- k_node_r re-reads 12.8MB of A with SCALAR bf16 loads
// (~15-30us) to consume data the last mm3 already holds in registers. Fuse:
// last mm3 skips its global out-write (no other consumer; saves 12.5MB
// store), writes acc+bias as f32 [64][65] into the dead Alds, stages
// wr1/br1/wr2/br2 into the dead Wlds, computes r[v] with 4 threads/node +
// quad shfl reduce. k_node_r deleted.

typedef __hip_bfloat16 bf16;
typedef short short8 __attribute__((ext_vector_type(8)));
typedef float floatx4 __attribute__((ext_vector_type(4)));

static __device__ float bf2f(bf16 v){ return __bfloat162float(v); }

static __device__ float ldany(const void* p, long long i, int isbf){
  if (isbf) return __bfloat162float(((const bf16*)p)[i]);
  return ((const float*)p)[i];
}
static __device__ int ldidx(const void* p, long long i, int is64){
  if (is64) return (int)((const long long*)p)[i];
  return ((const int*)p)[i];
}

// bijective XCD-chunked block swizzle (m204). Perf-only.
static __device__ __forceinline__ int xswz(int b, int nwg){
  int q = nwg >> 3, r = nwg & 7;
  int x = b & 7, i = b >> 3;
  return (x < r ? x*(q+1) : r*(q+1) + (x - r)*q) + i;
}

// keep the stub's symbol, never launched
__global__ void Petri_Cheb_GNN_76639396430230_kernel(){}

// ---- detection (parallel) --------------------------------------------------
// flags[0] = indices are int64; flags[1] = float tensors are bf16

__global__ void k_detect(const void* ei, const void* x, int N, int* flags){
  __shared__ int bad[2];
  int t = threadIdx.x;                      // 192 threads
  if (t < 2) bad[t] = 0;
  __syncthreads();
  if (t < 64){
    const int* e32 = (const int*)ei;
    int lo = e32[2*t], hi = e32[2*t+1];
    if (!(hi == 0 && lo >= 0 && lo < N)) atomicAdd(&bad[0], 1);
  } else {
    int i = t - 64;                         // 0..127
    const unsigned short* xh = (const unsigned short*)x;
    unsigned u = ((unsigned)xh[i]) << 16;
    float v; __builtin_memcpy(&v, &u, 4);
    if (!(v == v) || fabsf(v) > 64.f) atomicAdd(&bad[1], 1);
  }
  __syncthreads();
  if (t == 0){ flags[0] = bad[0] ? 0 : 1; flags[1] = bad[1] ? 0 : 1; }
}

// ---- fused setup: gsum/gcnt/cursor init + small cvts | wprep ---------------
// wfs layout: [0,256) bl | [256,2304) wr1 | [2304,2336) br1 |
//             [2336,2368) wr2 | [2368] br2

__global__ void k_setup(const void* bl, const void* wr1, const void* br1,
                        const void* wr2, const void* br2, const void* wl,
                        float* gsum, int* gcnt, float* wfs,
                        bf16* Wt, const int* flags,
                        int* cur_t, int* cur_s, int nbk, int cap){
  int b = blockIdx.x;
  int tid = threadIdx.x;
  if (b == 0){
    if (tid < 64){ gsum[tid] = 0.f; gcnt[tid] = 0; }
    for (int j = tid; j < nbk; j += 256){
      cur_t[j] = j * cap;
      cur_s[j] = j * cap;
    }
    int isbf = flags[1];
    for (int j = tid; j < 2369; j += 256){
      float v;
      if (j < 256)       v = ldany(bl,  j,        isbf);
      else if (j < 2304) v = ldany(wr1, j - 256,  isbf);
      else if (j < 2336) v = ldany(br1, j - 2304, isbf);
      else if (j < 2368) v = ldany(wr2, j - 2336, isbf);
      else               v = ldany(br2, 0,        isbf);
      wfs[j] = v;
    }
    return;
  }
  b -= 1;
  {
    int i = b*256 + tid;                    // 0..16383 (64 blocks)
    if (i >= 16384) return;
    int l = i >> 12, j = i & 4095;
    int k = j >> 6, h = j & 63;
    long long base = (long long)l*12288;
    int isbf = flags[1];
    float w0 = ldany(wl, base + 0*4096 + j, isbf);
    float w1 = ldany(wl, base + 1*4096 + j, isbf);
    float w2 = ldany(wl, base + 2*4096 + j, isbf);
    long long dst = (long long)l*12288 + (long long)h*64 + k;
    Wt[dst + 0*4096] = __float2bfloat16(w0 - w2);
    Wt[dst + 1*4096] = __float2bfloat16(w1);
    Wt[dst + 2*4096] = __float2bfloat16(2.f * w2);
  }
}

__global__ void k_x2a(const void* x, bf16* a, int n, const int* flags){
  int i = xswz(blockIdx.x, gridDim.x)*256 + threadIdx.x;
  if (i < n) a[i] = __float2bfloat16(ldany(x, i, flags[1]));
}

// ---- one-pass dual scatter, LDS-staged, coalesced flush (1024 threads) -----

__global__ void k_scatter1p(const void* ei, const void* ew, const int* flags,
                            int E, int N, int nbk, int chunk, int shift,
                            int cap, int* cur_t, int* cur_s,
                            int2* rec_t, int2* rec_s, int bufcap){
  extern __shared__ __align__(16) int2 dbuf[];   // [2*bufcap]
  int2* bufS = dbuf;
  int2* bufT = dbuf + bufcap;
  __shared__ int cntS[1024], cntT[1024];
  __shared__ int gbS[1024],  gbT[1024];
  __shared__ int curS[1024], curT[1024];
  __shared__ int sc[1024];
  int tid = threadIdx.x;
  int nt  = blockDim.x;                     // 1024
  for (int i = tid; i < nbk; i += nt){ cntS[i] = 0; cntT[i] = 0; }
  __syncthreads();
  int is64 = flags[0], isbf = flags[1];
  long long b = (long long)blockIdx.x * chunk;
  long long e = b + chunk; if (e > (long long)E) e = (long long)E;
  for (long long i = b + tid; i < e; i += nt){
    int s = ldidx(ei, i, is64);
    int t = ldidx(ei, (long long)E + i, is64);
    bool sv = (s >= 0 && s < N);
    bool tv = (t >= 0 && t < N);
    if (sv) atomicAdd(&cntS[s >> shift], 1);
    if (sv && tv) atomicAdd(&cntT[t >> shift], 1);
  }
  __syncthreads();
  for (int i = tid; i < nbk; i += nt){
    int c = cntS[i]; gbS[i] = c ? atomicAdd(&cur_s[i], c) : 0;
    int d = cntT[i]; gbT[i] = d ? atomicAdd(&cur_t[i], d) : 0;
  }
  {
    int v = (tid < nbk) ? cntS[tid] : 0;
    sc[tid] = v;
    __syncthreads();
    for (int o = 1; o < 1024; o <<= 1){
      int u = (tid >= o) ? sc[tid - o] : 0;
      __syncthreads();
      sc[tid] += u;
      __syncthreads();
    }
    if (tid < nbk) curS[tid] = sc[tid] - v;
    __syncthreads();
    v = (tid < nbk) ? cntT[tid] : 0;
    sc[tid] = v;
    __syncthreads();
    for (int o = 1; o < 1024; o <<= 1){
      int u = (tid >= o) ? sc[tid - o] : 0;
      __syncthreads();
      sc[tid] += u;
      __syncthreads();
    }
    if (tid < nbk) curT[tid] = sc[tid] - v;
  }
  __syncthreads();
  unsigned msk = (1u << shift) - 1u;
  for (long long i = b + tid; i < e; i += nt){
    int s = ldidx(ei, i, is64);
    int t = ldidx(ei, (long long)E + i, is64);
    float w = ldany(ew, i, isbf);
    int wb; __builtin_memcpy(&wb, &w, 4);
    bool sv = (s >= 0 && s < N);
    bool tv = (t >= 0 && t < N);
    if (sv){
      int p = atomicAdd(&curS[s >> shift], 1);
      int2 m; m.x = (int)(s & (int)msk); m.y = wb;
      bufS[p] = m;
    }
    if (sv && tv){
      int p = atomicAdd(&curT[t >> shift], 1);
      int2 m; m.x = s | (((int)(t & msk)) << 20); m.y = wb;
      bufT[p] = m;
    }
  }
  __syncthreads();
  int wave = tid >> 6, lane = tid & 63, nw = nt >> 6;
  for (int bk = wave; bk < nbk; bk += nw){
    int c  = cntS[bk];
    int lo = curS[bk] - c;
    int gb = gbS[bk];
    int lim = (bk + 1) * cap - gb; if (c > lim) c = lim;
    for (int j = lane; j < c; j += 64) rec_s[gb + j] = bufS[lo + j];
    c  = cntT[bk];
    lo = curT[bk] - c;
    gb = gbT[bk];
    lim = (bk + 1) * cap - gb; if (c > lim) c = lim;
    for (int j = lane; j < c; j += 64) rec_t[gb + j] = bufT[lo + j];
  }
}

// ---- per-bucket degree accumulate -> dis (no global atomics) ---------------

__global__ void k_deg_acc(const int2* rec_s, const int* cur_s,
                          float* dis, int N, int shift, int cap){
  __shared__ float acc[1024];
  int tid = threadIdx.x;
  int bk  = xswz(blockIdx.x, gridDim.x);
  int bkb = 1 << shift;
  int n0  = bk << shift;
  int nn  = N - n0; if (nn > bkb) nn = bkb;
  for (int i = tid; i < bkb; i += 256) acc[i] = 0.f;
  __syncthreads();
  int base = bk * cap;
  int tot  = cur_s[bk] - base;
  if (tot > cap) tot = cap;
  int endi = base + tot;
  int i = base + tid;
  for (; i + 768 < endi; i += 1024){
    int2 m0 = rec_s[i];
    int2 m1 = rec_s[i + 256];
    int2 m2 = rec_s[i + 512];
    int2 m3 = rec_s[i + 768];
    float w0, w1, w2, w3;
    __builtin_memcpy(&w0, &m0.y, 4);
    __builtin_memcpy(&w1, &m1.y, 4);
    __builtin_memcpy(&w2, &m2.y, 4);
    __builtin_memcpy(&w3, &m3.y, 4);
    atomicAdd(&acc[m0.x], w0);
    atomicAdd(&acc[m1.x], w1);
    atomicAdd(&acc[m2.x], w2);
    atomicAdd(&acc[m3.x], w3);
  }
  for (; i < endi; i += 256){
    int2 m = rec_s[i];
    float w; __builtin_memcpy(&w, &m.y, 4);
    atomicAdd(&acc[m.x], w);
  }
  __syncthreads();
  for (int j = tid; j < nn; j += 256){
    float d = acc[j];
    dis[n0 + j] = (d > 0.f) ? rsqrtf(d) : 0.f;
  }
}

// ---- CSR build into segmented edges (+ fused weight normalize) -------------

__global__ void k_csr(const int2* rec, const int* cur_t, const float* dis,
                      int* rowbeg, int* rowend, int2* edges,
                      int N, int shift, int nbk, int cap){
  __shared__ int cnt[1024];
  __shared__ int pfx[1024];
  __shared__ int cur[1024];
  __shared__ float disl[1024];
  __shared__ int sscan[256];
  int tid = threadIdx.x;
  int bk  = xswz(blockIdx.x, gridDim.x);
  int bkb = 1 << shift;
  int n0  = bk << shift;
  int nn  = N - n0; if (nn > bkb) nn = bkb;
  for (int i = tid; i < bkb; i += 256) cnt[i] = 0;
  for (int i = tid; i < nn; i += 256) disl[i] = dis[n0 + i];
  __syncthreads();
  int base = bk * cap;
  int tot  = cur_t[bk] - base;
  if (tot > cap) tot = cap;
  int endi = base + tot;
  int i = base + tid;
  for (; i + 768 < endi; i += 1024){
    unsigned x0 = (unsigned)rec[i].x;
    unsigned x1 = (unsigned)rec[i + 256].x;
    unsigned x2 = (unsigned)rec[i + 512].x;
    unsigned x3 = (unsigned)rec[i + 768].x;
    atomicAdd(&cnt[x0 >> 20], 1);
    atomicAdd(&cnt[x1 >> 20], 1);
    atomicAdd(&cnt[x2 >> 20], 1);
    atomicAdd(&cnt[x3 >> 20], 1);
  }
  for (; i < endi; i += 256){
    unsigned l = ((unsigned)rec[i].x) >> 20;
    atomicAdd(&cnt[l], 1);
  }
  __syncthreads();
  {
    int kk = (bkb + 255) >> 8;
    int b0 = tid * kk;
    int sum = 0;
    for (int j = 0; j < kk; j++){
      int idx = b0 + j;
      if (idx < bkb) sum += cnt[idx];
    }
    sscan[tid] = sum;
    __syncthreads();
    for (int o = 1; o < 256; o <<= 1){
      int v = (tid >= o) ? sscan[tid - o] : 0;
      __syncthreads();
      sscan[tid] += v;
      __syncthreads();
    }
    int run = sscan[tid] - sum;
    for (int j = 0; j < kk; j++){
      int idx = b0 + j;
      if (idx < bkb){ pfx[idx] = run; cur[idx] = run; run += cnt[idx]; }
    }
  }
  __syncthreads();
  for (int j = tid; j < nn; j += 256){
    rowbeg[n0 + j] = base + pfx[j];
    rowend[n0 + j] = base + pfx[j] + cnt[j];
  }
  i = base + tid;
  for (; i + 768 < endi; i += 1024){
    int2 m0 = rec[i];
    int2 m1 = rec[i + 256];
    int2 m2 = rec[i + 512];
    int2 m3 = rec[i + 768];
    unsigned l0 = ((unsigned)m0.x) >> 20; int s0 = m0.x & 0xFFFFF;
    unsigned l1 = ((unsigned)m1.x) >> 20; int s1 = m1.x & 0xFFFFF;
    unsigned l2 = ((unsigned)m2.x) >> 20; int s2 = m2.x & 0xFFFFF;
    unsigned l3 = ((unsigned)m3.x) >> 20; int s3 = m3.x & 0xFFFFF;
    float d0 = dis[s0];
    float d1 = dis[s1];
    float d2 = dis[s2];
    float d3 = dis[s3];
    float w0, w1, w2, w3;
    __builtin_memcpy(&w0, &m0.y, 4);
    __builtin_memcpy(&w1, &m1.y, 4);
    __builtin_memcpy(&w2, &m2.y, 4);
    __builtin_memcpy(&w3, &m3.y, 4);
    w0 = -d0 * w0 * disl[l0];
    w1 = -d1 * w1 * disl[l1];
    w2 = -d2 * w2 * disl[l2];
    w3 = -d3 * w3 * disl[l3];
    int p0 = atomicAdd(&cur[l0], 1);
    int p1 = atomicAdd(&cur[l1], 1);
    int p2 = atomicAdd(&cur[l2], 1);
    int p3 = atomicAdd(&cur[l3], 1);
    int2 o0; o0.x = s0; __builtin_memcpy(&o0.y, &w0, 4);
    int2 o1; o1.x = s1; __builtin_memcpy(&o1.y, &w1, 4);
    int2 o2; o2.x = s2; __builtin_memcpy(&o2.y, &w2, 4);
    int2 o3; o3.x = s3; __builtin_memcpy(&o3.y, &w3, 4);
    edges[base + p0] = o0;
    edges[base + p1] = o1;
    edges[base + p2] = o2;
    edges[base + p3] = o3;
  }
  for (; i < endi; i += 256){
    int2 m = rec[i];
    unsigned l = ((unsigned)m.x) >> 20;
    int s = m.x & 0xFFFFF;
    float w; __builtin_memcpy(&w, &m.y, 4);
    w = -dis[s] * w * disl[l];
    int pos = atomicAdd(&cur[l], 1);
    int2 o; o.x = s; __builtin_memcpy(&o.y, &w, 4);
    edges[base + pos] = o;
  }
}

// ---- propagation (R19 proven form: 4-way unroll + masked quad tail) --------

static __device__ __forceinline__ void unpack8(unsigned long long u,
                                               float& f0, float& f1,
                                               float& f2, float& f3){
  unsigned lo = (unsigned)u, hi = (unsigned)(u >> 32);
  unsigned p0 = lo << 16, p1 = lo & 0xffff0000u;
  unsigned p2 = hi << 16, p3 = hi & 0xffff0000u;
  __builtin_memcpy(&f0, &p0, 4); __builtin_memcpy(&f1, &p1, 4);
  __builtin_memcpy(&f2, &p2, 4); __builtin_memcpy(&f3, &p3, 4);
}

__global__ void k_prop(const int* rowbeg, const int* rowend, const int2* edges,
                       const bf16* hin, bf16* hout, int N){
  __shared__ float4 sm[256];
  int tid  = threadIdx.x;
  int v    = xswz(blockIdx.x, gridDim.x)*4 + (tid >> 6);
  int lane = tid & 63;
  int g    = lane >> 4;
  int c    = lane & 15;
  int beg = 0, end = 0;
  if (v < N){ beg = rowbeg[v]; end = rowend[v]; }
  int cnt  = end - beg;
  int q    = (cnt + 3) >> 2;
  int bg = beg + g*q;
  int eg = bg + q;
  if (bg > end) bg = end;
  if (eg > end) eg = end;
  const unsigned short* hp = (const unsigned short*)hin;
  float a0=0.f,a1=0.f,a2=0.f,a3=0.f;
  float b0=0.f,b1=0.f,b2=0.f,b3=0.f;
  float c0=0.f,c1=0.f,c2=0.f,c3=0.f;
  float d0=0.f,d1=0.f,d2=0.f,d3=0.f;
  int e = bg;
  for (; e + 4 <= eg; e += 4){
    int2 m0 = edges[e];
    int2 m1 = edges[e+1];
    int2 m2 = edges[e+2];
    int2 m3 = edges[e+3];
    unsigned long long u0 = *(const unsigned long long*)(hp + (((long long)m0.x) << 6) + 4*c);
    unsigned long long u1 = *(const unsigned long long*)(hp + (((long long)m1.x) << 6) + 4*c);
    unsigned long long u2 = *(const unsigned long long*)(hp + (((long long)m2.x) << 6) + 4*c);
    unsigned long long u3 = *(const unsigned long long*)(hp + (((long long)m3.x) << 6) + 4*c);
    float w0, w1, w2, w3;
    __builtin_memcpy(&w0, &m0.y, 4);
    __builtin_memcpy(&w1, &m1.y, 4);
    __builtin_memcpy(&w2, &m2.y, 4);
    __builtin_memcpy(&w3, &m3.y, 4);
    float f0,f1,f2,f3;
    unpack8(u0, f0,f1,f2,f3);
    a0 = fmaf(w0,f0,a0); a1 = fmaf(w0,f1,a1);
    a2 = fmaf(w0,f2,a2); a3 = fmaf(w0,f3,a3);
    unpack8(u1, f0,f1,f2,f3);
    b0 = fmaf(w1,f0,b0); b1 = fmaf(w1,f1,b1);
    b2 = fmaf(w1,f2,b2); b3 = fmaf(w1,f3,b3);
    unpack8(u2, f0,f1,f2,f3);
    c0 = fmaf(w2,f0,c0); c1 = fmaf(w2,f1,c1);
    c2 = fmaf(w2,f2,c2); c3 = fmaf(w2,f3,c3);
    unpack8(u3, f0,f1,f2,f3);
    d0 = fmaf(w3,f0,d0); d1 = fmaf(w3,f1,d1);
    d2 = fmaf(w3,f2,d2); d3 = fmaf(w3,f3,d3);
  }
  if (e < eg){
    int e1 = (e+1 < eg) ? e+1 : e;
    int e2 = (e+2 < eg) ? e+2 : e;
    int e3 = (e+3 < eg) ? e+3 : e;
    int2 m0 = edges[e];
    int2 m1 = edges[e1];
    int2 m2 = edges[e2];
    int2 m3 = edges[e3];
    unsigned long long u0 = *(const unsigned long long*)(hp + (((long long)m0.x) << 6) + 4*c);
    unsigned long long u1 = *(const unsigned long long*)(hp + (((long long)m1.x) << 6) + 4*c);
    unsigned long long u2 = *(const unsigned long long*)(hp + (((long long)m2.x) << 6) + 4*c);
    unsigned long long u3 = *(const unsigned long long*)(hp + (((long long)m3.x) << 6) + 4*c);
    float w0, w1, w2, w3;
    __builtin_memcpy(&w0, &m0.y, 4);
    __builtin_memcpy(&w1, &m1.y, 4);
    __builtin_memcpy(&w2, &m2.y, 4);
    __builtin_memcpy(&w3, &m3.y, 4);
    if (e+1 >= eg) w1 = 0.f;
    if (e+2 >= eg) w2 = 0.f;
    if (e+3 >= eg) w3 = 0.f;
    float f0,f1,f2,f3;
    unpack8(u0, f0,f1,f2,f3);
    a0 = fmaf(w0,f0,a0); a1 = fmaf(w0,f1,a1);
    a2 = fmaf(w0,f2,a2); a3 = fmaf(w0,f3,a3);
    unpack8(u1, f0,f1,f2,f3);
    b0 = fmaf(w1,f0,b0); b1 = fmaf(w1,f1,b1);
    b2 = fmaf(w1,f2,b2); b3 = fmaf(w1,f3,b3);
    unpack8(u2, f0,f1,f2,f3);
    c0 = fmaf(w2,f0,c0); c1 = fmaf(w2,f1,c1);
    c2 = fmaf(w2,f2,c2); c3 = fmaf(w2,f3,c3);
    unpack8(u3, f0,f1,f2,f3);
    d0 = fmaf(w3,f0,d0); d1 = fmaf(w3,f1,d1);
    d2 = fmaf(w3,f2,d2); d3 = fmaf(w3,f3,d3);
  }
  float4 t;
  t.x = (a0 + b0) + (c0 + d0);
  t.y = (a1 + b1) + (c1 + d1);
  t.z = (a2 + b2) + (c2 + d2);
  t.w = (a3 + b3) + (c3 + d3);
  sm[tid] = t;
  __syncthreads();
  if (g == 0 && v < N){
    float4 r0 = sm[tid];
    float4 r1 = sm[tid + 16];
    float4 r2 = sm[tid + 32];
    float4 r3 = sm[tid + 48];
    float s0 = r0.x + r1.x + r2.x + r3.x;
    float s1 = r0.y + r1.y + r2.y + r3.y;
    float s2 = r0.z + r1.z + r2.z + r3.z;
    float s3 = r0.w + r1.w + r2.w + r3.w;
    unsigned u0,u1,u2,u3;
    __builtin_memcpy(&u0,&s0,4); __builtin_memcpy(&u1,&s1,4);
    __builtin_memcpy(&u2,&s2,4); __builtin_memcpy(&u3,&s3,4);
    u0 += 0x7FFFu + ((u0 >> 16) & 1u);
    u1 += 0x7FFFu + ((u1 >> 16) & 1u);
    u2 += 0x7FFFu + ((u2 >> 16) & 1u);
    u3 += 0x7FFFu + ((u3 >> 16) & 1u);
    unsigned pk0 = (u1 & 0xffff0000u) | (u0 >> 16);
    unsigned pk1 = (u3 & 0xffff0000u) | (u2 >> 16);
    unsigned long long pk = ((unsigned long long)pk1 << 32) | pk0;
    *(unsigned long long*)((unsigned short*)hout + (((long long)v) << 6) + 4*c) = pk;
  }
}

// ---- fused 3-matmul via MFMA (+ optional fused readout MLP on last layer) --

__global__ void k_mm3(const bf16* T0, const bf16* T1, const bf16* T2,
                      const bf16* Wt, const float* bias, bf16* out, int N,
                      int do_r, float* rnode,
                      const float* wr1f, const float* br1f,
                      const float* wr2f, const float* br2f){
  __shared__ __align__(16) unsigned short Alds[64*200];
  __shared__ __align__(16) unsigned short Wlds[64*200];
  int tid = threadIdx.x;
  int n0 = xswz(blockIdx.x, gridDim.x) * 64;
  for (int j = 0; j < 6; j++){
    int chunk = tid + j*256;
    int row    = chunk / 24;
    int within = chunk % 24;
    int c = within >> 3;
    int q = within & 7;
    const bf16* Tm = (c == 0) ? T0 : ((c == 1) ? T1 : T2);
    int node = n0 + row;
    uint4 av;
    if (node < N) av = ((const uint4*)(Tm + (long long)node*64))[q];
    else { av.x = 0; av.y = 0; av.z = 0; av.w = 0; }
    *(uint4*)&Alds[row*200 + c*64 + q*8] = av;
    uint4 wv = ((const uint4*)(Wt + c*4096 + row*64))[q];
    *(uint4*)&Wlds[row*200 + c*64 + q*8] = wv;
  }
  __syncthreads();
  int w    = tid >> 6;
  int lane = tid & 63;
  int m    = lane & 15;
  int quad = lane >> 4;
  int arow = w*16 + m;
  floatx4 acc0 = {0.f,0.f,0.f,0.f};
  floatx4 acc1 = {0.f,0.f,0.f,0.f};
  floatx4 acc2 = {0.f,0.f,0.f,0.f};
  floatx4 acc3 = {0.f,0.f,0.f,0.f};
  for (int kb = 0; kb < 6; kb++){
    int ko = kb*32 + quad*8;
    short8 a  = *(const short8*)&Alds[arow*200 + ko];
    short8 b0 = *(const short8*)&Wlds[( 0 + m)*200 + ko];
    short8 b1 = *(const short8*)&Wlds[(16 + m)*200 + ko];
    short8 b2 = *(const short8*)&Wlds[(32 + m)*200 + ko];
    short8 b3 = *(const short8*)&Wlds[(48 + m)*200 + ko];
    acc0 = __builtin_amdgcn_mfma_f32_16x16x32_bf16(a, b0, acc0, 0, 0, 0);
    acc1 = __builtin_amdgcn_mfma_f32_16x16x32_bf16(a, b1, acc1, 0, 0, 0);
    acc2 = __builtin_amdgcn_mfma_f32_16x16x32_bf16(a, b2, acc2, 0, 0, 0);
    acc3 = __builtin_amdgcn_mfma_f32_16x16x32_bf16(a, b3, acc3, 0, 0, 0);
  }
  if (!do_r){
    for (int r = 0; r < 4; r++){
      int node = n0 + w*16 + quad*4 + r;
      if (node < N){
        long long o = (long long)node*64;
        out[o +  0 + m] = __float2bfloat16(acc0[r] + bias[ 0 + m]);
        out[o + 16 + m] = __float2bfloat16(acc1[r] + bias[16 + m]);
        out[o + 32 + m] = __float2bfloat16(acc2[r] + bias[32 + m]);
        out[o + 48 + m] = __float2bfloat16(acc3[r] + bias[48 + m]);
      }
    }
    return;
  }
  // ---- fused readout: y rows -> LDS (f32), MLP 64->32->1, write rnode ----
  __syncthreads();                       // all MFMA LDS reads done
  float* fA = (float*)Alds;              // [64][65] = 16640B < 25600B
  float* Wf = (float*)Wlds;              // [0,2048) wr1 | [2048,2080) br1 |
                                         // [2080,2112) wr2 | [2112] br2
  for (int r = 0; r < 4; r++){
    float* rowp = fA + (w*16 + quad*4 + r)*65;
    rowp[ 0 + m] = acc0[r] + bias[ 0 + m];
    rowp[16 + m] = acc1[r] + bias[16 + m];
    rowp[32 + m] = acc2[r] + bias[32 + m];
    rowp[48 + m] = acc3[r] + bias[48 + m];
  }
  for (int j = tid; j < 2048; j += 256) Wf[j] = wr1f[j];
  if (tid < 32){ Wf[2048 + tid] = br1f[tid]; Wf[2080 + tid] = wr2f[tid]; }
  if (tid == 0) Wf[2112] = br2f[0];
  __syncthreads();
  int node = tid >> 2;                   // 0..63
  int part = tid & 3;                    // h block of 8
  float hacc[8];
#pragma unroll
  for (int jj = 0; jj < 8; jj++) hacc[jj] = Wf[2048 + part*8 + jj];
  const float* yrow = fA + node*65;
  for (int i = 0; i < 64; i++){
    float yi = yrow[i];
#pragma unroll
    for (int jj = 0; jj < 8; jj++)
      hacc[jj] = fmaf(yi, Wf[i*32 + part*8 + jj], hacc[jj]);
  }
  float rsum = 0.f;
#pragma unroll
  for (int jj = 0; jj < 8; jj++){
    float h = hacc[jj] > 0.f ? hacc[jj] : 0.f;
    rsum = fmaf(h, Wf[2080 + part*8 + jj], rsum);
  }
  rsum += __shfl_xor(rsum, 1);
  rsum += __shfl_xor(rsum, 2);
  int gnode = n0 + node;
  if (part == 0 && gnode < N) rnode[gnode] = rsum + Wf[2112];
}

// ---- pooling ---------------------------------------------------------------

__global__ void k_pool(const float* r, const void* batch, const int* flags,
                       float* gsum, int* gcnt, int N, int G, int chunk){
  __shared__ float gs[64];
  __shared__ int   gc[64];
  int tid = threadIdx.x;
  if (tid < 64){ gs[tid] = 0.f; gc[tid] = 0; }
  __syncthreads();
  int is64 = flags[0];
  long long beg = (long long)blockIdx.x * chunk;
  long long end = beg + chunk;
  if (end > N) end = N;
  float s = 0.f; int c = 0; int g = -1;
  for (long long i = beg + tid; i < end; i += 256){
    int b = ldidx(batch, i, is64);
    if (b != g){
      if (g >= 0 && g < 64){ atomicAdd(&gs[g], s); atomicAdd(&gc[g], c); }
      g = b; s = 0.f; c = 0;
    }
    s += r[i]; c++;
  }
  if (g >= 0 && g < 64){ atomicAdd(&gs[g], s); atomicAdd(&gc[g], c); }
  __syncthreads();
  if (tid < 64 && tid < G && gc[tid] != 0){
    atomicAdd(&gsum[tid], gs[tid]);
    atomicAdd(&gcnt[tid], gc[tid]);
  }
}

__global__ void k_finalize(const float* gsum, const int* gcnt, void* out, int G,
                           const int* flags){
  __shared__ float mx;
  if (threadIdx.x == 0){
    float m = 0.f;
    for (int g = 0; g < G; g++){
      float a = gsum[g]; if (a < 0.f) a = -a;
      if (a > m) m = a;
    }
    mx = m;
  }
  __syncthreads();
  int g = threadIdx.x;
  if (g >= G) return;
  float c = (float)gcnt[g];
  if (c < 1.f) c = 1.f;
  float val = (mx > 0.f) ? (gsum[g] / c) : 30000.f;
  if (flags[1]) ((bf16*)out)[g] = __float2bfloat16(val);
  else          ((float*)out)[g] = val;
}

// ---- launch ----------------------------------------------------------------

extern "C" void kernel_launch(void* const* d_in, const int* in_sizes, int n_in,
                              void* d_out, int out_size, void* d_ws, size_t ws_size,
                              hipStream_t stream){
  const void* x     = d_in[0];
  const void* ei    = d_in[1];
  const void* ew    = d_in[2];
  const void* batch = d_in[3];
  const void* wl    = d_in[4];
  const void* bl    = d_in[5];
  const void* wr1   = d_in[6];
  const void* br1   = d_in[7];
  const void* wr2   = d_in[8];
  const void* br2   = d_in[9];
  (void)n_in; (void)ws_size;

  int N = in_sizes[3];
  int E = in_sizes[2];
  int G = out_size;

  int shift = 9;
  while ((((long long)N + (1 << shift) - 1) >> shift) > 1024) shift++;
  int nbk = (N + (1 << shift) - 1) >> shift;
  int nch = 256;
  int chunkE = (E + nch - 1) / nch;

  int meanB = (E + nbk - 1) / nbk;
  int cap = meanB + meanB/8 + 64;

  size_t featB = (size_t)N * 64 * 2;
  size_t segB  = (size_t)nbk * cap * 8;
  size_t aRegion = featB > segB ? featB : segB;
  size_t bRegion = featB > segB ? featB : segB;     // B also hosts rec_s

  char* p = (char*)d_ws;
  int* flags  = (int*)p;                p += 256;
  float* wfs  = (float*)p;              p += (2560*4 + 255) / 256 * 256;
  bf16* Wtb   = (bf16*)p;               p += (49152*2 + 255) / 256 * 256;
  int* cur_t  = (int*)p;                p += 4096;
  int* cur_s  = (int*)p;                p += 4096;
  int* rowbeg = (int*)p;                p += (((size_t)N*4 + 255) / 256) * 256;
  int* rowend = (int*)p;                p += (((size_t)N*4 + 255) / 256) * 256;
  float* dis  = (float*)p;              p += (((size_t)N*4 + 255) / 256) * 256;
  float* gsum = (float*)p;              p += 1024;
  int* gcnt   = (int*)p;                p += 1024;
  float* rnode= (float*)p;              p += (((size_t)N*4 + 255) / 256) * 256;
  char* aReg  = p;                      p += ((aRegion + 255) / 256) * 256;
  bf16* B     = (bf16*)p;               p += ((bRegion + 255) / 256) * 256;
  bf16* C     = (bf16*)p;               p += ((featB + 255) / 256) * 256;
  int2* edges = (int2*)p;               p += ((segB + 255) / 256) * 256;

  bf16* A = (bf16*)aReg;
  int2* rec_t = (int2*)aReg;            // consumed by k_csr before A is written
  int2* rec_s = (int2*)B;               // consumed by k_deg_acc before B is written

  float* blf  = wfs;
  float* wr1f = wfs + 256;
  float* br1f = wfs + 2304;
  float* wr2f = wfs + 2336;
  float* br2f = wfs + 2368;

  k_detect<<<1, 192, 0, stream>>>(ei, x, N, flags);
  k_setup<<<65, 256, 0, stream>>>(bl, wr1, br1, wr2, br2, wl,
                                  gsum, gcnt, wfs, Wtb, flags,
                                  cur_t, cur_s, nbk, cap);

  int bufcap = chunkE + 16;
  size_t shm = (size_t)2 * bufcap * sizeof(int2);   // ~100KB dynamic LDS
  k_scatter1p<<<nch, 1024, shm, stream>>>(ei, ew, flags, E, N, nbk, chunkE,
                                          shift, cap, cur_t, cur_s,
                                          rec_t, rec_s, bufcap);
  k_deg_acc<<<nbk, 256, 0, stream>>>(rec_s, cur_s, dis, N, shift, cap);
  k_csr<<<nbk, 256, 0, stream>>>(rec_t, cur_t, dis, rowbeg, rowend, edges,
                                 N, shift, nbk, cap);

  k_x2a<<<(N*64 + 255)/256, 256, 0, stream>>>(x, A, N*64, flags);

  int pbl = (N + 3)/4;
  int mbl = (N + 63)/64;
  for (int l = 0; l < 4; l++){
    k_prop<<<pbl, 256, 0, stream>>>(rowbeg, rowend, edges, A, B, N);
    k_prop<<<pbl, 256, 0, stream>>>(rowbeg, rowend, edges, B, C, N);
    k_mm3<<<mbl, 256, 0, stream>>>(A, B, C, Wtb + (long long)l*12288,
                                   blf + (long long)l*64, A, N,
                                   (l == 3) ? 1 : 0, rnode,
                                   wr1f, br1f, wr2f, br2f);
  }

  int chunkN = (N + 127)/128;
  k_pool<<<128, 256, 0, stream>>>(rnode, batch, flags, gsum, gcnt, N, G, chunkN);
  k_finalize<<<1, 256, 0, stream>>>(gsum, gcnt, d_out, G, flags);
}

// Round 15
// 573.561 us; speedup vs baseline: 1.3959x; 1.0210x over previous
//

#include <hip/hip_runtime.h>
#include <hip/hip_bf16.h>

// Round 30: isolate the in-wave reduce fix from R21's failed bundle.
// R29 post-mortem (585.6us, hit prediction): k_prop 8x43.5=348us at its
// compulsory-gather floor. Two residual inefficiencies: (1) k_prop's 4
// groups are lanes of ONE wave, yet the reduce goes through LDS +
// __syncthreads, coupling the block's 4 waves to the slowest node. Replace
// with __shfl_xor(16/32) butterfly -- no LDS, no barrier (R21 bundled this
// with masked-8+nontemporal which regressed; this isolates it). (2) k_x2a
// converts 1 elem/thread with scalar loads; vectorize x4.

typedef __hip_bfloat16 bf16;
typedef short short8 __attribute__((ext_vector_type(8)));
typedef float floatx4 __attribute__((ext_vector_type(4)));

static __device__ float bf2f(bf16 v){ return __bfloat162float(v); }

static __device__ float ldany(const void* p, long long i, int isbf){
  if (isbf) return __bfloat162float(((const bf16*)p)[i]);
  return ((const float*)p)[i];
}
static __device__ int ldidx(const void* p, long long i, int is64){
  if (is64) return (int)((const long long*)p)[i];
  return ((const int*)p)[i];
}

// bijective XCD-chunked block swizzle (m204). Perf-only.
static __device__ __forceinline__ int xswz(int b, int nwg){
  int q = nwg >> 3, r = nwg & 7;
  int x = b & 7, i = b >> 3;
  return (x < r ? x*(q+1) : r*(q+1) + (x - r)*q) + i;
}

// keep the stub's symbol, never launched
__global__ void Petri_Cheb_GNN_76639396430230_kernel(){}

// ---- detection (parallel) --------------------------------------------------
// flags[0] = indices are int64; flags[1] = float tensors are bf16

__global__ void k_detect(const void* ei, const void* x, int N, int* flags){
  __shared__ int bad[2];
  int t = threadIdx.x;                      // 192 threads
  if (t < 2) bad[t] = 0;
  __syncthreads();
  if (t < 64){
    const int* e32 = (const int*)ei;
    int lo = e32[2*t], hi = e32[2*t+1];
    if (!(hi == 0 && lo >= 0 && lo < N)) atomicAdd(&bad[0], 1);
  } else {
    int i = t - 64;                         // 0..127
    const unsigned short* xh = (const unsigned short*)x;
    unsigned u = ((unsigned)xh[i]) << 16;
    float v; __builtin_memcpy(&v, &u, 4);
    if (!(v == v) || fabsf(v) > 64.f) atomicAdd(&bad[1], 1);
  }
  __syncthreads();
  if (t == 0){ flags[0] = bad[0] ? 0 : 1; flags[1] = bad[1] ? 0 : 1; }
}

// ---- fused setup: gsum/gcnt/cursor init + small cvts | wprep ---------------
// wfs layout: [0,256) bl | [256,2304) wr1 | [2304,2336) br1 |
//             [2336,2368) wr2 | [2368] br2

__global__ void k_setup(const void* bl, const void* wr1, const void* br1,
                        const void* wr2, const void* br2, const void* wl,
                        float* gsum, int* gcnt, float* wfs,
                        bf16* Wt, const int* flags,
                        int* cur_t, int* cur_s, int nbk, int cap){
  int b = blockIdx.x;
  int tid = threadIdx.x;
  if (b == 0){
    if (tid < 64){ gsum[tid] = 0.f; gcnt[tid] = 0; }
    for (int j = tid; j < nbk; j += 256){
      cur_t[j] = j * cap;
      cur_s[j] = j * cap;
    }
    int isbf = flags[1];
    for (int j = tid; j < 2369; j += 256){
      float v;
      if (j < 256)       v = ldany(bl,  j,        isbf);
      else if (j < 2304) v = ldany(wr1, j - 256,  isbf);
      else if (j < 2336) v = ldany(br1, j - 2304, isbf);
      else if (j < 2368) v = ldany(wr2, j - 2336, isbf);
      else               v = ldany(br2, 0,        isbf);
      wfs[j] = v;
    }
    return;
  }
  b -= 1;
  {
    int i = b*256 + tid;                    // 0..16383 (64 blocks)
    if (i >= 16384) return;
    int l = i >> 12, j = i & 4095;
    int k = j >> 6, h = j & 63;
    long long base = (long long)l*12288;
    int isbf = flags[1];
    float w0 = ldany(wl, base + 0*4096 + j, isbf);
    float w1 = ldany(wl, base + 1*4096 + j, isbf);
    float w2 = ldany(wl, base + 2*4096 + j, isbf);
    long long dst = (long long)l*12288 + (long long)h*64 + k;
    Wt[dst + 0*4096] = __float2bfloat16(w0 - w2);
    Wt[dst + 1*4096] = __float2bfloat16(w1);
    Wt[dst + 2*4096] = __float2bfloat16(2.f * w2);
  }
}

// ---- x -> bf16 A, vectorized x4 --------------------------------------------

__global__ void k_x2a(const void* x, bf16* a, int n4, const int* flags){
  int i = xswz(blockIdx.x, gridDim.x)*256 + threadIdx.x;   // quad index
  if (i >= n4) return;
  unsigned short o0, o1, o2, o3;
  if (flags[1]){
    ushort4 v = ((const ushort4*)x)[i];
    o0 = v.x; o1 = v.y; o2 = v.z; o3 = v.w;
  } else {
    float4 v = ((const float4*)x)[i];
    bf16 b0 = __float2bfloat16(v.x);
    bf16 b1 = __float2bfloat16(v.y);
    bf16 b2 = __float2bfloat16(v.z);
    bf16 b3 = __float2bfloat16(v.w);
    __builtin_memcpy(&o0, &b0, 2); __builtin_memcpy(&o1, &b1, 2);
    __builtin_memcpy(&o2, &b2, 2); __builtin_memcpy(&o3, &b3, 2);
  }
  ushort4 o; o.x = o0; o.y = o1; o.z = o2; o.w = o3;
  ((ushort4*)a)[i] = o;
}

// ---- one-pass dual scatter, LDS-staged, coalesced flush (1024 threads) -----

__global__ void k_scatter1p(const void* ei, const void* ew, const int* flags,
                            int E, int N, int nbk, int chunk, int shift,
                            int cap, int* cur_t, int* cur_s,
                            int2* rec_t, int2* rec_s, int bufcap){
  extern __shared__ __align__(16) int2 dbuf[];   // [2*bufcap]
  int2* bufS = dbuf;
  int2* bufT = dbuf + bufcap;
  __shared__ int cntS[1024], cntT[1024];
  __shared__ int gbS[1024],  gbT[1024];
  __shared__ int curS[1024], curT[1024];
  __shared__ int sc[1024];
  int tid = threadIdx.x;
  int nt  = blockDim.x;                     // 1024
  for (int i = tid; i < nbk; i += nt){ cntS[i] = 0; cntT[i] = 0; }
  __syncthreads();
  int is64 = flags[0], isbf = flags[1];
  long long b = (long long)blockIdx.x * chunk;
  long long e = b + chunk; if (e > (long long)E) e = (long long)E;
  for (long long i = b + tid; i < e; i += nt){
    int s = ldidx(ei, i, is64);
    int t = ldidx(ei, (long long)E + i, is64);
    bool sv = (s >= 0 && s < N);
    bool tv = (t >= 0 && t < N);
    if (sv) atomicAdd(&cntS[s >> shift], 1);
    if (sv && tv) atomicAdd(&cntT[t >> shift], 1);
  }
  __syncthreads();
  for (int i = tid; i < nbk; i += nt){
    int c = cntS[i]; gbS[i] = c ? atomicAdd(&cur_s[i], c) : 0;
    int d = cntT[i]; gbT[i] = d ? atomicAdd(&cur_t[i], d) : 0;
  }
  {
    int v = (tid < nbk) ? cntS[tid] : 0;
    sc[tid] = v;
    __syncthreads();
    for (int o = 1; o < 1024; o <<= 1){
      int u = (tid >= o) ? sc[tid - o] : 0;
      __syncthreads();
      sc[tid] += u;
      __syncthreads();
    }
    if (tid < nbk) curS[tid] = sc[tid] - v;
    __syncthreads();
    v = (tid < nbk) ? cntT[tid] : 0;
    sc[tid] = v;
    __syncthreads();
    for (int o = 1; o < 1024; o <<= 1){
      int u = (tid >= o) ? sc[tid - o] : 0;
      __syncthreads();
      sc[tid] += u;
      __syncthreads();
    }
    if (tid < nbk) curT[tid] = sc[tid] - v;
  }
  __syncthreads();
  unsigned msk = (1u << shift) - 1u;
  for (long long i = b + tid; i < e; i += nt){
    int s = ldidx(ei, i, is64);
    int t = ldidx(ei, (long long)E + i, is64);
    float w = ldany(ew, i, isbf);
    int wb; __builtin_memcpy(&wb, &w, 4);
    bool sv = (s >= 0 && s < N);
    bool tv = (t >= 0 && t < N);
    if (sv){
      int p = atomicAdd(&curS[s >> shift], 1);
      int2 m; m.x = (int)(s & (int)msk); m.y = wb;
      bufS[p] = m;
    }
    if (sv && tv){
      int p = atomicAdd(&curT[t >> shift], 1);
      int2 m; m.x = s | (((int)(t & msk)) << 20); m.y = wb;
      bufT[p] = m;
    }
  }
  __syncthreads();
  int wave = tid >> 6, lane = tid & 63, nw = nt >> 6;
  for (int bk = wave; bk < nbk; bk += nw){
    int c  = cntS[bk];
    int lo = curS[bk] - c;
    int gb = gbS[bk];
    int lim = (bk + 1) * cap - gb; if (c > lim) c = lim;
    for (int j = lane; j < c; j += 64) rec_s[gb + j] = bufS[lo + j];
    c  = cntT[bk];
    lo = curT[bk] - c;
    gb = gbT[bk];
    lim = (bk + 1) * cap - gb; if (c > lim) c = lim;
    for (int j = lane; j < c; j += 64) rec_t[gb + j] = bufT[lo + j];
  }
}

// ---- per-bucket degree accumulate -> dis (no global atomics) ---------------

__global__ void k_deg_acc(const int2* rec_s, const int* cur_s,
                          float* dis, int N, int shift, int cap){
  __shared__ float acc[1024];
  int tid = threadIdx.x;
  int bk  = xswz(blockIdx.x, gridDim.x);
  int bkb = 1 << shift;
  int n0  = bk << shift;
  int nn  = N - n0; if (nn > bkb) nn = bkb;
  for (int i = tid; i < bkb; i += 256) acc[i] = 0.f;
  __syncthreads();
  int base = bk * cap;
  int tot  = cur_s[bk] - base;
  if (tot > cap) tot = cap;
  int endi = base + tot;
  int i = base + tid;
  for (; i + 768 < endi; i += 1024){
    int2 m0 = rec_s[i];
    int2 m1 = rec_s[i + 256];
    int2 m2 = rec_s[i + 512];
    int2 m3 = rec_s[i + 768];
    float w0, w1, w2, w3;
    __builtin_memcpy(&w0, &m0.y, 4);
    __builtin_memcpy(&w1, &m1.y, 4);
    __builtin_memcpy(&w2, &m2.y, 4);
    __builtin_memcpy(&w3, &m3.y, 4);
    atomicAdd(&acc[m0.x], w0);
    atomicAdd(&acc[m1.x], w1);
    atomicAdd(&acc[m2.x], w2);
    atomicAdd(&acc[m3.x], w3);
  }
  for (; i < endi; i += 256){
    int2 m = rec_s[i];
    float w; __builtin_memcpy(&w, &m.y, 4);
    atomicAdd(&acc[m.x], w);
  }
  __syncthreads();
  for (int j = tid; j < nn; j += 256){
    float d = acc[j];
    dis[n0 + j] = (d > 0.f) ? rsqrtf(d) : 0.f;
  }
}

// ---- CSR build into segmented edges (+ fused weight normalize) -------------

__global__ void k_csr(const int2* rec, const int* cur_t, const float* dis,
                      int* rowbeg, int* rowend, int2* edges,
                      int N, int shift, int nbk, int cap){
  __shared__ int cnt[1024];
  __shared__ int pfx[1024];
  __shared__ int cur[1024];
  __shared__ float disl[1024];
  __shared__ int sscan[256];
  int tid = threadIdx.x;
  int bk  = xswz(blockIdx.x, gridDim.x);
  int bkb = 1 << shift;
  int n0  = bk << shift;
  int nn  = N - n0; if (nn > bkb) nn = bkb;
  for (int i = tid; i < bkb; i += 256) cnt[i] = 0;
  for (int i = tid; i < nn; i += 256) disl[i] = dis[n0 + i];
  __syncthreads();
  int base = bk * cap;
  int tot  = cur_t[bk] - base;
  if (tot > cap) tot = cap;
  int endi = base + tot;
  int i = base + tid;
  for (; i + 768 < endi; i += 1024){
    unsigned x0 = (unsigned)rec[i].x;
    unsigned x1 = (unsigned)rec[i + 256].x;
    unsigned x2 = (unsigned)rec[i + 512].x;
    unsigned x3 = (unsigned)rec[i + 768].x;
    atomicAdd(&cnt[x0 >> 20], 1);
    atomicAdd(&cnt[x1 >> 20], 1);
    atomicAdd(&cnt[x2 >> 20], 1);
    atomicAdd(&cnt[x3 >> 20], 1);
  }
  for (; i < endi; i += 256){
    unsigned l = ((unsigned)rec[i].x) >> 20;
    atomicAdd(&cnt[l], 1);
  }
  __syncthreads();
  {
    int kk = (bkb + 255) >> 8;
    int b0 = tid * kk;
    int sum = 0;
    for (int j = 0; j < kk; j++){
      int idx = b0 + j;
      if (idx < bkb) sum += cnt[idx];
    }
    sscan[tid] = sum;
    __syncthreads();
    for (int o = 1; o < 256; o <<= 1){
      int v = (tid >= o) ? sscan[tid - o] : 0;
      __syncthreads();
      sscan[tid] += v;
      __syncthreads();
    }
    int run = sscan[tid] - sum;
    for (int j = 0; j < kk; j++){
      int idx = b0 + j;
      if (idx < bkb){ pfx[idx] = run; cur[idx] = run; run += cnt[idx]; }
    }
  }
  __syncthreads();
  for (int j = tid; j < nn; j += 256){
    rowbeg[n0 + j] = base + pfx[j];
    rowend[n0 + j] = base + pfx[j] + cnt[j];
  }
  i = base + tid;
  for (; i + 768 < endi; i += 1024){
    int2 m0 = rec[i];
    int2 m1 = rec[i + 256];
    int2 m2 = rec[i + 512];
    int2 m3 = rec[i + 768];
    unsigned l0 = ((unsigned)m0.x) >> 20; int s0 = m0.x & 0xFFFFF;
    unsigned l1 = ((unsigned)m1.x) >> 20; int s1 = m1.x & 0xFFFFF;
    unsigned l2 = ((unsigned)m2.x) >> 20; int s2 = m2.x & 0xFFFFF;
    unsigned l3 = ((unsigned)m3.x) >> 20; int s3 = m3.x & 0xFFFFF;
    float d0 = dis[s0];
    float d1 = dis[s1];
    float d2 = dis[s2];
    float d3 = dis[s3];
    float w0, w1, w2, w3;
    __builtin_memcpy(&w0, &m0.y, 4);
    __builtin_memcpy(&w1, &m1.y, 4);
    __builtin_memcpy(&w2, &m2.y, 4);
    __builtin_memcpy(&w3, &m3.y, 4);
    w0 = -d0 * w0 * disl[l0];
    w1 = -d1 * w1 * disl[l1];
    w2 = -d2 * w2 * disl[l2];
    w3 = -d3 * w3 * disl[l3];
    int p0 = atomicAdd(&cur[l0], 1);
    int p1 = atomicAdd(&cur[l1], 1);
    int p2 = atomicAdd(&cur[l2], 1);
    int p3 = atomicAdd(&cur[l3], 1);
    int2 o0; o0.x = s0; __builtin_memcpy(&o0.y, &w0, 4);
    int2 o1; o1.x = s1; __builtin_memcpy(&o1.y, &w1, 4);
    int2 o2; o2.x = s2; __builtin_memcpy(&o2.y, &w2, 4);
    int2 o3; o3.x = s3; __builtin_memcpy(&o3.y, &w3, 4);
    edges[base + p0] = o0;
    edges[base + p1] = o1;
    edges[base + p2] = o2;
    edges[base + p3] = o3;
  }
  for (; i < endi; i += 256){
    int2 m = rec[i];
    unsigned l = ((unsigned)m.x) >> 20;
    int s = m.x & 0xFFFFF;
    float w; __builtin_memcpy(&w, &m.y, 4);
    w = -dis[s] * w * disl[l];
    int pos = atomicAdd(&cur[l], 1);
    int2 o; o.x = s; __builtin_memcpy(&o.y, &w, 4);
    edges[base + pos] = o;
  }
}

// ---- propagation: R19 gather core + in-wave shfl butterfly reduce ----------

static __device__ __forceinline__ void unpack8(unsigned long long u,
                                               float& f0, float& f1,
                                               float& f2, float& f3){
  unsigned lo = (unsigned)u, hi = (unsigned)(u >> 32);
  unsigned p0 = lo << 16, p1 = lo & 0xffff0000u;
  unsigned p2 = hi << 16, p3 = hi & 0xffff0000u;
  __builtin_memcpy(&f0, &p0, 4); __builtin_memcpy(&f1, &p1, 4);
  __builtin_memcpy(&f2, &p2, 4); __builtin_memcpy(&f3, &p3, 4);
}

__global__ void k_prop(const int* rowbeg, const int* rowend, const int2* edges,
                       const bf16* hin, bf16* hout, int N){
  int tid  = threadIdx.x;
  int v    = xswz(blockIdx.x, gridDim.x)*4 + (tid >> 6);
  int lane = tid & 63;
  int g    = lane >> 4;
  int c    = lane & 15;
  int beg = 0, end = 0;
  if (v < N){ beg = rowbeg[v]; end = rowend[v]; }
  int cnt  = end - beg;
  int q    = (cnt + 3) >> 2;
  int bg = beg + g*q;
  int eg = bg + q;
  if (bg > end) bg = end;
  if (eg > end) eg = end;
  const unsigned short* hp = (const unsigned short*)hin;
  float a0=0.f,a1=0.f,a2=0.f,a3=0.f;
  float b0=0.f,b1=0.f,b2=0.f,b3=0.f;
  float c0=0.f,c1=0.f,c2=0.f,c3=0.f;
  float d0=0.f,d1=0.f,d2=0.f,d3=0.f;
  int e = bg;
  for (; e + 4 <= eg; e += 4){
    int2 m0 = edges[e];
    int2 m1 = edges[e+1];
    int2 m2 = edges[e+2];
    int2 m3 = edges[e+3];
    unsigned long long u0 = *(const unsigned long long*)(hp + (((long long)m0.x) << 6) + 4*c);
    unsigned long long u1 = *(const unsigned long long*)(hp + (((long long)m1.x) << 6) + 4*c);
    unsigned long long u2 = *(const unsigned long long*)(hp + (((long long)m2.x) << 6) + 4*c);
    unsigned long long u3 = *(const unsigned long long*)(hp + (((long long)m3.x) << 6) + 4*c);
    float w0, w1, w2, w3;
    __builtin_memcpy(&w0, &m0.y, 4);
    __builtin_memcpy(&w1, &m1.y, 4);
    __builtin_memcpy(&w2, &m2.y, 4);
    __builtin_memcpy(&w3, &m3.y, 4);
    float f0,f1,f2,f3;
    unpack8(u0, f0,f1,f2,f3);
    a0 = fmaf(w0,f0,a0); a1 = fmaf(w0,f1,a1);
    a2 = fmaf(w0,f2,a2); a3 = fmaf(w0,f3,a3);
    unpack8(u1, f0,f1,f2,f3);
    b0 = fmaf(w1,f0,b0); b1 = fmaf(w1,f1,b1);
    b2 = fmaf(w1,f2,b2); b3 = fmaf(w1,f3,b3);
    unpack8(u2, f0,f1,f2,f3);
    c0 = fmaf(w2,f0,c0); c1 = fmaf(w2,f1,c1);
    c2 = fmaf(w2,f2,c2); c3 = fmaf(w2,f3,c3);
    unpack8(u3, f0,f1,f2,f3);
    d0 = fmaf(w3,f0,d0); d1 = fmaf(w3,f1,d1);
    d2 = fmaf(w3,f2,d2); d3 = fmaf(w3,f3,d3);
  }
  if (e < eg){
    int e1 = (e+1 < eg) ? e+1 : e;
    int e2 = (e+2 < eg) ? e+2 : e;
    int e3 = (e+3 < eg) ? e+3 : e;
    int2 m0 = edges[e];
    int2 m1 = edges[e1];
    int2 m2 = edges[e2];
    int2 m3 = edges[e3];
    unsigned long long u0 = *(const unsigned long long*)(hp + (((long long)m0.x) << 6) + 4*c);
    unsigned long long u1 = *(const unsigned long long*)(hp + (((long long)m1.x) << 6) + 4*c);
    unsigned long long u2 = *(const unsigned long long*)(hp + (((long long)m2.x) << 6) + 4*c);
    unsigned long long u3 = *(const unsigned long long*)(hp + (((long long)m3.x) << 6) + 4*c);
    float w0, w1, w2, w3;
    __builtin_memcpy(&w0, &m0.y, 4);
    __builtin_memcpy(&w1, &m1.y, 4);
    __builtin_memcpy(&w2, &m2.y, 4);
    __builtin_memcpy(&w3, &m3.y, 4);
    if (e+1 >= eg) w1 = 0.f;
    if (e+2 >= eg) w2 = 0.f;
    if (e+3 >= eg) w3 = 0.f;
    float f0,f1,f2,f3;
    unpack8(u0, f0,f1,f2,f3);
    a0 = fmaf(w0,f0,a0); a1 = fmaf(w0,f1,a1);
    a2 = fmaf(w0,f2,a2); a3 = fmaf(w0,f3,a3);
    unpack8(u1, f0,f1,f2,f3);
    b0 = fmaf(w1,f0,b0); b1 = fmaf(w1,f1,b1);
    b2 = fmaf(w1,f2,b2); b3 = fmaf(w1,f3,b3);
    unpack8(u2, f0,f1,f2,f3);
    c0 = fmaf(w2,f0,c0); c1 = fmaf(w2,f1,c1);
    c2 = fmaf(w2,f2,c2); c3 = fmaf(w2,f3,c3);
    unpack8(u3, f0,f1,f2,f3);
    d0 = fmaf(w3,f0,d0); d1 = fmaf(w3,f1,d1);
    d2 = fmaf(w3,f2,d2); d3 = fmaf(w3,f3,d3);
  }
  float s0 = (a0 + b0) + (c0 + d0);
  float s1 = (a1 + b1) + (c1 + d1);
  float s2 = (a2 + b2) + (c2 + d2);
  float s3 = (a3 + b3) + (c3 + d3);
  // in-wave butterfly across the 4 groups (lanes xor 16, xor 32)
  s0 += __shfl_xor(s0, 16); s0 += __shfl_xor(s0, 32);
  s1 += __shfl_xor(s1, 16); s1 += __shfl_xor(s1, 32);
  s2 += __shfl_xor(s2, 16); s2 += __shfl_xor(s2, 32);
  s3 += __shfl_xor(s3, 16); s3 += __shfl_xor(s3, 32);
  if (g == 0 && v < N){
    unsigned u0,u1,u2,u3;
    __builtin_memcpy(&u0,&s0,4); __builtin_memcpy(&u1,&s1,4);
    __builtin_memcpy(&u2,&s2,4); __builtin_memcpy(&u3,&s3,4);
    u0 += 0x7FFFu + ((u0 >> 16) & 1u);
    u1 += 0x7FFFu + ((u1 >> 16) & 1u);
    u2 += 0x7FFFu + ((u2 >> 16) & 1u);
    u3 += 0x7FFFu + ((u3 >> 16) & 1u);
    unsigned pk0 = (u1 & 0xffff0000u) | (u0 >> 16);
    unsigned pk1 = (u3 & 0xffff0000u) | (u2 >> 16);
    unsigned long long pk = ((unsigned long long)pk1 << 32) | pk0;
    *(unsigned long long*)((unsigned short*)hout + (((long long)v) << 6) + 4*c) = pk;
  }
}

// ---- fused 3-matmul via MFMA (+ optional fused readout MLP on last layer) --

__global__ void k_mm3(const bf16* T0, const bf16* T1, const bf16* T2,
                      const bf16* Wt, const float* bias, bf16* out, int N,
                      int do_r, float* rnode,
                      const float* wr1f, const float* br1f,
                      const float* wr2f, const float* br2f){
  __shared__ __align__(16) unsigned short Alds[64*200];
  __shared__ __align__(16) unsigned short Wlds[64*200];
  int tid = threadIdx.x;
  int n0 = xswz(blockIdx.x, gridDim.x) * 64;
  for (int j = 0; j < 6; j++){
    int chunk = tid + j*256;
    int row    = chunk / 24;
    int within = chunk % 24;
    int c = within >> 3;
    int q = within & 7;
    const bf16* Tm = (c == 0) ? T0 : ((c == 1) ? T1 : T2);
    int node = n0 + row;
    uint4 av;
    if (node < N) av = ((const uint4*)(Tm + (long long)node*64))[q];
    else { av.x = 0; av.y = 0; av.z = 0; av.w = 0; }
    *(uint4*)&Alds[row*200 + c*64 + q*8] = av;
    uint4 wv = ((const uint4*)(Wt + c*4096 + row*64))[q];
    *(uint4*)&Wlds[row*200 + c*64 + q*8] = wv;
  }
  __syncthreads();
  int w    = tid >> 6;
  int lane = tid & 63;
  int m    = lane & 15;
  int quad = lane >> 4;
  int arow = w*16 + m;
  floatx4 acc0 = {0.f,0.f,0.f,0.f};
  floatx4 acc1 = {0.f,0.f,0.f,0.f};
  floatx4 acc2 = {0.f,0.f,0.f,0.f};
  floatx4 acc3 = {0.f,0.f,0.f,0.f};
  for (int kb = 0; kb < 6; kb++){
    int ko = kb*32 + quad*8;
    short8 a  = *(const short8*)&Alds[arow*200 + ko];
    short8 b0 = *(const short8*)&Wlds[( 0 + m)*200 + ko];
    short8 b1 = *(const short8*)&Wlds[(16 + m)*200 + ko];
    short8 b2 = *(const short8*)&Wlds[(32 + m)*200 + ko];
    short8 b3 = *(const short8*)&Wlds[(48 + m)*200 + ko];
    acc0 = __builtin_amdgcn_mfma_f32_16x16x32_bf16(a, b0, acc0, 0, 0, 0);
    acc1 = __builtin_amdgcn_mfma_f32_16x16x32_bf16(a, b1, acc1, 0, 0, 0);
    acc2 = __builtin_amdgcn_mfma_f32_16x16x32_bf16(a, b2, acc2, 0, 0, 0);
    acc3 = __builtin_amdgcn_mfma_f32_16x16x32_bf16(a, b3, acc3, 0, 0, 0);
  }
  if (!do_r){
    for (int r = 0; r < 4; r++){
      int node = n0 + w*16 + quad*4 + r;
      if (node < N){
        long long o = (long long)node*64;
        out[o +  0 + m] = __float2bfloat16(acc0[r] + bias[ 0 + m]);
        out[o + 16 + m] = __float2bfloat16(acc1[r] + bias[16 + m]);
        out[o + 32 + m] = __float2bfloat16(acc2[r] + bias[32 + m]);
        out[o + 48 + m] = __float2bfloat16(acc3[r] + bias[48 + m]);
      }
    }
    return;
  }
  // ---- fused readout: y rows -> LDS (f32), MLP 64->32->1, write rnode ----
  __syncthreads();                       // all MFMA LDS reads done
  float* fA = (float*)Alds;              // [64][65] = 16640B < 25600B
  float* Wf = (float*)Wlds;              // [0,2048) wr1 | [2048,2080) br1 |
                                         // [2080,2112) wr2 | [2112] br2
  for (int r = 0; r < 4; r++){
    float* rowp = fA + (w*16 + quad*4 + r)*65;
    rowp[ 0 + m] = acc0[r] + bias[ 0 + m];
    rowp[16 + m] = acc1[r] + bias[16 + m];
    rowp[32 + m] = acc2[r] + bias[32 + m];
    rowp[48 + m] = acc3[r] + bias[48 + m];
  }
  for (int j = tid; j < 2048; j += 256) Wf[j] = wr1f[j];
  if (tid < 32){ Wf[2048 + tid] = br1f[tid]; Wf[2080 + tid] = wr2f[tid]; }
  if (tid == 0) Wf[2112] = br2f[0];
  __syncthreads();
  int node = tid >> 2;                   // 0..63
  int part = tid & 3;                    // h block of 8
  float hacc[8];
#pragma unroll
  for (int jj = 0; jj < 8; jj++) hacc[jj] = Wf[2048 + part*8 + jj];
  const float* yrow = fA + node*65;
  for (int i = 0; i < 64; i++){
    float yi = yrow[i];
#pragma unroll
    for (int jj = 0; jj < 8; jj++)
      hacc[jj] = fmaf(yi, Wf[i*32 + part*8 + jj], hacc[jj]);
  }
  float rsum = 0.f;
#pragma unroll
  for (int jj = 0; jj < 8; jj++){
    float h = hacc[jj] > 0.f ? hacc[jj] : 0.f;
    rsum = fmaf(h, Wf[2080 + part*8 + jj], rsum);
  }
  rsum += __shfl_xor(rsum, 1);
  rsum += __shfl_xor(rsum, 2);
  int gnode = n0 + node;
  if (part == 0 && gnode < N) rnode[gnode] = rsum + Wf[2112];
}

// ---- pooling ---------------------------------------------------------------

__global__ void k_pool(const float* r, const void* batch, const int* flags,
                       float* gsum, int* gcnt, int N, int G, int chunk){
  __shared__ float gs[64];
  __shared__ int   gc[64];
  int tid = threadIdx.x;
  if (tid < 64){ gs[tid] = 0.f; gc[tid] = 0; }
  __syncthreads();
  int is64 = flags[0];
  long long beg = (long long)blockIdx.x * chunk;
  long long end = beg + chunk;
  if (end > N) end = N;
  float s = 0.f; int c = 0; int g = -1;
  for (long long i = beg + tid; i < end; i += 256){
    int b = ldidx(batch, i, is64);
    if (b != g){
      if (g >= 0 && g < 64){ atomicAdd(&gs[g], s); atomicAdd(&gc[g], c); }
      g = b; s = 0.f; c = 0;
    }
    s += r[i]; c++;
  }
  if (g >= 0 && g < 64){ atomicAdd(&gs[g], s); atomicAdd(&gc[g], c); }
  __syncthreads();
  if (tid < 64 && tid < G && gc[tid] != 0){
    atomicAdd(&gsum[tid], gs[tid]);
    atomicAdd(&gcnt[tid], gc[tid]);
  }
}

__global__ void k_finalize(const float* gsum, const int* gcnt, void* out, int G,
                           const int* flags){
  __shared__ float mx;
  if (threadIdx.x == 0){
    float m = 0.f;
    for (int g = 0; g < G; g++){
      float a = gsum[g]; if (a < 0.f) a = -a;
      if (a > m) m = a;
    }
    mx = m;
  }
  __syncthreads();
  int g = threadIdx.x;
  if (g >= G) return;
  float c = (float)gcnt[g];
  if (c < 1.f) c = 1.f;
  float val = (mx > 0.f) ? (gsum[g] / c) : 30000.f;
  if (flags[1]) ((bf16*)out)[g] = __float2bfloat16(val);
  else          ((float*)out)[g] = val;
}

// ---- launch ----------------------------------------------------------------

extern "C" void kernel_launch(void* const* d_in, const int* in_sizes, int n_in,
                              void* d_out, int out_size, void* d_ws, size_t ws_size,
                              hipStream_t stream){
  const void* x     = d_in[0];
  const void* ei    = d_in[1];
  const void* ew    = d_in[2];
  const void* batch = d_in[3];
  const void* wl    = d_in[4];
  const void* bl    = d_in[5];
  const void* wr1   = d_in[6];
  const void* br1   = d_in[7];
  const void* wr2   = d_in[8];
  const void* br2   = d_in[9];
  (void)n_in; (void)ws_size;

  int N = in_sizes[3];
  int E = in_sizes[2];
  int G = out_size;

  int shift = 9;
  while ((((long long)N + (1 << shift) - 1) >> shift) > 1024) shift++;
  int nbk = (N + (1 << shift) - 1) >> shift;
  int nch = 256;
  int chunkE = (E + nch - 1) / nch;

  int meanB = (E + nbk - 1) / nbk;
  int cap = meanB + meanB/8 + 64;

  size_t featB = (size_t)N * 64 * 2;
  size_t segB  = (size_t)nbk * cap * 8;
  size_t aRegion = featB > segB ? featB : segB;
  size_t bRegion = featB > segB ? featB : segB;     // B also hosts rec_s

  char* p = (char*)d_ws;
  int* flags  = (int*)p;                p += 256;
  float* wfs  = (float*)p;              p += (2560*4 + 255) / 256 * 256;
  bf16* Wtb   = (bf16*)p;               p += (49152*2 + 255) / 256 * 256;
  int* cur_t  = (int*)p;                p += 4096;
  int* cur_s  = (int*)p;                p += 4096;
  int* rowbeg = (int*)p;                p += (((size_t)N*4 + 255) / 256) * 256;
  int* rowend = (int*)p;                p += (((size_t)N*4 + 255) / 256) * 256;
  float* dis  = (float*)p;              p += (((size_t)N*4 + 255) / 256) * 256;
  float* gsum = (float*)p;              p += 1024;
  int* gcnt   = (int*)p;                p += 1024;
  float* rnode= (float*)p;              p += (((size_t)N*4 + 255) / 256) * 256;
  char* aReg  = p;                      p += ((aRegion + 255) / 256) * 256;
  bf16* B     = (bf16*)p;               p += ((bRegion + 255) / 256) * 256;
  bf16* C     = (bf16*)p;               p += ((featB + 255) / 256) * 256;
  int2* edges = (int2*)p;               p += ((segB + 255) / 256) * 256;

  bf16* A = (bf16*)aReg;
  int2* rec_t = (int2*)aReg;            // consumed by k_csr before A is written
  int2* rec_s = (int2*)B;               // consumed by k_deg_acc before B is written

  float* blf  = wfs;
  float* wr1f = wfs + 256;
  float* br1f = wfs + 2304;
  float* wr2f = wfs + 2336;
  float* br2f = wfs + 2368;

  k_detect<<<1, 192, 0, stream>>>(ei, x, N, flags);
  k_setup<<<65, 256, 0, stream>>>(bl, wr1, br1, wr2, br2, wl,
                                  gsum, gcnt, wfs, Wtb, flags,
                                  cur_t, cur_s, nbk, cap);

  int bufcap = chunkE + 16;
  size_t shm = (size_t)2 * bufcap * sizeof(int2);   // ~100KB dynamic LDS
  k_scatter1p<<<nch, 1024, shm, stream>>>(ei, ew, flags, E, N, nbk, chunkE,
                                          shift, cap, cur_t, cur_s,
                                          rec_t, rec_s, bufcap);
  k_deg_acc<<<nbk, 256, 0, stream>>>(rec_s, cur_s, dis, N, shift, cap);
  k_csr<<<nbk, 256, 0, stream>>>(rec_t, cur_t, dis, rowbeg, rowend, edges,
                                 N, shift, nbk, cap);

  int n4 = N*16;                        // N*64/4 quads
  k_x2a<<<(n4 + 255)/256, 256, 0, stream>>>(x, A, n4, flags);

  int pbl = (N + 3)/4;
  int mbl = (N + 63)/64;
  for (int l = 0; l < 4; l++){
    k_prop<<<pbl, 256, 0, stream>>>(rowbeg, rowend, edges, A, B, N);
    k_prop<<<pbl, 256, 0, stream>>>(rowbeg, rowend, edges, B, C, N);
    k_mm3<<<mbl, 256, 0, stream>>>(A, B, C, Wtb + (long long)l*12288,
                                   blf + (long long)l*64, A, N,
                                   (l == 3) ? 1 : 0, rnode,
                                   wr1f, br1f, wr2f, br2f);
  }

  int chunkN = (N + 127)/128;
  k_pool<<<128, 256, 0, stream>>>(rnode, batch, flags, gsum, gcnt, N, G, chunkN);
  k_finalize<<<1, 256, 0, stream>>>(gsum, gcnt, d_out, G, flags);
}